// Round 1
// baseline (1696.261 us; speedup 1.0000x reference)
//
#include <hip/hip_runtime.h>
#include <math.h>

// ---------------------------------------------------------------------------
// Problem constants (bs=256, in_feat=48, d_model=512, dct_n=10, input_n=50,
// output_n=25, KERNEL=10, HEADS=4, vl=35, vn=16)
// ---------------------------------------------------------------------------
static constexpr float BN_SCALE_F = 0.9999950000374997f;

// ---------------- DCT matrix (rows 0..9 of the 35x35 orthonormal DCT-II) ----
__global__ void k_dct(float* __restrict__ d) {
    int id = blockIdx.x * blockDim.x + threadIdx.x;
    if (id < 350) {
        int k = id / 35, i = id % 35;
        double w = (k == 0) ? sqrt(1.0 / 35.0) : sqrt(2.0 / 35.0);
        d[id] = (float)(w * cos(3.14159265358979323846 * (i + 0.5) * k / 35.0));
    }
}

// ---------------- weight transposes ----------------------------------------
// w1[h][o][i][k] (4,512,48,6) -> w1t[h][o][k*48+i], scaled by 1e-3 (the /1000)
__global__ void k_trw1(const float* __restrict__ w, float* __restrict__ wt) {
    int id = blockIdx.x * 256 + threadIdx.x;
    if (id < 4 * 512 * 288) {
        int ho = id / 288, r = id % 288;
        int k = r / 48, i = r % 48;
        (void)k; (void)i;
        wt[id] = w[(long)ho * 288 + (r % 48) * 6 + (r / 48)] * 1e-3f;
    }
}
// w2[h][o][i][k] (4,512,512,5) -> w2t[h][o][k*512+i]
__global__ void k_trw2(const float* __restrict__ w, float* __restrict__ wt) {
    int id = blockIdx.x * 256 + threadIdx.x;
    if (id < 4 * 512 * 2560) {
        int ho = id / 2560, r = id % 2560;
        wt[id] = w[(long)ho * 2560 + (r % 512) * 5 + (r / 512)];
    }
}

// ---------------- generic tiled fp32 GEMM -----------------------------------
// C[n*M + m] = sum_k A(m,k) * B(n,k)   (optionally ReLU'd)
// ATN:  A is row-major M x K  (A[m*K+k])   -- transposed conv weights
// !ATN: A is row-major K x M  (A[k*M+m])   -- GCN weight matrices
// B row base depends on BMODE (conv windows are contiguous slices).
enum { B_SRC = 0, B_R1K = 1, B_R1Q = 2, B_PLAIN = 3 };

template <int BMODE, bool ATN, bool RELU>
__global__ __launch_bounds__(256) void gemm64(
    const float* __restrict__ Ab, const float* __restrict__ Bb,
    float* __restrict__ Cb, const int M, const int N, const int K,
    const int NT, const int toff, const long aStr, const long bStr,
    const long cStr) {
    __shared__ float As[16][68];
    __shared__ float Bs[16][68];
    const int tid = threadIdx.x;
    const int n0 = blockIdx.x * 64;
    const int m0 = blockIdx.y * 64;
    const float* A = Ab + (long)blockIdx.z * aStr;
    const float* B = Bb + (long)blockIdx.z * bStr;
    float* C = Cb + (long)blockIdx.z * cStr;

    const int brow = tid >> 2;         // 0..63 : n within tile (staging)
    const int bk4 = (tid & 3) << 2;    // 0,4,8,12
    long bbase;
    {
        const int n = n0 + brow;
        if (BMODE == B_SRC)
            bbase = (long)(n / NT) * 2400 + (long)((n % NT) + toff) * 48;
        else if (BMODE == B_R1K)
            bbase = (long)((n >> 4) * 20 + (n & 15)) * 512;
        else if (BMODE == B_R1Q)
            bbase = (long)n * 2560;
        else
            bbase = (long)n * K;
    }

    const int am = tid >> 2;           // ATN staging: m, k-quarter
    const int ak4 = (tid & 3) << 2;
    const int ak = tid >> 4;           // ANN staging: k row, m-quarter
    const int am4 = (tid & 15) << 2;

    const int tm = tid & 15;           // micro-tile coords
    const int tn = tid >> 4;

    float acc[4][4];
#pragma unroll
    for (int j = 0; j < 4; ++j)
#pragma unroll
        for (int i = 0; i < 4; ++i) acc[j][i] = 0.f;

    for (int k0 = 0; k0 < K; k0 += 16) {
        if (ATN) {
            const int k = k0 + ak4;
            const long base = (long)(m0 + am) * K;
            float4 av;
            if (k + 3 < K)
                av = *(const float4*)(A + base + k);
            else {
                av.x = (k + 0 < K) ? A[base + k + 0] : 0.f;
                av.y = (k + 1 < K) ? A[base + k + 1] : 0.f;
                av.z = (k + 2 < K) ? A[base + k + 2] : 0.f;
                av.w = (k + 3 < K) ? A[base + k + 3] : 0.f;
            }
            As[ak4 + 0][am] = av.x;
            As[ak4 + 1][am] = av.y;
            As[ak4 + 2][am] = av.z;
            As[ak4 + 3][am] = av.w;
        } else {
            const int k = k0 + ak;
            float4 av = make_float4(0.f, 0.f, 0.f, 0.f);
            if (k < K) av = *(const float4*)(A + (long)k * M + m0 + am4);
            *(float4*)(&As[ak][am4]) = av;
        }
        {
            const int k = k0 + bk4;
            float4 bv;
            if (k + 3 < K)
                bv = *(const float4*)(B + bbase + k);
            else {
                bv.x = (k + 0 < K) ? B[bbase + k + 0] : 0.f;
                bv.y = (k + 1 < K) ? B[bbase + k + 1] : 0.f;
                bv.z = (k + 2 < K) ? B[bbase + k + 2] : 0.f;
                bv.w = (k + 3 < K) ? B[bbase + k + 3] : 0.f;
            }
            Bs[bk4 + 0][brow] = bv.x;
            Bs[bk4 + 1][brow] = bv.y;
            Bs[bk4 + 2][brow] = bv.z;
            Bs[bk4 + 3][brow] = bv.w;
        }
        __syncthreads();
#pragma unroll
        for (int kk = 0; kk < 16; ++kk) {
            const float4 a = *(const float4*)(&As[kk][tm << 2]);
            const float4 b = *(const float4*)(&Bs[kk][tn << 2]);
            const float av_[4] = {a.x, a.y, a.z, a.w};
            const float bv_[4] = {b.x, b.y, b.z, b.w};
#pragma unroll
            for (int j = 0; j < 4; ++j)
#pragma unroll
                for (int i = 0; i < 4; ++i)
                    acc[j][i] = fmaf(bv_[j], av_[i], acc[j][i]);
        }
        __syncthreads();
    }
#pragma unroll
    for (int j = 0; j < 4; ++j) {
        const long n = n0 + (tn << 2) + j;
        float4 v = make_float4(acc[j][0], acc[j][1], acc[j][2], acc[j][3]);
        if (RELU) {
            v.x = fmaxf(v.x, 0.f);
            v.y = fmaxf(v.y, 0.f);
            v.z = fmaxf(v.z, 0.f);
            v.w = fmaxf(v.w, 0.f);
        }
        *(float4*)(C + n * M + m0 + (tm << 2)) = v;
    }
}

// ---------------- attention scoring -----------------------------------------
// score[t] = q . key[t] + 1e-15 ; attw = score / sum(score)
__global__ __launch_bounds__(256) void k_score(const float* __restrict__ qh,
                                               const float* __restrict__ keyh,
                                               float* __restrict__ attw) {
    const int hb = blockIdx.x;  // h*256+b
    const int tid = threadIdx.x;
    __shared__ float qS[512];
    __shared__ float sS[16];
    __shared__ float sSum;
    const float* q = qh + (long)hb * 512;
    qS[tid] = q[tid];
    qS[tid + 256] = q[tid + 256];
    __syncthreads();
    const int t = tid >> 4;
    const int l = tid & 15;
    const float* krow = keyh + ((long)hb * 16 + t) * 512;
    float p = 0.f;
    for (int o = l; o < 512; o += 16) p = fmaf(qS[o], krow[o], p);
#pragma unroll
    for (int off = 8; off; off >>= 1) p += __shfl_down(p, off, 16);
    if (l == 0) sS[t] = p + 1e-15f;
    __syncthreads();
    if (tid == 0) {
        float s = 0.f;
#pragma unroll
        for (int i = 0; i < 16; ++i) s += sS[i];
        sSum = s;
    }
    __syncthreads();
    if (tid < 16) attw[(long)hb * 16 + tid] = sS[tid] / sSum;
}

// ---------------- src_value: DCT of the 16 sliding windows -------------------
// sv[b][n][f*10+d] = sum_v dct10[d][v] * src[b][n+v][f]
__global__ __launch_bounds__(512) void k_srcvalue(const float* __restrict__ src,
                                                  const float* __restrict__ dct10,
                                                  float* __restrict__ sv) {
    const int bn = blockIdx.x;  // b*16+n
    const int b = bn >> 4, n = bn & 15;
    __shared__ float W[1680];
    __shared__ float D[350];
    const float* s0 = src + (long)b * 2400 + n * 48;
    for (int i = threadIdx.x; i < 1680; i += 512) W[i] = s0[i];
    for (int i = threadIdx.x; i < 350; i += 512) D[i] = dct10[i];
    __syncthreads();
    if (threadIdx.x < 480) {
        const int f = threadIdx.x / 10, d = threadIdx.x % 10;
        float acc = 0.f;
#pragma unroll
        for (int v = 0; v < 35; ++v) acc = fmaf(D[d * 35 + v], W[v * 48 + f], acc);
        sv[(long)bn * 480 + threadIdx.x] = acc;  // threadIdx == f*10+d
    }
}

// ---------------- dct_att[h][b][j] = sum_k attw[h,b,k]*sv[b,k,j] -------------
__global__ __launch_bounds__(512) void k_dctatt(const float* __restrict__ attw,
                                                const float* __restrict__ sv,
                                                float* __restrict__ datt) {
    const int hb = blockIdx.x;
    const int b = hb & 255;
    __shared__ float aw[16];
    if (threadIdx.x < 16) aw[threadIdx.x] = attw[(long)hb * 16 + threadIdx.x];
    __syncthreads();
    if (threadIdx.x < 480) {
        float acc = 0.f;
#pragma unroll
        for (int k = 0; k < 16; ++k)
            acc = fmaf(aw[k], sv[((long)b * 16 + k) * 480 + threadIdx.x], acc);
        datt[(long)hb * 480 + threadIdx.x] = acc;
    }
}

// ---------------- dct_in[:, :, 0:10] : DCT of gathered input -----------------
// rows v<10 are src times 40..49; rows v>=10 all equal src time 49.
__global__ __launch_bounds__(512) void k_dctin1(const float* __restrict__ src,
                                                const float* __restrict__ dct10,
                                                float* __restrict__ dctin) {
    const int b = blockIdx.x;
    __shared__ float G[480];
    __shared__ float D[350];
    const float* s0 = src + (long)b * 2400 + 40 * 48;
    if (threadIdx.x < 480) G[threadIdx.x] = s0[threadIdx.x];
    for (int i = threadIdx.x; i < 350; i += 512) D[i] = dct10[i];
    __syncthreads();
    if (threadIdx.x < 480) {
        const int f = threadIdx.x / 10, d = threadIdx.x % 10;
        float acc = 0.f;
#pragma unroll
        for (int v = 0; v < 10; ++v) acc = fmaf(D[d * 35 + v], G[v * 48 + f], acc);
        float cs = 0.f;
#pragma unroll
        for (int v = 10; v < 35; ++v) cs += D[d * 35 + v];
        acc = fmaf(cs, G[9 * 48 + f], acc);
        dctin[(long)b * 960 + f * 20 + d] = acc;
    }
}

// ---------------- att_lin into dct_in[:, :, 10:20] ---------------------------
__global__ __launch_bounds__(512) void k_attlin(const float* __restrict__ datt,
                                                const float* __restrict__ lw,
                                                const float* __restrict__ lb,
                                                float* __restrict__ dctin) {
    const int b = blockIdx.x;
    __shared__ float L[1920];  // [h][f*10+d]
    for (int i = threadIdx.x; i < 1920; i += 512) {
        const int h = i / 480, j = i % 480;
        L[i] = datt[((long)h * 256 + b) * 480 + j];
    }
    __syncthreads();
    if (threadIdx.x < 480) {
        const int n = threadIdx.x / 10, d = threadIdx.x % 10;
        float acc = lb[n];
#pragma unroll
        for (int h = 0; h < 4; ++h)
#pragma unroll
            for (int f = 0; f < 48; ++f)
                acc = fmaf(lw[n * 192 + h * 48 + f], L[h * 480 + f * 10 + d], acc);
        dctin[(long)b * 960 + n * 20 + 10 + d] = acc;
    }
}

// ---------------- GCN second half: Y = tanh((att @ T + b)*s) (+res) ----------
__global__ __launch_bounds__(256) void gc_part2(const float* __restrict__ T,
                                                const float* __restrict__ att,
                                                const float* __restrict__ bias,
                                                const float* __restrict__ res,
                                                float* __restrict__ Y) {
    const int b = blockIdx.y;
    const int f = blockIdx.x * 256 + threadIdx.x;
    __shared__ float aS[2304];
    for (int i = threadIdx.x; i < 2304; i += 256) aS[i] = att[i];
    __syncthreads();
    float acc[48];
#pragma unroll
    for (int n = 0; n < 48; ++n) acc[n] = 0.f;
    const float* Tb = T + (long)b * 48 * 512 + f;
    for (int m = 0; m < 48; ++m) {
        const float tv = Tb[(long)m * 512];
#pragma unroll
        for (int n = 0; n < 48; ++n) acc[n] = fmaf(aS[n * 48 + m], tv, acc[n]);
    }
    const float bf = bias[f];
    float* Yb = Y + (long)b * 48 * 512 + f;
    const float* Rb = res ? res + (long)b * 48 * 512 + f : nullptr;
#pragma unroll
    for (int n = 0; n < 48; ++n) {
        float v = tanhf((acc[n] + bf) * BN_SCALE_F);
        if (Rb) v += Rb[(long)n * 512];
        Yb[(long)n * 512] = v;
    }
}

// ---------------- t2 = y @ gc_out_w  (256,48,512)x(512,20) -------------------
__global__ __launch_bounds__(960) void k_ygow(const float* __restrict__ Y,
                                              const float* __restrict__ gow,
                                              float* __restrict__ T2) {
    const int b = blockIdx.x;
    __shared__ float G[10240];
    for (int i = threadIdx.x; i < 10240; i += 960) G[i] = gow[i];
    __syncthreads();
    const int m = threadIdx.x / 20, dd = threadIdx.x % 20;
    const float* Yr = Y + ((long)b * 48 + m) * 512;
    float acc = 0.f;
    for (int k = 0; k < 512; ++k) acc = fmaf(Yr[k], G[k * 20 + dd], acc);
    T2[(long)b * 960 + threadIdx.x] = acc;
}

// ---------------- dct_out = goa @ t2 + gob + dct_in --------------------------
__global__ __launch_bounds__(960) void k_gcout2(const float* __restrict__ T2,
                                                const float* __restrict__ goa,
                                                const float* __restrict__ gob,
                                                const float* __restrict__ dctin,
                                                float* __restrict__ dout) {
    const int b = blockIdx.x;
    __shared__ float aS[2304];
    __shared__ float tS[960];
    for (int i = threadIdx.x; i < 2304; i += 960) aS[i] = goa[i];
    tS[threadIdx.x] = T2[(long)b * 960 + threadIdx.x];
    __syncthreads();
    const int n = threadIdx.x / 20, dd = threadIdx.x % 20;
    float acc = gob[dd] + dctin[(long)b * 960 + threadIdx.x];
#pragma unroll
    for (int m = 0; m < 48; ++m) acc = fmaf(aS[n * 48 + m], tS[m * 20 + dd], acc);
    dout[(long)b * 960 + threadIdx.x] = acc;
}

// ---------------- final iDCT: out[b][v][n] = sum_d dct10[d][v]*dout[b][n][d] -
__global__ __launch_bounds__(512) void k_idct(const float* __restrict__ dout,
                                              const float* __restrict__ dct10,
                                              float* __restrict__ out) {
    const int b = blockIdx.x;
    __shared__ float dS[960];
    __shared__ float D[350];
    for (int i = threadIdx.x; i < 960; i += 512) dS[i] = dout[(long)b * 960 + i];
    for (int i = threadIdx.x; i < 350; i += 512) D[i] = dct10[i];
    __syncthreads();
    for (int e = threadIdx.x; e < 1680; e += 512) {
        const int v = e / 48, n = e % 48;
        float acc = 0.f;
#pragma unroll
        for (int d = 0; d < 10; ++d) acc = fmaf(D[d * 35 + v], dS[n * 20 + d], acc);
        out[(long)b * 1680 + e] = acc;
    }
}

// ---------------------------------------------------------------------------
// Workspace layout (float offsets). Conv-phase pool is reused by the GCN.
// ---------------------------------------------------------------------------
static constexpr long O_DCT10 = 0;                      // 350 (pad 384)
static constexpr long O_ATTW = 384;                     // 4*256*16
static constexpr long O_QH = O_ATTW + 16384;            // 4*256*512
static constexpr long O_DCTIN = O_QH + 524288;          // 256*48*20
static constexpr long O_DCTOUT = O_DCTIN + 245760;      // 256*48*20
static constexpr long O_SRCVAL = O_DCTOUT + 245760;     // 256*16*480
static constexpr long O_KEYH = O_SRCVAL + 1966080;      // 4*256*16*512
static constexpr long O_POOL = O_KEYH + 8388608;
// conv phase (inside pool)
static constexpr long P_W1TQ = 0;                       // 589824
static constexpr long P_W1TK = 589824;                  // 589824
static constexpr long P_W2TQ = 1179648;                 // 5242880
static constexpr long P_W2TK = 6422528;                 // 5242880
static constexpr long P_R1K = 11665408;                 // 4*256*20*512
static constexpr long P_R1Q = 22151168;                 // 4*256*5*512
// att phase (pool reuse)
static constexpr long P_DCTATT = 0;                     // 4*256*480
// GCN phase (pool reuse)
static constexpr long P_YA = 0;                         // 256*48*512
static constexpr long P_YB = 6291456;
static constexpr long P_T = 12582912;

extern "C" void kernel_launch(void* const* d_in, const int* in_sizes, int n_in,
                              void* d_out, int out_size, void* d_ws,
                              size_t ws_size, hipStream_t stream) {
    const float* src = (const float*)d_in[0];
    const float* cq1 = (const float*)d_in[1];
    const float* cq2 = (const float*)d_in[2];
    const float* ck1 = (const float*)d_in[3];
    const float* ck2 = (const float*)d_in[4];
    const float* lw = (const float*)d_in[5];
    const float* lb = (const float*)d_in[6];
    const float* giw = (const float*)d_in[7];
    const float* gia = (const float*)d_in[8];
    const float* gib = (const float*)d_in[9];
    const float* gbw = (const float*)d_in[10];
    const float* gba = (const float*)d_in[11];
    const float* gbb = (const float*)d_in[12];
    const float* gow = (const float*)d_in[13];
    const float* goa = (const float*)d_in[14];
    const float* gob = (const float*)d_in[15];
    float* out = (float*)d_out;
    float* ws = (float*)d_ws;
    float* pool = ws + O_POOL;

    k_dct<<<2, 256, 0, stream>>>(ws + O_DCT10);
    k_trw1<<<(589824 + 255) / 256, 256, 0, stream>>>(cq1, pool + P_W1TQ);
    k_trw1<<<(589824 + 255) / 256, 256, 0, stream>>>(ck1, pool + P_W1TK);
    k_trw2<<<(5242880 + 255) / 256, 256, 0, stream>>>(cq2, pool + P_W2TQ);
    k_trw2<<<(5242880 + 255) / 256, 256, 0, stream>>>(ck2, pool + P_W2TK);

    // conv1: K-branch (t=0..19, toff=0) and Q-branch (t=0..4, toff=40)
    gemm64<B_SRC, true, true><<<dim3(5120 / 64, 8, 4), 256, 0, stream>>>(
        pool + P_W1TK, src, pool + P_R1K, 512, 5120, 288, 20, 0, 512L * 288,
        0L, 5120L * 512);
    gemm64<B_SRC, true, true><<<dim3(1280 / 64, 8, 4), 256, 0, stream>>>(
        pool + P_W1TQ, src, pool + P_R1Q, 512, 1280, 288, 5, 40, 512L * 288,
        0L, 1280L * 512);
    // conv2: K -> keyh[h][b][t][o], Q -> qh[h][b][o]
    gemm64<B_R1K, true, true><<<dim3(4096 / 64, 8, 4), 256, 0, stream>>>(
        pool + P_W2TK, pool + P_R1K, ws + O_KEYH, 512, 4096, 2560, 0, 0,
        512L * 2560, 2621440L, 2097152L);
    gemm64<B_R1Q, true, true><<<dim3(256 / 64, 8, 4), 256, 0, stream>>>(
        pool + P_W2TQ, pool + P_R1Q, ws + O_QH, 512, 256, 2560, 0, 0,
        512L * 2560, 655360L, 131072L);

    k_score<<<1024, 256, 0, stream>>>(ws + O_QH, ws + O_KEYH, ws + O_ATTW);
    k_srcvalue<<<4096, 512, 0, stream>>>(src, ws + O_DCT10, ws + O_SRCVAL);
    k_dctatt<<<1024, 512, 0, stream>>>(ws + O_ATTW, ws + O_SRCVAL,
                                       pool + P_DCTATT);
    k_dctin1<<<256, 512, 0, stream>>>(src, ws + O_DCT10, ws + O_DCTIN);
    k_attlin<<<256, 512, 0, stream>>>(pool + P_DCTATT, lw, lb, ws + O_DCTIN);

    // ---- GCN ----
    // gc_in: T = dct_in @ giw (K=20), y0 = tanh((gia@T + gib)*s) -> YA
    gemm64<B_PLAIN, false, false><<<dim3(192, 8, 1), 256, 0, stream>>>(
        giw, ws + O_DCTIN, pool + P_T, 512, 12288, 20, 0, 0, 0L, 0L, 0L);
    gc_part2<<<dim3(2, 256), 256, 0, stream>>>(pool + P_T, gia, gib, nullptr,
                                               pool + P_YA);
    // s=0, j=0: YA -> YB
    gemm64<B_PLAIN, false, false><<<dim3(192, 8, 1), 256, 0, stream>>>(
        gbw + 0L * 262144, pool + P_YA, pool + P_T, 512, 12288, 512, 0, 0, 0L,
        0L, 0L);
    gc_part2<<<dim3(2, 256), 256, 0, stream>>>(pool + P_T, gba + 0 * 2304,
                                               gbb + 0 * 512, nullptr,
                                               pool + P_YB);
    // s=0, j=1: YB -> YB (+res YA)
    gemm64<B_PLAIN, false, false><<<dim3(192, 8, 1), 256, 0, stream>>>(
        gbw + 1L * 262144, pool + P_YB, pool + P_T, 512, 12288, 512, 0, 0, 0L,
        0L, 0L);
    gc_part2<<<dim3(2, 256), 256, 0, stream>>>(pool + P_T, gba + 1 * 2304,
                                               gbb + 1 * 512, pool + P_YA,
                                               pool + P_YB);
    // s=1, j=0: YB -> YA
    gemm64<B_PLAIN, false, false><<<dim3(192, 8, 1), 256, 0, stream>>>(
        gbw + 2L * 262144, pool + P_YB, pool + P_T, 512, 12288, 512, 0, 0, 0L,
        0L, 0L);
    gc_part2<<<dim3(2, 256), 256, 0, stream>>>(pool + P_T, gba + 2 * 2304,
                                               gbb + 2 * 512, nullptr,
                                               pool + P_YA);
    // s=1, j=1: YA -> YA (+res YB)
    gemm64<B_PLAIN, false, false><<<dim3(192, 8, 1), 256, 0, stream>>>(
        gbw + 3L * 262144, pool + P_YA, pool + P_T, 512, 12288, 512, 0, 0, 0L,
        0L, 0L);
    gc_part2<<<dim3(2, 256), 256, 0, stream>>>(pool + P_T, gba + 3 * 2304,
                                               gbb + 3 * 512, pool + P_YB,
                                               pool + P_YA);

    // gc_out + residual dct_in, then iDCT
    k_ygow<<<256, 960, 0, stream>>>(pool + P_YA, gow, pool + P_T);
    k_gcout2<<<256, 960, 0, stream>>>(pool + P_T, goa, gob, ws + O_DCTIN,
                                      ws + O_DCTOUT);
    k_idct<<<256, 512, 0, stream>>>(ws + O_DCTOUT, ws + O_DCT10, out);
}

// Round 4
// 711.450 us; speedup vs baseline: 2.3842x; 2.3842x over previous
//
#include <hip/hip_runtime.h>
#include <math.h>

// ---------------------------------------------------------------------------
// Problem constants (bs=256, in_feat=48, d_model=512, dct_n=10, input_n=50,
// output_n=25, KERNEL=10, HEADS=4, vl=35, vn=16)
// ---------------------------------------------------------------------------
static constexpr float BN_SCALE_F = 0.9999950000374997f;

typedef __bf16 bf16;
typedef bf16 bf16x8 __attribute__((ext_vector_type(8)));
typedef bf16 bf16x4 __attribute__((ext_vector_type(4)));
typedef float floatx4 __attribute__((ext_vector_type(4)));

#define GLOBAL_AS __attribute__((address_space(1)))
#define LDS_AS __attribute__((address_space(3)))

// ---------------- DCT matrix (rows 0..9 of the 35x35 orthonormal DCT-II) ----
__global__ void k_dct(float* __restrict__ d) {
    int id = blockIdx.x * blockDim.x + threadIdx.x;
    if (id < 350) {
        int k = id / 35, i = id % 35;
        double w = (k == 0) ? sqrt(1.0 / 35.0) : sqrt(2.0 / 35.0);
        d[id] = (float)(w * cos(3.14159265358979323846 * (i + 0.5) * k / 35.0));
    }
}

// ---------------- conversions / weight transposes (fp32 -> bf16) ------------
// src (256*2400) -> bf16, with 256-elem zero slack for conv1-Q overread
__global__ void k_cvtsrc(const float* __restrict__ s, bf16* __restrict__ o) {
    int id = blockIdx.x * 256 + threadIdx.x;
    if (id < 614656) o[id] = (bf16)(id < 614400 ? s[id] : 0.f);
}
// w1[h][o][i][k] (4,512,48,6) -> w1t[ho][c=k*48+i] K-padded to 320, *1e-3
__global__ void k_trw1(const float* __restrict__ w, bf16* __restrict__ wt) {
    int id = blockIdx.x * 256 + threadIdx.x;
    if (id < 4 * 512 * 320) {
        int ho = id / 320, c = id % 320;
        float v = (c < 288) ? w[(long)ho * 288 + (c % 48) * 6 + (c / 48)] * 1e-3f : 0.f;
        wt[id] = (bf16)v;
    }
}
// w2[h][o][i][k] (4,512,512,5) -> w2t[ho][c=k*512+i]
__global__ void k_trw2(const float* __restrict__ w, bf16* __restrict__ wt) {
    int id = blockIdx.x * 256 + threadIdx.x;
    if (id < 4 * 512 * 2560) {
        int ho = id / 2560, c = id % 2560;
        wt[id] = (bf16)w[(long)ho * 2560 + (c % 512) * 5 + (c / 512)];
    }
}
// gbw[s][k][m] (4,512,512) -> gbwt[s][m][k] bf16
__global__ void k_trgw(const float* __restrict__ w, bf16* __restrict__ wt) {
    int id = blockIdx.x * 256 + threadIdx.x;
    if (id < 4 * 512 * 512) {
        int s = id >> 18, r = id & 262143;
        int m = r >> 9, k = r & 511;
        wt[id] = (bf16)w[(long)s * 262144 + k * 512 + m];
    }
}

// ---------------- bf16 MFMA NT GEMM -----------------------------------------
// C[n*M+m] = sum_k A[m][k] * Brow(n)[k]; A row-major MxK bf16 (K mult of 64),
// B rows are K-contiguous bf16 slices whose base depends on BMODE.
// 128x128 tile, BK=64, 256 threads (4 waves, each 64x64 = 4x4 MFMA tiles).
// Staging via global_load_lds(16B) with XOR chunk swizzle (chunk ^= row&7) so
// LDS stays lane-contiguous for the DMA AND ds_read_b128 is 2-way (free).
enum { BM_SRC = 0, BM_R1K = 1, BM_PLAIN = 3 };

template <int BMODE, bool RELU, bool OUTBF>
__global__ __launch_bounds__(256) void mgemm(
    const bf16* __restrict__ Ab, const bf16* __restrict__ Bb,
    void* __restrict__ Cb, const int M, const int N, const int K,
    const int NT, const int toff, const long aStr, const long bStr,
    const long cStr) {
    __shared__ bf16 As[128 * 64];
    __shared__ bf16 Bs[128 * 64];
    const int tid = threadIdx.x;
    const int wave = tid >> 6;
    const int lane = tid & 63;
    const int wm = (wave & 1) << 6;
    const int wn = (wave >> 1) << 6;
    const int m0 = blockIdx.y * 128;
    const int n0 = blockIdx.x * 128;
    const bf16* A = Ab + (long)blockIdx.z * aStr;
    const bf16* B = Bb + (long)blockIdx.z * bStr;

    // staging: lane covers row (lane>>3) of each 8-row group, LDS chunk lane&7,
    // fetching global chunk (lane&7)^(lane>>3)  => LDS[r][c] = G[r][c^(r&7)]
    const int srow = lane >> 3;
    const int gch = (lane & 7) ^ srow;
    const bf16* aptr[4];
    const bf16* bptr[4];
#pragma unroll
    for (int i = 0; i < 4; ++i) {
        const int ar = wave * 32 + i * 8 + srow;
        aptr[i] = A + (long)(m0 + ar) * K + gch * 8;
        const int n = n0 + ar;
        long bbase;
        if (BMODE == BM_SRC)
            bbase = (long)(n / NT) * 2400 + (long)((n % NT) + toff) * 48;
        else if (BMODE == BM_R1K)
            bbase = (long)((n >> 4) * 20 + (n & 15)) * 512;
        else
            bbase = (long)n * K;
        bptr[i] = B + bbase + gch * 8;
    }
    const int ldsOff = wave * 32 * 64;  // elements; + i*8*64 per load

    floatx4 acc[4][4];
#pragma unroll
    for (int j = 0; j < 4; ++j)
#pragma unroll
        for (int i = 0; i < 4; ++i) acc[j][i] = (floatx4){0.f, 0.f, 0.f, 0.f};

    const int fr = lane & 15;  // fragment row (m or n within 16)
    const int fq = lane >> 4;  // quad (k chunk within 32-k step)
    const int fx = lane & 7;   // xor key (== row&7 for rows fr mod 16)

    for (int k0 = 0; k0 < K; k0 += 64) {
#pragma unroll
        for (int i = 0; i < 4; ++i) {
            __builtin_amdgcn_global_load_lds(
                (const GLOBAL_AS void*)(aptr[i] + k0),
                (LDS_AS void*)(As + ldsOff + i * 512), 16, 0, 0);
            __builtin_amdgcn_global_load_lds(
                (const GLOBAL_AS void*)(bptr[i] + k0),
                (LDS_AS void*)(Bs + ldsOff + i * 512), 16, 0, 0);
        }
        __syncthreads();
#pragma unroll
        for (int kk = 0; kk < 2; ++kk) {
            bf16x8 af[4], bfr[4];
#pragma unroll
            for (int im = 0; im < 4; ++im)
                af[im] = *(const bf16x8*)(As + (wm + im * 16 + fr) * 64 +
                                          ((((kk << 2) + fq) ^ fx) << 3));
#pragma unroll
            for (int in = 0; in < 4; ++in)
                bfr[in] = *(const bf16x8*)(Bs + (wn + in * 16 + fr) * 64 +
                                           ((((kk << 2) + fq) ^ fx) << 3));
#pragma unroll
            for (int in = 0; in < 4; ++in)
#pragma unroll
                for (int im = 0; im < 4; ++im)
                    acc[in][im] = __builtin_amdgcn_mfma_f32_16x16x32_bf16(
                        af[im], bfr[in], acc[in][im], 0, 0, 0);
        }
        __syncthreads();
    }
    // epilogue: D[m=(lane>>4)*4+r][n=lane&15] -> C[n*M+m] (m-contiguous x4)
#pragma unroll
    for (int in = 0; in < 4; ++in) {
        const long n = n0 + wn + in * 16 + fr;
#pragma unroll
        for (int im = 0; im < 4; ++im) {
            floatx4 v = acc[in][im];
            if (RELU) {
                v.x = fmaxf(v.x, 0.f);
                v.y = fmaxf(v.y, 0.f);
                v.z = fmaxf(v.z, 0.f);
                v.w = fmaxf(v.w, 0.f);
            }
            const long m = m0 + wm + im * 16 + (fq << 2);
            if (OUTBF) {
                bf16* C = (bf16*)Cb + (long)blockIdx.z * cStr + n * M + m;
                bf16x4 ov;
                ov.x = (bf16)v.x;
                ov.y = (bf16)v.y;
                ov.z = (bf16)v.z;
                ov.w = (bf16)v.w;
                *(bf16x4*)C = ov;
            } else {
                float* C = (float*)Cb + (long)blockIdx.z * cStr + n * M + m;
                *(floatx4*)C = v;
            }
        }
    }
}

// ---------------- fp32 tiled GEMM (kept only for gc_in, K=20) ----------------
__global__ __launch_bounds__(256) void gemm64(
    const float* __restrict__ Ab, const float* __restrict__ Bb,
    float* __restrict__ Cb, const int M, const int N, const int K) {
    __shared__ float As[16][68];
    __shared__ float Bs[16][68];
    const int tid = threadIdx.x;
    const int n0 = blockIdx.x * 64;
    const int m0 = blockIdx.y * 64;
    const float* A = Ab;
    const float* B = Bb;
    float* C = Cb;

    const int brow = tid >> 2;
    const int bk4 = (tid & 3) << 2;
    long bbase = (long)(n0 + brow) * K;

    const int ak = tid >> 4;
    const int am4 = (tid & 15) << 2;
    const int tm = tid & 15;
    const int tn = tid >> 4;

    float acc[4][4];
#pragma unroll
    for (int j = 0; j < 4; ++j)
#pragma unroll
        for (int i = 0; i < 4; ++i) acc[j][i] = 0.f;

    for (int k0 = 0; k0 < K; k0 += 16) {
        {
            const int k = k0 + ak;
            float4 av = make_float4(0.f, 0.f, 0.f, 0.f);
            if (k < K) av = *(const float4*)(A + (long)k * M + m0 + am4);
            *(float4*)(&As[ak][am4]) = av;
        }
        {
            const int k = k0 + bk4;
            float4 bv;
            if (k + 3 < K)
                bv = *(const float4*)(B + bbase + k);
            else {
                bv.x = (k + 0 < K) ? B[bbase + k + 0] : 0.f;
                bv.y = (k + 1 < K) ? B[bbase + k + 1] : 0.f;
                bv.z = (k + 2 < K) ? B[bbase + k + 2] : 0.f;
                bv.w = (k + 3 < K) ? B[bbase + k + 3] : 0.f;
            }
            Bs[bk4 + 0][brow] = bv.x;
            Bs[bk4 + 1][brow] = bv.y;
            Bs[bk4 + 2][brow] = bv.z;
            Bs[bk4 + 3][brow] = bv.w;
        }
        __syncthreads();
#pragma unroll
        for (int kk = 0; kk < 16; ++kk) {
            const float4 a = *(const float4*)(&As[kk][tm << 2]);
            const float4 b = *(const float4*)(&Bs[kk][tn << 2]);
            const float av_[4] = {a.x, a.y, a.z, a.w};
            const float bv_[4] = {b.x, b.y, b.z, b.w};
#pragma unroll
            for (int j = 0; j < 4; ++j)
#pragma unroll
                for (int i = 0; i < 4; ++i)
                    acc[j][i] = fmaf(bv_[j], av_[i], acc[j][i]);
        }
        __syncthreads();
    }
#pragma unroll
    for (int j = 0; j < 4; ++j) {
        const long n = n0 + (tn << 2) + j;
        float4 v = make_float4(acc[j][0], acc[j][1], acc[j][2], acc[j][3]);
        *(float4*)(C + n * M + m0 + (tm << 2)) = v;
    }
}

// ---------------- attention scoring -----------------------------------------
__global__ __launch_bounds__(256) void k_score(const float* __restrict__ qh,
                                               const float* __restrict__ keyh,
                                               float* __restrict__ attw) {
    const int hb = blockIdx.x;  // h*256+b
    const int tid = threadIdx.x;
    __shared__ float qS[512];
    __shared__ float sS[16];
    __shared__ float sSum;
    const float* q = qh + (long)hb * 512;
    qS[tid] = q[tid];
    qS[tid + 256] = q[tid + 256];
    __syncthreads();
    const int t = tid >> 4;
    const int l = tid & 15;
    const float* krow = keyh + ((long)hb * 16 + t) * 512;
    float p = 0.f;
    for (int o = l; o < 512; o += 16) p = fmaf(qS[o], krow[o], p);
#pragma unroll
    for (int off = 8; off; off >>= 1) p += __shfl_down(p, off, 16);
    if (l == 0) sS[t] = p + 1e-15f;
    __syncthreads();
    if (tid == 0) {
        float s = 0.f;
#pragma unroll
        for (int i = 0; i < 16; ++i) s += sS[i];
        sSum = s;
    }
    __syncthreads();
    if (tid < 16) attw[(long)hb * 16 + tid] = sS[tid] / sSum;
}

// ---------------- src_value: DCT of the 16 sliding windows -------------------
__global__ __launch_bounds__(512) void k_srcvalue(const float* __restrict__ src,
                                                  const float* __restrict__ dct10,
                                                  float* __restrict__ sv) {
    const int bn = blockIdx.x;  // b*16+n
    const int b = bn >> 4, n = bn & 15;
    __shared__ float W[1680];
    __shared__ float D[350];
    const float* s0 = src + (long)b * 2400 + n * 48;
    for (int i = threadIdx.x; i < 1680; i += 512) W[i] = s0[i];
    for (int i = threadIdx.x; i < 350; i += 512) D[i] = dct10[i];
    __syncthreads();
    if (threadIdx.x < 480) {
        const int f = threadIdx.x / 10, d = threadIdx.x % 10;
        float acc = 0.f;
#pragma unroll
        for (int v = 0; v < 35; ++v) acc = fmaf(D[d * 35 + v], W[v * 48 + f], acc);
        sv[(long)bn * 480 + threadIdx.x] = acc;
    }
}

// ---------------- dct_att[h][b][j] = sum_k attw[h,b,k]*sv[b,k,j] -------------
__global__ __launch_bounds__(512) void k_dctatt(const float* __restrict__ attw,
                                                const float* __restrict__ sv,
                                                float* __restrict__ datt) {
    const int hb = blockIdx.x;
    const int b = hb & 255;
    __shared__ float aw[16];
    if (threadIdx.x < 16) aw[threadIdx.x] = attw[(long)hb * 16 + threadIdx.x];
    __syncthreads();
    if (threadIdx.x < 480) {
        float acc = 0.f;
#pragma unroll
        for (int k = 0; k < 16; ++k)
            acc = fmaf(aw[k], sv[((long)b * 16 + k) * 480 + threadIdx.x], acc);
        datt[(long)hb * 480 + threadIdx.x] = acc;
    }
}

// ---------------- dct_in[:, :, 0:10] -----------------------------------------
__global__ __launch_bounds__(512) void k_dctin1(const float* __restrict__ src,
                                                const float* __restrict__ dct10,
                                                float* __restrict__ dctin) {
    const int b = blockIdx.x;
    __shared__ float G[480];
    __shared__ float D[350];
    const float* s0 = src + (long)b * 2400 + 40 * 48;
    if (threadIdx.x < 480) G[threadIdx.x] = s0[threadIdx.x];
    for (int i = threadIdx.x; i < 350; i += 512) D[i] = dct10[i];
    __syncthreads();
    if (threadIdx.x < 480) {
        const int f = threadIdx.x / 10, d = threadIdx.x % 10;
        float acc = 0.f;
#pragma unroll
        for (int v = 0; v < 10; ++v) acc = fmaf(D[d * 35 + v], G[v * 48 + f], acc);
        float cs = 0.f;
#pragma unroll
        for (int v = 10; v < 35; ++v) cs += D[d * 35 + v];
        acc = fmaf(cs, G[9 * 48 + f], acc);
        dctin[(long)b * 960 + f * 20 + d] = acc;
    }
}

// ---------------- att_lin into dct_in[:, :, 10:20] ---------------------------
__global__ __launch_bounds__(512) void k_attlin(const float* __restrict__ datt,
                                                const float* __restrict__ lw,
                                                const float* __restrict__ lb,
                                                float* __restrict__ dctin) {
    const int b = blockIdx.x;
    __shared__ float L[1920];
    for (int i = threadIdx.x; i < 1920; i += 512) {
        const int h = i / 480, j = i % 480;
        L[i] = datt[((long)h * 256 + b) * 480 + j];
    }
    __syncthreads();
    if (threadIdx.x < 480) {
        const int n = threadIdx.x / 10, d = threadIdx.x % 10;
        float acc = lb[n];
#pragma unroll
        for (int h = 0; h < 4; ++h)
#pragma unroll
            for (int f = 0; f < 48; ++f)
                acc = fmaf(lw[n * 192 + h * 48 + f], L[h * 480 + f * 10 + d], acc);
        dctin[(long)b * 960 + n * 20 + 10 + d] = acc;
    }
}

// ---------------- GCN second half: Y = tanh((att @ T + b)*s) (+res) ----------
__global__ __launch_bounds__(256) void gc_part2(const float* __restrict__ T,
                                                const float* __restrict__ att,
                                                const float* __restrict__ bias,
                                                const bf16* __restrict__ res,
                                                bf16* __restrict__ Y) {
    const int b = blockIdx.y;
    const int f = blockIdx.x * 256 + threadIdx.x;
    __shared__ float aS[2304];
    for (int i = threadIdx.x; i < 2304; i += 256) aS[i] = att[i];
    __syncthreads();
    float acc[48];
#pragma unroll
    for (int n = 0; n < 48; ++n) acc[n] = 0.f;
    const float* Tb = T + (long)b * 48 * 512 + f;
    for (int m = 0; m < 48; ++m) {
        const float tv = Tb[(long)m * 512];
#pragma unroll
        for (int n = 0; n < 48; ++n) acc[n] = fmaf(aS[n * 48 + m], tv, acc[n]);
    }
    const float bf = bias[f];
    bf16* Yb = Y + (long)b * 48 * 512 + f;
    const bf16* Rb = res ? res + (long)b * 48 * 512 + f : nullptr;
#pragma unroll
    for (int n = 0; n < 48; ++n) {
        float v = tanhf((acc[n] + bf) * BN_SCALE_F);
        if (Rb) v += (float)Rb[(long)n * 512];
        Yb[(long)n * 512] = (bf16)v;
    }
}

// ---------------- t2 = y @ gc_out_w ------------------------------------------
__global__ __launch_bounds__(960) void k_ygow(const bf16* __restrict__ Y,
                                              const float* __restrict__ gow,
                                              float* __restrict__ T2) {
    const int b = blockIdx.x;
    __shared__ float G[10240];
    for (int i = threadIdx.x; i < 10240; i += 960) G[i] = gow[i];
    __syncthreads();
    const int m = threadIdx.x / 20, dd = threadIdx.x % 20;
    const bf16* Yr = Y + ((long)b * 48 + m) * 512;
    float acc = 0.f;
    for (int k = 0; k < 512; ++k) acc = fmaf((float)Yr[k], G[k * 20 + dd], acc);
    T2[(long)b * 960 + threadIdx.x] = acc;
}

// ---------------- dct_out = goa @ t2 + gob + dct_in --------------------------
__global__ __launch_bounds__(960) void k_gcout2(const float* __restrict__ T2,
                                                const float* __restrict__ goa,
                                                const float* __restrict__ gob,
                                                const float* __restrict__ dctin,
                                                float* __restrict__ dout) {
    const int b = blockIdx.x;
    __shared__ float aS[2304];
    __shared__ float tS[960];
    for (int i = threadIdx.x; i < 2304; i += 960) aS[i] = goa[i];
    tS[threadIdx.x] = T2[(long)b * 960 + threadIdx.x];
    __syncthreads();
    const int n = threadIdx.x / 20, dd = threadIdx.x % 20;
    float acc = gob[dd] + dctin[(long)b * 960 + threadIdx.x];
#pragma unroll
    for (int m = 0; m < 48; ++m) acc = fmaf(aS[n * 48 + m], tS[m * 20 + dd], acc);
    dout[(long)b * 960 + threadIdx.x] = acc;
}

// ---------------- final iDCT -------------------------------------------------
__global__ __launch_bounds__(512) void k_idct(const float* __restrict__ dout,
                                              const float* __restrict__ dct10,
                                              float* __restrict__ out) {
    const int b = blockIdx.x;
    __shared__ float dS[960];
    __shared__ float D[350];
    for (int i = threadIdx.x; i < 960; i += 512) dS[i] = dout[(long)b * 960 + i];
    for (int i = threadIdx.x; i < 350; i += 512) D[i] = dct10[i];
    __syncthreads();
    for (int e = threadIdx.x; e < 1680; e += 512) {
        const int v = e / 48, n = e % 48;
        float acc = 0.f;
#pragma unroll
        for (int d = 0; d < 10; ++d) acc = fmaf(D[d * 35 + v], dS[n * 20 + d], acc);
        out[(long)b * 1680 + e] = acc;
    }
}

// ---------------------------------------------------------------------------
// Workspace layout (BYTE offsets, all 16B-aligned). ~118 MB used.
// keyh (4*4096*512 fp32 = 33,554,432 B) ALIASES [WS_T, WS_T+33.5MB):
// it is dead before T (gc_in) or YA (first gc_part2) are written.
// Round-3 bug was keyh getting 8 MB (float-count reused as byte-count).
// ---------------------------------------------------------------------------
static constexpr size_t WS_DCT10 = 0;                          // 1536
static constexpr size_t WS_ATTW = 1536;                        // 65536
static constexpr size_t WS_QH = WS_ATTW + 65536;               // 2097152
static constexpr size_t WS_DCTIN = WS_QH + 2097152;            // 983040
static constexpr size_t WS_DCTOUT = WS_DCTIN + 983040;         // 983040
static constexpr size_t WS_SRCVAL = WS_DCTOUT + 983040;        // 7864320
static constexpr size_t WS_PAD0 = WS_SRCVAL + 7864320;         // 8388608 (unused)
static constexpr size_t WS_SRCBF = WS_PAD0 + 8388608;          // 1229824
static constexpr size_t WS_W1TQ = WS_SRCBF + 1229824;          // 1310720
static constexpr size_t WS_W1TK = WS_W1TQ + 1310720;           // 1310720
static constexpr size_t WS_W2TQ = WS_W1TK + 1310720;           // 10485760
static constexpr size_t WS_W2TK = WS_W2TQ + 10485760;          // 10485760
static constexpr size_t WS_GBWT = WS_W2TK + 10485760;          // 2097152
static constexpr size_t WS_R1K = WS_GBWT + 2097152;            // 20971520
static constexpr size_t WS_R1Q = WS_R1K + 20971520;            // 5242880
static constexpr size_t WS_T = WS_R1Q + 5242880;               // 25165824
static constexpr size_t WS_YA = WS_T + 25165824;               // 12582912
static constexpr size_t WS_YB = WS_YA + 12582912;              // 12582912
static constexpr size_t WS_DCTATT = WS_YB + 12582912;          // 1966080
static constexpr size_t WS_KEYH = WS_T;  // alias: 33554432 B <= T+YA extent

extern "C" void kernel_launch(void* const* d_in, const int* in_sizes, int n_in,
                              void* d_out, int out_size, void* d_ws,
                              size_t ws_size, hipStream_t stream) {
    const float* src = (const float*)d_in[0];
    const float* cq1 = (const float*)d_in[1];
    const float* cq2 = (const float*)d_in[2];
    const float* ck1 = (const float*)d_in[3];
    const float* ck2 = (const float*)d_in[4];
    const float* lw = (const float*)d_in[5];
    const float* lb = (const float*)d_in[6];
    const float* giw = (const float*)d_in[7];
    const float* gia = (const float*)d_in[8];
    const float* gib = (const float*)d_in[9];
    const float* gbw = (const float*)d_in[10];
    const float* gba = (const float*)d_in[11];
    const float* gbb = (const float*)d_in[12];
    const float* gow = (const float*)d_in[13];
    const float* goa = (const float*)d_in[14];
    const float* gob = (const float*)d_in[15];
    float* out = (float*)d_out;
    char* ws = (char*)d_ws;

    float* dct10 = (float*)(ws + WS_DCT10);
    float* attw = (float*)(ws + WS_ATTW);
    float* qh = (float*)(ws + WS_QH);
    float* dctin = (float*)(ws + WS_DCTIN);
    float* dctout = (float*)(ws + WS_DCTOUT);
    float* srcval = (float*)(ws + WS_SRCVAL);
    float* keyh = (float*)(ws + WS_KEYH);
    bf16* srcbf = (bf16*)(ws + WS_SRCBF);
    bf16* w1tq = (bf16*)(ws + WS_W1TQ);
    bf16* w1tk = (bf16*)(ws + WS_W1TK);
    bf16* w2tq = (bf16*)(ws + WS_W2TQ);
    bf16* w2tk = (bf16*)(ws + WS_W2TK);
    bf16* gbwt = (bf16*)(ws + WS_GBWT);
    bf16* r1k = (bf16*)(ws + WS_R1K);
    bf16* r1q = (bf16*)(ws + WS_R1Q);
    float* T = (float*)(ws + WS_T);
    bf16* ya = (bf16*)(ws + WS_YA);
    bf16* yb = (bf16*)(ws + WS_YB);
    float* dctatt = (float*)(ws + WS_DCTATT);

    k_dct<<<2, 256, 0, stream>>>(dct10);
    k_cvtsrc<<<2401, 256, 0, stream>>>(src, srcbf);
    k_trw1<<<2560, 256, 0, stream>>>(cq1, w1tq);
    k_trw1<<<2560, 256, 0, stream>>>(ck1, w1tk);
    k_trw2<<<20480, 256, 0, stream>>>(cq2, w2tq);
    k_trw2<<<20480, 256, 0, stream>>>(ck2, w2tk);
    k_trgw<<<4096, 256, 0, stream>>>(gbw, gbwt);

    // conv1 (K padded 288->320): K-branch N=5120 (t0..19), Q-branch N=1280 (t40..44)
    mgemm<BM_SRC, true, true><<<dim3(40, 4, 4), 256, 0, stream>>>(
        w1tk, srcbf, r1k, 512, 5120, 320, 20, 0, 512L * 320, 0L, 5120L * 512);
    mgemm<BM_SRC, true, true><<<dim3(10, 4, 4), 256, 0, stream>>>(
        w1tq, srcbf, r1q, 512, 1280, 320, 5, 40, 512L * 320, 0L, 1280L * 512);
    // conv2: K -> keyh[h][b*16+t][o] fp32, Q -> qh[h][b][o] fp32
    mgemm<BM_R1K, true, false><<<dim3(32, 4, 4), 256, 0, stream>>>(
        w2tk, r1k, keyh, 512, 4096, 2560, 0, 0, 512L * 2560, 2621440L, 2097152L);
    mgemm<BM_PLAIN, true, false><<<dim3(2, 4, 4), 256, 0, stream>>>(
        w2tq, r1q, qh, 512, 256, 2560, 0, 0, 512L * 2560, 655360L, 131072L);

    k_score<<<1024, 256, 0, stream>>>(qh, keyh, attw);
    k_srcvalue<<<4096, 512, 0, stream>>>(src, dct10, srcval);
    k_dctatt<<<1024, 512, 0, stream>>>(attw, srcval, dctatt);
    k_dctin1<<<256, 512, 0, stream>>>(src, dct10, dctin);
    k_attlin<<<256, 512, 0, stream>>>(dctatt, lw, lb, dctin);

    // ---- GCN ----  (T/YA writes begin only after k_score consumed keyh)
    // gc_in: T = dct_in @ giw (K=20, fp32), y0 = tanh((gia@T+gib)*s) -> YA(bf16)
    gemm64<<<dim3(192, 8, 1), 256, 0, stream>>>(giw, dctin, T, 512, 12288, 20);
    gc_part2<<<dim3(2, 256), 256, 0, stream>>>(T, gia, gib, (const bf16*)nullptr, ya);
    // s=0,j=0: YA -> YB
    mgemm<BM_PLAIN, false, false><<<dim3(96, 4, 1), 256, 0, stream>>>(
        gbwt + 0L * 262144, ya, T, 512, 12288, 512, 0, 0, 0L, 0L, 0L);
    gc_part2<<<dim3(2, 256), 256, 0, stream>>>(T, gba + 0 * 2304, gbb + 0 * 512,
                                               (const bf16*)nullptr, yb);
    // s=0,j=1: YB -> YB (+res YA)
    mgemm<BM_PLAIN, false, false><<<dim3(96, 4, 1), 256, 0, stream>>>(
        gbwt + 1L * 262144, yb, T, 512, 12288, 512, 0, 0, 0L, 0L, 0L);
    gc_part2<<<dim3(2, 256), 256, 0, stream>>>(T, gba + 1 * 2304, gbb + 1 * 512,
                                               ya, yb);
    // s=1,j=0: YB -> YA
    mgemm<BM_PLAIN, false, false><<<dim3(96, 4, 1), 256, 0, stream>>>(
        gbwt + 2L * 262144, yb, T, 512, 12288, 512, 0, 0, 0L, 0L, 0L);
    gc_part2<<<dim3(2, 256), 256, 0, stream>>>(T, gba + 2 * 2304, gbb + 2 * 512,
                                               (const bf16*)nullptr, ya);
    // s=1,j=1: YA -> YA (+res YB)
    mgemm<BM_PLAIN, false, false><<<dim3(96, 4, 1), 256, 0, stream>>>(
        gbwt + 3L * 262144, ya, T, 512, 12288, 512, 0, 0, 0L, 0L, 0L);
    gc_part2<<<dim3(2, 256), 256, 0, stream>>>(T, gba + 3 * 2304, gbb + 3 * 512,
                                               yb, ya);

    // gc_out + residual dct_in, then iDCT
    k_ygow<<<256, 960, 0, stream>>>(ya, gow, T);
    k_gcout2<<<256, 960, 0, stream>>>(T, goa, gob, dctin, dctout);
    k_idct<<<256, 512, 0, stream>>>(dctout, dct10, out);
}

// Round 5
// 530.031 us; speedup vs baseline: 3.2003x; 1.3423x over previous
//
#include <hip/hip_runtime.h>
#include <math.h>

// ---------------------------------------------------------------------------
// Problem constants (bs=256, in_feat=48, d_model=512, dct_n=10, input_n=50,
// output_n=25, KERNEL=10, HEADS=4, vl=35, vn=16)
// ---------------------------------------------------------------------------
static constexpr float BN_SCALE_F = 0.9999950000374997f;

typedef __bf16 bf16;
typedef bf16 bf16x8 __attribute__((ext_vector_type(8)));
typedef bf16 bf16x4 __attribute__((ext_vector_type(4)));
typedef float floatx4 __attribute__((ext_vector_type(4)));

#define GLOBAL_AS __attribute__((address_space(1)))
#define LDS_AS __attribute__((address_space(3)))

// ---------------- DCT matrix (rows 0..9 of the 35x35 orthonormal DCT-II) ----
__global__ void k_dct(float* __restrict__ d) {
    int id = blockIdx.x * blockDim.x + threadIdx.x;
    if (id < 350) {
        int k = id / 35, i = id % 35;
        double w = (k == 0) ? sqrt(1.0 / 35.0) : sqrt(2.0 / 35.0);
        d[id] = (float)(w * cos(3.14159265358979323846 * (i + 0.5) * k / 35.0));
    }
}

// ---------------- conversions / weight transposes (fp32 -> bf16) ------------
__global__ void k_cvtsrc(const float* __restrict__ s, bf16* __restrict__ o) {
    int id = blockIdx.x * 256 + threadIdx.x;
    if (id < 614656) o[id] = (bf16)(id < 614400 ? s[id] : 0.f);
}
// w1[h][o][i][k] (4,512,48,6) -> w1t[ho][c=k*48+i] K-padded to 320, *1e-3
__global__ void k_trw1(const float* __restrict__ w, bf16* __restrict__ wt) {
    int id = blockIdx.x * 256 + threadIdx.x;
    if (id < 4 * 512 * 320) {
        int ho = id / 320, c = id % 320;
        float v = (c < 288) ? w[(long)ho * 288 + (c % 48) * 6 + (c / 48)] * 1e-3f : 0.f;
        wt[id] = (bf16)v;
    }
}
// w2[h][o][i][k] (4,512,512,5) -> w2t[ho][c=k*512+i]
__global__ void k_trw2(const float* __restrict__ w, bf16* __restrict__ wt) {
    int id = blockIdx.x * 256 + threadIdx.x;
    if (id < 4 * 512 * 2560) {
        int ho = id / 2560, c = id % 2560;
        wt[id] = (bf16)w[(long)ho * 2560 + (c % 512) * 5 + (c / 512)];
    }
}
// gbw[s][k][m] (4,512,512) -> gbwt[s][m][k] bf16
__global__ void k_trgw(const float* __restrict__ w, bf16* __restrict__ wt) {
    int id = blockIdx.x * 256 + threadIdx.x;
    if (id < 4 * 512 * 512) {
        int s = id >> 18, r = id & 262143;
        int m = r >> 9, k = r & 511;
        wt[id] = (bf16)w[(long)s * 262144 + k * 512 + m];
    }
}
// giw (20,512) -> giwP[f][k64] bf16, K padded 20->64
__global__ void k_trgiw(const float* __restrict__ giw, bf16* __restrict__ gp) {
    int id = blockIdx.x * 256 + threadIdx.x;
    if (id < 512 * 64) {
        int f = id >> 6, k = id & 63;
        gp[id] = (bf16)(k < 20 ? giw[k * 512 + f] : 0.f);
    }
}

// ---------------- bf16 MFMA NT GEMM with fused epilogue ----------------------
// C[n*M+m] = sum_k A[m][k] * Brow(n)[k]; A row-major MxK bf16 (K mult of 64),
// B rows are K-contiguous bf16 slices whose base depends on BMODE.
// 128x128 tile, BK=64, 256 threads. global_load_lds(16B) + XOR chunk swizzle.
// EPI: 0 = fp32 out; 1 = relu fp32; 2 = relu bf16;
//      3 = bf16 tanh((acc+bias[m])*BN) (+res[n*M+m] if res!=null)
enum { BM_SRC = 0, BM_R1K = 1, BM_PLAIN = 3 };
enum { EPI_F32 = 0, EPI_RELU_F32 = 1, EPI_RELU_BF16 = 2, EPI_TANH_BF16 = 3 };

template <int BMODE, int EPI>
__global__ __launch_bounds__(256) void mgemm(
    const bf16* __restrict__ Ab, const bf16* __restrict__ Bb,
    void* __restrict__ Cb, const float* __restrict__ bias,
    const bf16* __restrict__ res, const int M, const int N, const int K,
    const int NT, const int toff, const long aStr, const long bStr,
    const long cStr) {
    __shared__ bf16 As[128 * 64];
    __shared__ bf16 Bs[128 * 64];
    const int tid = threadIdx.x;
    const int wave = tid >> 6;
    const int lane = tid & 63;
    const int wm = (wave & 1) << 6;
    const int wn = (wave >> 1) << 6;
    const int m0 = blockIdx.y * 128;
    const int n0 = blockIdx.x * 128;
    const bf16* A = Ab + (long)blockIdx.z * aStr;
    const bf16* B = Bb + (long)blockIdx.z * bStr;

    const int srow = lane >> 3;
    const int gch = (lane & 7) ^ srow;
    const bf16* aptr[4];
    const bf16* bptr[4];
#pragma unroll
    for (int i = 0; i < 4; ++i) {
        const int ar = wave * 32 + i * 8 + srow;
        aptr[i] = A + (long)(m0 + ar) * K + gch * 8;
        const int n = n0 + ar;
        long bbase;
        if (BMODE == BM_SRC)
            bbase = (long)(n / NT) * 2400 + (long)((n % NT) + toff) * 48;
        else if (BMODE == BM_R1K)
            bbase = (long)((n >> 4) * 20 + (n & 15)) * 512;
        else
            bbase = (long)n * K;
        bptr[i] = B + bbase + gch * 8;
    }
    const int ldsOff = wave * 32 * 64;

    floatx4 acc[4][4];
#pragma unroll
    for (int j = 0; j < 4; ++j)
#pragma unroll
        for (int i = 0; i < 4; ++i) acc[j][i] = (floatx4){0.f, 0.f, 0.f, 0.f};

    const int fr = lane & 15;
    const int fq = lane >> 4;
    const int fx = lane & 7;

    for (int k0 = 0; k0 < K; k0 += 64) {
#pragma unroll
        for (int i = 0; i < 4; ++i) {
            __builtin_amdgcn_global_load_lds(
                (const GLOBAL_AS void*)(aptr[i] + k0),
                (LDS_AS void*)(As + ldsOff + i * 512), 16, 0, 0);
            __builtin_amdgcn_global_load_lds(
                (const GLOBAL_AS void*)(bptr[i] + k0),
                (LDS_AS void*)(Bs + ldsOff + i * 512), 16, 0, 0);
        }
        __syncthreads();
#pragma unroll
        for (int kk = 0; kk < 2; ++kk) {
            bf16x8 af[4], bfr[4];
#pragma unroll
            for (int im = 0; im < 4; ++im)
                af[im] = *(const bf16x8*)(As + (wm + im * 16 + fr) * 64 +
                                          ((((kk << 2) + fq) ^ fx) << 3));
#pragma unroll
            for (int in = 0; in < 4; ++in)
                bfr[in] = *(const bf16x8*)(Bs + (wn + in * 16 + fr) * 64 +
                                           ((((kk << 2) + fq) ^ fx) << 3));
#pragma unroll
            for (int in = 0; in < 4; ++in)
#pragma unroll
                for (int im = 0; im < 4; ++im)
                    acc[in][im] = __builtin_amdgcn_mfma_f32_16x16x32_bf16(
                        af[im], bfr[in], acc[in][im], 0, 0, 0);
        }
        __syncthreads();
    }
    // epilogue: D[m=(lane>>4)*4+r][n=lane&15] -> C[n*M+m] (m-contiguous x4)
#pragma unroll
    for (int in = 0; in < 4; ++in) {
        const long n = n0 + wn + in * 16 + fr;
#pragma unroll
        for (int im = 0; im < 4; ++im) {
            floatx4 v = acc[in][im];
            const long m = m0 + wm + im * 16 + (fq << 2);
            if (EPI == EPI_RELU_F32 || EPI == EPI_RELU_BF16) {
                v.x = fmaxf(v.x, 0.f);
                v.y = fmaxf(v.y, 0.f);
                v.z = fmaxf(v.z, 0.f);
                v.w = fmaxf(v.w, 0.f);
            }
            if (EPI == EPI_TANH_BF16) {
                const float4 bv = *(const float4*)(bias + m);
                v.x = tanhf((v.x + bv.x) * BN_SCALE_F);
                v.y = tanhf((v.y + bv.y) * BN_SCALE_F);
                v.z = tanhf((v.z + bv.z) * BN_SCALE_F);
                v.w = tanhf((v.w + bv.w) * BN_SCALE_F);
                if (res) {
                    const bf16x4 r = *(const bf16x4*)(res + n * M + m);
                    v.x += (float)r[0];
                    v.y += (float)r[1];
                    v.z += (float)r[2];
                    v.w += (float)r[3];
                }
            }
            if (EPI == EPI_RELU_BF16 || EPI == EPI_TANH_BF16) {
                bf16* C = (bf16*)Cb + (long)blockIdx.z * cStr + n * M + m;
                bf16x4 ov;
                ov[0] = (bf16)v.x;
                ov[1] = (bf16)v.y;
                ov[2] = (bf16)v.z;
                ov[3] = (bf16)v.w;
                *(bf16x4*)C = ov;
            } else {
                float* C = (float*)Cb + (long)blockIdx.z * cStr + n * M + m;
                *(floatx4*)C = v;
            }
        }
    }
}

// ---------------- Z[b,n,f] = sum_m att[n,m] * Y[b,m,f]  (48x48 small GEMM) ---
// grid (4 f-tiles of 128, 256 b), block 256. Y,Z bf16 [b][48][512], att fp32.
__global__ __launch_bounds__(256) void k_attmul(const float* __restrict__ att,
                                                const bf16* __restrict__ Y,
                                                bf16* __restrict__ Z) {
    const int ft = blockIdx.x;
    const int b = blockIdx.y;
    __shared__ float attS[2304];
    __shared__ unsigned int YS[48 * 68];  // rows 48, 68 dwords (128 bf16 + pad)
    const int t = threadIdx.x;
#pragma unroll
    for (int i = 0; i < 9; ++i) attS[t + i * 256] = att[t + i * 256];
#pragma unroll
    for (int i = 0; i < 3; ++i) {
        const int u = t + i * 256;
        const int m = u >> 4, fg = u & 15;
        const uint4 v = *(const uint4*)(Y + ((long)b * 48 + m) * 512 + ft * 128 + fg * 8);
        *(uint4*)(YS + m * 68 + fg * 4) = v;
    }
    __syncthreads();
    const int ng = t >> 4, fgp = t & 15;  // 16 n-groups x 16 f-groups
    float acc[3][8];
#pragma unroll
    for (int i = 0; i < 3; ++i)
#pragma unroll
        for (int j = 0; j < 8; ++j) acc[i][j] = 0.f;
    const float* a0 = attS + (3 * ng) * 48;
#pragma unroll 4
    for (int m = 0; m < 48; ++m) {
        const bf16x8 yv = *(const bf16x8*)(YS + m * 68 + fgp * 4);
        float yf[8];
#pragma unroll
        for (int j = 0; j < 8; ++j) yf[j] = (float)yv[j];
        const float a_0 = a0[m];
        const float a_1 = a0[48 + m];
        const float a_2 = a0[96 + m];
#pragma unroll
        for (int j = 0; j < 8; ++j) {
            acc[0][j] = fmaf(a_0, yf[j], acc[0][j]);
            acc[1][j] = fmaf(a_1, yf[j], acc[1][j]);
            acc[2][j] = fmaf(a_2, yf[j], acc[2][j]);
        }
    }
#pragma unroll
    for (int i = 0; i < 3; ++i) {
        const int n = 3 * ng + i;
        bf16x8 o;
#pragma unroll
        for (int j = 0; j < 8; ++j) o[j] = (bf16)acc[i][j];
        *(bf16x8*)(Z + ((long)b * 48 + n) * 512 + ft * 128 + fgp * 8) = o;
    }
}

// ---------------- z0[b,n,k64] = gia @ dctin  (K padded 20->64, bf16) ---------
__global__ __launch_bounds__(960) void k_z0(const float* __restrict__ gia,
                                            const float* __restrict__ dctin,
                                            bf16* __restrict__ z0) {
    const int b = blockIdx.x;
    __shared__ float aS[2304];
    __shared__ float dS[960];
    const int t = threadIdx.x;
    for (int i = t; i < 2304; i += 960) aS[i] = gia[i];
    dS[t] = dctin[(long)b * 960 + t];
    __syncthreads();
    const int n = t / 20, d = t % 20;
    float acc = 0.f;
#pragma unroll
    for (int m = 0; m < 48; ++m) acc = fmaf(aS[n * 48 + m], dS[m * 20 + d], acc);
    z0[((long)b * 48 + n) * 64 + d] = (bf16)acc;
    for (int i = t; i < 48 * 44; i += 960) {
        const int n2 = i / 44, dz = 20 + i % 44;
        z0[((long)b * 48 + n2) * 64 + dz] = (bf16)0.f;
    }
}

// ---------------- dct_out = Zo @ gow + gob + dctin ---------------------------
__global__ __launch_bounds__(960) void k_out2(const bf16* __restrict__ Zo,
                                              const float* __restrict__ gow,
                                              const float* __restrict__ gob,
                                              const float* __restrict__ dctin,
                                              float* __restrict__ dout) {
    const int b = blockIdx.x;
    __shared__ bf16 GS[20 * 520];  // gow transposed [d][k], padded rows
    const int t = threadIdx.x;
    for (int i = t; i < 10240; i += 960) {
        const int d = i >> 9, k = i & 511;
        GS[d * 520 + k] = (bf16)gow[k * 20 + d];
    }
    __syncthreads();
    const int n = t / 20, d = t % 20;
    float acc = gob[d] + dctin[(long)b * 960 + t];
    const bf16* zr = Zo + ((long)b * 48 + n) * 512;
    const bf16* gr = GS + d * 520;
#pragma unroll 8
    for (int k8 = 0; k8 < 64; ++k8) {
        const bf16x8 zv = *(const bf16x8*)(zr + k8 * 8);
        const bf16x8 gv = *(const bf16x8*)(gr + k8 * 8);
#pragma unroll
        for (int j = 0; j < 8; ++j) acc = fmaf((float)zv[j], (float)gv[j], acc);
    }
    dout[(long)b * 960 + t] = acc;
}

// ---------------- attention scoring -----------------------------------------
__global__ __launch_bounds__(256) void k_score(const float* __restrict__ qh,
                                               const float* __restrict__ keyh,
                                               float* __restrict__ attw) {
    const int hb = blockIdx.x;
    const int tid = threadIdx.x;
    __shared__ float qS[512];
    __shared__ float sS[16];
    __shared__ float sSum;
    const float* q = qh + (long)hb * 512;
    qS[tid] = q[tid];
    qS[tid + 256] = q[tid + 256];
    __syncthreads();
    const int t = tid >> 4;
    const int l = tid & 15;
    const float* krow = keyh + ((long)hb * 16 + t) * 512;
    float p = 0.f;
    for (int o = l; o < 512; o += 16) p = fmaf(qS[o], krow[o], p);
#pragma unroll
    for (int off = 8; off; off >>= 1) p += __shfl_down(p, off, 16);
    if (l == 0) sS[t] = p + 1e-15f;
    __syncthreads();
    if (tid == 0) {
        float s = 0.f;
#pragma unroll
        for (int i = 0; i < 16; ++i) s += sS[i];
        sSum = s;
    }
    __syncthreads();
    if (tid < 16) attw[(long)hb * 16 + tid] = sS[tid] / sSum;
}

// ---------------- src_value: DCT of the 16 sliding windows -------------------
__global__ __launch_bounds__(512) void k_srcvalue(const float* __restrict__ src,
                                                  const float* __restrict__ dct10,
                                                  float* __restrict__ sv) {
    const int bn = blockIdx.x;
    const int b = bn >> 4, n = bn & 15;
    __shared__ float W[1680];
    __shared__ float D[350];
    const float* s0 = src + (long)b * 2400 + n * 48;
    for (int i = threadIdx.x; i < 1680; i += 512) W[i] = s0[i];
    for (int i = threadIdx.x; i < 350; i += 512) D[i] = dct10[i];
    __syncthreads();
    if (threadIdx.x < 480) {
        const int f = threadIdx.x / 10, d = threadIdx.x % 10;
        float acc = 0.f;
#pragma unroll
        for (int v = 0; v < 35; ++v) acc = fmaf(D[d * 35 + v], W[v * 48 + f], acc);
        sv[(long)bn * 480 + threadIdx.x] = acc;
    }
}

// ---------------- dct_att[h][b][j] = sum_k attw[h,b,k]*sv[b,k,j] -------------
__global__ __launch_bounds__(512) void k_dctatt(const float* __restrict__ attw,
                                                const float* __restrict__ sv,
                                                float* __restrict__ datt) {
    const int hb = blockIdx.x;
    const int b = hb & 255;
    __shared__ float aw[16];
    if (threadIdx.x < 16) aw[threadIdx.x] = attw[(long)hb * 16 + threadIdx.x];
    __syncthreads();
    if (threadIdx.x < 480) {
        float acc = 0.f;
#pragma unroll
        for (int k = 0; k < 16; ++k)
            acc = fmaf(aw[k], sv[((long)b * 16 + k) * 480 + threadIdx.x], acc);
        datt[(long)hb * 480 + threadIdx.x] = acc;
    }
}

// ---------------- dct_in[:, :, 0:10] -----------------------------------------
__global__ __launch_bounds__(512) void k_dctin1(const float* __restrict__ src,
                                                const float* __restrict__ dct10,
                                                float* __restrict__ dctin) {
    const int b = blockIdx.x;
    __shared__ float G[480];
    __shared__ float D[350];
    const float* s0 = src + (long)b * 2400 + 40 * 48;
    if (threadIdx.x < 480) G[threadIdx.x] = s0[threadIdx.x];
    for (int i = threadIdx.x; i < 350; i += 512) D[i] = dct10[i];
    __syncthreads();
    if (threadIdx.x < 480) {
        const int f = threadIdx.x / 10, d = threadIdx.x % 10;
        float acc = 0.f;
#pragma unroll
        for (int v = 0; v < 10; ++v) acc = fmaf(D[d * 35 + v], G[v * 48 + f], acc);
        float cs = 0.f;
#pragma unroll
        for (int v = 10; v < 35; ++v) cs += D[d * 35 + v];
        acc = fmaf(cs, G[9 * 48 + f], acc);
        dctin[(long)b * 960 + f * 20 + d] = acc;
    }
}

// ---------------- att_lin into dct_in[:, :, 10:20] ---------------------------
__global__ __launch_bounds__(512) void k_attlin(const float* __restrict__ datt,
                                                const float* __restrict__ lw,
                                                const float* __restrict__ lb,
                                                float* __restrict__ dctin) {
    const int b = blockIdx.x;
    __shared__ float L[1920];
    for (int i = threadIdx.x; i < 1920; i += 512) {
        const int h = i / 480, j = i % 480;
        L[i] = datt[((long)h * 256 + b) * 480 + j];
    }
    __syncthreads();
    if (threadIdx.x < 480) {
        const int n = threadIdx.x / 10, d = threadIdx.x % 10;
        float acc = lb[n];
#pragma unroll
        for (int h = 0; h < 4; ++h)
#pragma unroll
            for (int f = 0; f < 48; ++f)
                acc = fmaf(lw[n * 192 + h * 48 + f], L[h * 480 + f * 10 + d], acc);
        dctin[(long)b * 960 + n * 20 + 10 + d] = acc;
    }
}

// ---------------- final iDCT -------------------------------------------------
__global__ __launch_bounds__(512) void k_idct(const float* __restrict__ dout,
                                              const float* __restrict__ dct10,
                                              float* __restrict__ out) {
    const int b = blockIdx.x;
    __shared__ float dS[960];
    __shared__ float D[350];
    for (int i = threadIdx.x; i < 960; i += 512) dS[i] = dout[(long)b * 960 + i];
    for (int i = threadIdx.x; i < 350; i += 512) D[i] = dct10[i];
    __syncthreads();
    for (int e = threadIdx.x; e < 1680; e += 512) {
        const int v = e / 48, n = e % 48;
        float acc = 0.f;
#pragma unroll
        for (int d = 0; d < 10; ++d) acc = fmaf(D[d * 35 + v], dS[n * 20 + d], acc);
        out[(long)b * 1680 + e] = acc;
    }
}

// ---------------------------------------------------------------------------
// Workspace layout (BYTE offsets, 16B-aligned).
// keyh (33,554,432 B) aliases [WS_T ...): dead before Z/z0/ya are written
// (k_score runs before the GCN phase). Z/Zo (12.6MB) at WS_T; z0 at +16MB.
// ---------------------------------------------------------------------------
static constexpr size_t WS_DCT10 = 0;
static constexpr size_t WS_ATTW = 1536;
static constexpr size_t WS_QH = WS_ATTW + 65536;
static constexpr size_t WS_DCTIN = WS_QH + 2097152;
static constexpr size_t WS_DCTOUT = WS_DCTIN + 983040;
static constexpr size_t WS_SRCVAL = WS_DCTOUT + 983040;
static constexpr size_t WS_PAD0 = WS_SRCVAL + 7864320;
static constexpr size_t WS_SRCBF = WS_PAD0 + 8388608;
static constexpr size_t WS_W1TQ = WS_SRCBF + 1229824;
static constexpr size_t WS_W1TK = WS_W1TQ + 1310720;
static constexpr size_t WS_W2TQ = WS_W1TK + 1310720;
static constexpr size_t WS_W2TK = WS_W2TQ + 10485760;
static constexpr size_t WS_GBWT = WS_W2TK + 10485760;
static constexpr size_t WS_R1K = WS_GBWT + 2097152;
static constexpr size_t WS_R1Q = WS_R1K + 20971520;
static constexpr size_t WS_T = WS_R1Q + 5242880;        // 25165824 region
static constexpr size_t WS_YA = WS_T + 25165824;
static constexpr size_t WS_YB = WS_YA + 12582912;
static constexpr size_t WS_DCTATT = WS_YB + 12582912;
static constexpr size_t WS_GIWP = WS_DCTATT + 1966080;  // 65536
static constexpr size_t WS_KEYH = WS_T;                 // alias, 33554432 B
static constexpr size_t WS_Z = WS_T;                    // alias, 12582912 B
static constexpr size_t WS_Z0 = WS_T + 16777216;        // alias, 1572864 B

extern "C" void kernel_launch(void* const* d_in, const int* in_sizes, int n_in,
                              void* d_out, int out_size, void* d_ws,
                              size_t ws_size, hipStream_t stream) {
    const float* src = (const float*)d_in[0];
    const float* cq1 = (const float*)d_in[1];
    const float* cq2 = (const float*)d_in[2];
    const float* ck1 = (const float*)d_in[3];
    const float* ck2 = (const float*)d_in[4];
    const float* lw = (const float*)d_in[5];
    const float* lb = (const float*)d_in[6];
    const float* giw = (const float*)d_in[7];
    const float* gia = (const float*)d_in[8];
    const float* gib = (const float*)d_in[9];
    const float* gbw = (const float*)d_in[10];
    const float* gba = (const float*)d_in[11];
    const float* gbb = (const float*)d_in[12];
    const float* gow = (const float*)d_in[13];
    const float* goa = (const float*)d_in[14];
    const float* gob = (const float*)d_in[15];
    float* out = (float*)d_out;
    char* ws = (char*)d_ws;

    float* dct10 = (float*)(ws + WS_DCT10);
    float* attw = (float*)(ws + WS_ATTW);
    float* qh = (float*)(ws + WS_QH);
    float* dctin = (float*)(ws + WS_DCTIN);
    float* dctout = (float*)(ws + WS_DCTOUT);
    float* srcval = (float*)(ws + WS_SRCVAL);
    float* keyh = (float*)(ws + WS_KEYH);
    bf16* srcbf = (bf16*)(ws + WS_SRCBF);
    bf16* w1tq = (bf16*)(ws + WS_W1TQ);
    bf16* w1tk = (bf16*)(ws + WS_W1TK);
    bf16* w2tq = (bf16*)(ws + WS_W2TQ);
    bf16* w2tk = (bf16*)(ws + WS_W2TK);
    bf16* gbwt = (bf16*)(ws + WS_GBWT);
    bf16* r1k = (bf16*)(ws + WS_R1K);
    bf16* r1q = (bf16*)(ws + WS_R1Q);
    bf16* ya = (bf16*)(ws + WS_YA);
    bf16* yb = (bf16*)(ws + WS_YB);
    float* dctatt = (float*)(ws + WS_DCTATT);
    bf16* giwP = (bf16*)(ws + WS_GIWP);
    bf16* Z = (bf16*)(ws + WS_Z);
    bf16* z0 = (bf16*)(ws + WS_Z0);

    k_dct<<<2, 256, 0, stream>>>(dct10);
    k_cvtsrc<<<2401, 256, 0, stream>>>(src, srcbf);
    k_trw1<<<2560, 256, 0, stream>>>(cq1, w1tq);
    k_trw1<<<2560, 256, 0, stream>>>(ck1, w1tk);
    k_trw2<<<20480, 256, 0, stream>>>(cq2, w2tq);
    k_trw2<<<20480, 256, 0, stream>>>(ck2, w2tk);
    k_trgw<<<4096, 256, 0, stream>>>(gbw, gbwt);
    k_trgiw<<<128, 256, 0, stream>>>(giw, giwP);

    // conv1 (K padded 288->320): K-branch N=5120 (t0..19), Q-branch N=1280
    mgemm<BM_SRC, EPI_RELU_BF16><<<dim3(40, 4, 4), 256, 0, stream>>>(
        w1tk, srcbf, r1k, nullptr, nullptr, 512, 5120, 320, 20, 0, 512L * 320,
        0L, 5120L * 512);
    mgemm<BM_SRC, EPI_RELU_BF16><<<dim3(10, 4, 4), 256, 0, stream>>>(
        w1tq, srcbf, r1q, nullptr, nullptr, 512, 1280, 320, 5, 40, 512L * 320,
        0L, 1280L * 512);
    // conv2: K -> keyh fp32, Q -> qh fp32
    mgemm<BM_R1K, EPI_RELU_F32><<<dim3(32, 4, 4), 256, 0, stream>>>(
        w2tk, r1k, keyh, nullptr, nullptr, 512, 4096, 2560, 0, 0, 512L * 2560,
        2621440L, 2097152L);
    mgemm<BM_PLAIN, EPI_RELU_F32><<<dim3(2, 4, 4), 256, 0, stream>>>(
        w2tq, r1q, qh, nullptr, nullptr, 512, 256, 2560, 0, 0, 512L * 2560,
        655360L, 131072L);

    k_score<<<1024, 256, 0, stream>>>(qh, keyh, attw);
    k_srcvalue<<<4096, 512, 0, stream>>>(src, dct10, srcval);
    k_dctatt<<<1024, 512, 0, stream>>>(attw, srcval, dctatt);
    k_dctin1<<<256, 512, 0, stream>>>(src, dct10, dctin);
    k_attlin<<<256, 512, 0, stream>>>(dctatt, lw, lb, dctin);

    // ---- GCN (reassociated: y = tanh(((att@Y)@W + b)*s) (+res)) ----
    // layer 0: z0 = gia@dctin (K pad 64), ya = tanh((z0@giwP + gib)*s)
    k_z0<<<256, 960, 0, stream>>>(gia, dctin, z0);
    mgemm<BM_PLAIN, EPI_TANH_BF16><<<dim3(96, 4, 1), 256, 0, stream>>>(
        giwP, z0, ya, gib, nullptr, 512, 12288, 64, 0, 0, 0L, 0L, 0L);
    // s=0,j=0: ya -> yb
    k_attmul<<<dim3(4, 256), 256, 0, stream>>>(gba + 0 * 2304, ya, Z);
    mgemm<BM_PLAIN, EPI_TANH_BF16><<<dim3(96, 4, 1), 256, 0, stream>>>(
        gbwt + 0L * 262144, Z, yb, gbb + 0 * 512, nullptr, 512, 12288, 512, 0,
        0, 0L, 0L, 0L);
    // s=0,j=1: yb -> yb (+res ya)
    k_attmul<<<dim3(4, 256), 256, 0, stream>>>(gba + 1 * 2304, yb, Z);
    mgemm<BM_PLAIN, EPI_TANH_BF16><<<dim3(96, 4, 1), 256, 0, stream>>>(
        gbwt + 1L * 262144, Z, yb, gbb + 1 * 512, ya, 512, 12288, 512, 0, 0,
        0L, 0L, 0L);
    // s=1,j=0: yb -> ya
    k_attmul<<<dim3(4, 256), 256, 0, stream>>>(gba + 2 * 2304, yb, Z);
    mgemm<BM_PLAIN, EPI_TANH_BF16><<<dim3(96, 4, 1), 256, 0, stream>>>(
        gbwt + 2L * 262144, Z, ya, gbb + 2 * 512, nullptr, 512, 12288, 512, 0,
        0, 0L, 0L, 0L);
    // s=1,j=1: ya -> ya (+res yb)
    k_attmul<<<dim3(4, 256), 256, 0, stream>>>(gba + 3 * 2304, ya, Z);
    mgemm<BM_PLAIN, EPI_TANH_BF16><<<dim3(96, 4, 1), 256, 0, stream>>>(
        gbwt + 3L * 262144, Z, ya, gbb + 3 * 512, yb, 512, 12288, 512, 0, 0,
        0L, 0L, 0L);

    // gc_out: Zo = goa@ya; dct_out = Zo@gow + gob + dctin; then iDCT
    k_attmul<<<dim3(4, 256), 256, 0, stream>>>(goa, ya, Z);
    k_out2<<<256, 960, 0, stream>>>(Z, gow, gob, dctin, dctout);
    k_idct<<<256, 512, 0, stream>>>(dctout, dct10, out);
}

// Round 6
// 494.873 us; speedup vs baseline: 3.4277x; 1.0710x over previous
//
#include <hip/hip_runtime.h>
#include <math.h>

// ---------------------------------------------------------------------------
// Problem constants (bs=256, in_feat=48, d_model=512, dct_n=10, input_n=50,
// output_n=25, KERNEL=10, HEADS=4, vl=35, vn=16)
// ---------------------------------------------------------------------------
static constexpr float BN_SCALE_F = 0.9999950000374997f;

typedef __bf16 bf16;
typedef bf16 bf16x8 __attribute__((ext_vector_type(8)));
typedef bf16 bf16x4 __attribute__((ext_vector_type(4)));
typedef float floatx4 __attribute__((ext_vector_type(4)));

#define GLOBAL_AS __attribute__((address_space(1)))
#define LDS_AS __attribute__((address_space(3)))

enum { BM_SRC = 0, BM_R1K = 1, BM_PLAIN = 3 };
enum { EPI_F32 = 0, EPI_RELU_F32 = 1, EPI_RELU_BF16 = 2, EPI_TANH_BF16 = 3 };

// ---------------- mega prep: DCT build + all fp32->bf16 transposes ----------
// seg blocks: dct 2 | cvtsrc 2401 | trw1(q) 2560 | trw1(k) 2560 |
//             trw2(q) 20480 | trw2(k) 20480 | trgw 4096 | trgiw 128  = 52707
__device__ __forceinline__ void d_trw1(int id, const float* w, bf16* wt) {
    if (id < 4 * 512 * 320) {
        int ho = id / 320, c = id % 320;
        float v = (c < 288) ? w[(long)ho * 288 + (c % 48) * 6 + (c / 48)] * 1e-3f : 0.f;
        wt[id] = (bf16)v;
    }
}
__device__ __forceinline__ void d_trw2(int id, const float* w, bf16* wt) {
    if (id < 4 * 512 * 2560) {
        int ho = id / 2560, c = id % 2560;
        wt[id] = (bf16)w[(long)ho * 2560 + (c % 512) * 5 + (c / 512)];
    }
}
__global__ __launch_bounds__(256) void k_prep(
    const float* __restrict__ src, const float* __restrict__ cq1,
    const float* __restrict__ ck1, const float* __restrict__ cq2,
    const float* __restrict__ ck2, const float* __restrict__ gbw,
    const float* __restrict__ giw, float* __restrict__ dct10,
    bf16* __restrict__ srcbf, bf16* __restrict__ w1tq, bf16* __restrict__ w1tk,
    bf16* __restrict__ w2tq, bf16* __restrict__ w2tk, bf16* __restrict__ gbwt,
    bf16* __restrict__ giwP) {
    int bb = blockIdx.x;
    const int t = threadIdx.x;
    if (bb < 2) {
        int id = bb * 256 + t;
        if (id < 350) {
            int k = id / 35, i = id % 35;
            double w = (k == 0) ? sqrt(1.0 / 35.0) : sqrt(2.0 / 35.0);
            dct10[id] = (float)(w * cos(3.14159265358979323846 * (i + 0.5) * k / 35.0));
        }
        return;
    }
    bb -= 2;
    if (bb < 2401) {
        int id = bb * 256 + t;
        if (id < 614656) srcbf[id] = (bf16)(id < 614400 ? src[id] : 0.f);
        return;
    }
    bb -= 2401;
    if (bb < 2560) { d_trw1(bb * 256 + t, cq1, w1tq); return; }
    bb -= 2560;
    if (bb < 2560) { d_trw1(bb * 256 + t, ck1, w1tk); return; }
    bb -= 2560;
    if (bb < 20480) { d_trw2(bb * 256 + t, cq2, w2tq); return; }
    bb -= 20480;
    if (bb < 20480) { d_trw2(bb * 256 + t, ck2, w2tk); return; }
    bb -= 20480;
    if (bb < 4096) {
        int id = bb * 256 + t;
        if (id < 4 * 512 * 512) {
            int s = id >> 18, r = id & 262143;
            int m = r >> 9, k = r & 511;
            gbwt[id] = (bf16)gbw[(long)s * 262144 + k * 512 + m];
        }
        return;
    }
    bb -= 4096;
    {
        int id = bb * 256 + t;
        if (id < 512 * 64) {
            int f = id >> 6, k = id & 63;
            giwP[id] = (bf16)(k < 20 ? giw[k * 512 + f] : 0.f);
        }
    }
}

// ---------------- bf16 MFMA NT GEMM (single, fused epilogue) -----------------
template <int BMODE, int EPI>
__global__ __launch_bounds__(256) void mgemm(
    const bf16* __restrict__ Ab, const bf16* __restrict__ Bb,
    void* __restrict__ Cb, const float* __restrict__ bias,
    const bf16* __restrict__ res, const int M, const int N, const int K,
    const int NT, const int toff, const long aStr, const long bStr,
    const long cStr) {
    __shared__ bf16 As[128 * 64];
    __shared__ bf16 Bs[128 * 64];
    const int tid = threadIdx.x;
    const int wave = tid >> 6;
    const int lane = tid & 63;
    const int wm = (wave & 1) << 6;
    const int wn = (wave >> 1) << 6;
    const int m0 = blockIdx.y * 128;
    const int n0 = blockIdx.x * 128;
    const bf16* A = Ab + (long)blockIdx.z * aStr;
    const bf16* B = Bb + (long)blockIdx.z * bStr;

    const int srow = lane >> 3;
    const int gch = (lane & 7) ^ srow;
    const bf16* aptr[4];
    const bf16* bptr[4];
#pragma unroll
    for (int i = 0; i < 4; ++i) {
        const int ar = wave * 32 + i * 8 + srow;
        aptr[i] = A + (long)(m0 + ar) * K + gch * 8;
        const int n = n0 + ar;
        long bbase;
        if (BMODE == BM_SRC)
            bbase = (long)(n / NT) * 2400 + (long)((n % NT) + toff) * 48;
        else if (BMODE == BM_R1K)
            bbase = (long)((n >> 4) * 20 + (n & 15)) * 512;
        else
            bbase = (long)n * K;
        bptr[i] = B + bbase + gch * 8;
    }
    const int ldsOff = wave * 32 * 64;

    floatx4 acc[4][4];
#pragma unroll
    for (int j = 0; j < 4; ++j)
#pragma unroll
        for (int i = 0; i < 4; ++i) acc[j][i] = (floatx4){0.f, 0.f, 0.f, 0.f};

    const int fr = lane & 15;
    const int fq = lane >> 4;
    const int fx = lane & 7;

    for (int k0 = 0; k0 < K; k0 += 64) {
#pragma unroll
        for (int i = 0; i < 4; ++i) {
            __builtin_amdgcn_global_load_lds(
                (const GLOBAL_AS void*)(aptr[i] + k0),
                (LDS_AS void*)(As + ldsOff + i * 512), 16, 0, 0);
            __builtin_amdgcn_global_load_lds(
                (const GLOBAL_AS void*)(bptr[i] + k0),
                (LDS_AS void*)(Bs + ldsOff + i * 512), 16, 0, 0);
        }
        __syncthreads();
#pragma unroll
        for (int kk = 0; kk < 2; ++kk) {
            bf16x8 af[4], bfr[4];
#pragma unroll
            for (int im = 0; im < 4; ++im)
                af[im] = *(const bf16x8*)(As + (wm + im * 16 + fr) * 64 +
                                          ((((kk << 2) + fq) ^ fx) << 3));
#pragma unroll
            for (int in = 0; in < 4; ++in)
                bfr[in] = *(const bf16x8*)(Bs + (wn + in * 16 + fr) * 64 +
                                           ((((kk << 2) + fq) ^ fx) << 3));
#pragma unroll
            for (int in = 0; in < 4; ++in)
#pragma unroll
                for (int im = 0; im < 4; ++im)
                    acc[in][im] = __builtin_amdgcn_mfma_f32_16x16x32_bf16(
                        af[im], bfr[in], acc[in][im], 0, 0, 0);
        }
        __syncthreads();
    }
#pragma unroll
    for (int in = 0; in < 4; ++in) {
        const long n = n0 + wn + in * 16 + fr;
#pragma unroll
        for (int im = 0; im < 4; ++im) {
            floatx4 v = acc[in][im];
            const long m = m0 + wm + im * 16 + (fq << 2);
            if (EPI == EPI_RELU_F32 || EPI == EPI_RELU_BF16) {
                v.x = fmaxf(v.x, 0.f);
                v.y = fmaxf(v.y, 0.f);
                v.z = fmaxf(v.z, 0.f);
                v.w = fmaxf(v.w, 0.f);
            }
            if (EPI == EPI_TANH_BF16) {
                const float4 bv = *(const float4*)(bias + m);
                v.x = tanhf((v.x + bv.x) * BN_SCALE_F);
                v.y = tanhf((v.y + bv.y) * BN_SCALE_F);
                v.z = tanhf((v.z + bv.z) * BN_SCALE_F);
                v.w = tanhf((v.w + bv.w) * BN_SCALE_F);
                if (res) {
                    const bf16x4 r = *(const bf16x4*)(res + n * M + m);
                    v.x += (float)r[0];
                    v.y += (float)r[1];
                    v.z += (float)r[2];
                    v.w += (float)r[3];
                }
            }
            if (EPI == EPI_RELU_BF16 || EPI == EPI_TANH_BF16) {
                bf16* C = (bf16*)Cb + (long)blockIdx.z * cStr + n * M + m;
                bf16x4 ov;
                ov[0] = (bf16)v.x;
                ov[1] = (bf16)v.y;
                ov[2] = (bf16)v.z;
                ov[3] = (bf16)v.w;
                *(bf16x4*)C = ov;
            } else {
                float* C = (float*)Cb + (long)blockIdx.z * cStr + n * M + m;
                *(floatx4*)C = v;
            }
        }
    }
}

// ---------------- dual-branch GEMM (two problem instances in one dispatch) ---
struct GP {
    const bf16* A;
    const bf16* B;
    bf16* C;
    int NT;
    int toff;
    long aStr, bStr, cStr;
};
template <int BM1, int BM2>
__global__ __launch_bounds__(256) void mgemm2(GP p1, GP p2, const int splitX,
                                              const int M, const int K) {
    const bool first = (int)blockIdx.x < splitX;
    const GP p = first ? p1 : p2;
    const int bx = first ? (int)blockIdx.x : (int)blockIdx.x - splitX;
    __shared__ bf16 As[128 * 64];
    __shared__ bf16 Bs[128 * 64];
    const int tid = threadIdx.x;
    const int wave = tid >> 6;
    const int lane = tid & 63;
    const int wm = (wave & 1) << 6;
    const int wn = (wave >> 1) << 6;
    const int m0 = blockIdx.y * 128;
    const int n0 = bx * 128;
    const bf16* A = p.A + (long)blockIdx.z * p.aStr;
    const bf16* B = p.B + (long)blockIdx.z * p.bStr;

    const int srow = lane >> 3;
    const int gch = (lane & 7) ^ srow;
    const bf16* aptr[4];
    const bf16* bptr[4];
#pragma unroll
    for (int i = 0; i < 4; ++i) {
        const int ar = wave * 32 + i * 8 + srow;
        aptr[i] = A + (long)(m0 + ar) * K + gch * 8;
        const int n = n0 + ar;
        long bbase;
        const bool isSrc = first ? (BM1 == BM_SRC) : (BM2 == BM_SRC);
        const bool isR1k = first ? (BM1 == BM_R1K) : (BM2 == BM_R1K);
        if (isSrc)
            bbase = (long)(n / p.NT) * 2400 + (long)((n % p.NT) + p.toff) * 48;
        else if (isR1k)
            bbase = (long)((n >> 4) * 20 + (n & 15)) * 512;
        else
            bbase = (long)n * K;
        bptr[i] = B + bbase + gch * 8;
    }
    const int ldsOff = wave * 32 * 64;

    floatx4 acc[4][4];
#pragma unroll
    for (int j = 0; j < 4; ++j)
#pragma unroll
        for (int i = 0; i < 4; ++i) acc[j][i] = (floatx4){0.f, 0.f, 0.f, 0.f};

    const int fr = lane & 15;
    const int fq = lane >> 4;
    const int fx = lane & 7;

    for (int k0 = 0; k0 < K; k0 += 64) {
#pragma unroll
        for (int i = 0; i < 4; ++i) {
            __builtin_amdgcn_global_load_lds(
                (const GLOBAL_AS void*)(aptr[i] + k0),
                (LDS_AS void*)(As + ldsOff + i * 512), 16, 0, 0);
            __builtin_amdgcn_global_load_lds(
                (const GLOBAL_AS void*)(bptr[i] + k0),
                (LDS_AS void*)(Bs + ldsOff + i * 512), 16, 0, 0);
        }
        __syncthreads();
#pragma unroll
        for (int kk = 0; kk < 2; ++kk) {
            bf16x8 af[4], bfr[4];
#pragma unroll
            for (int im = 0; im < 4; ++im)
                af[im] = *(const bf16x8*)(As + (wm + im * 16 + fr) * 64 +
                                          ((((kk << 2) + fq) ^ fx) << 3));
#pragma unroll
            for (int in = 0; in < 4; ++in)
                bfr[in] = *(const bf16x8*)(Bs + (wn + in * 16 + fr) * 64 +
                                           ((((kk << 2) + fq) ^ fx) << 3));
#pragma unroll
            for (int in = 0; in < 4; ++in)
#pragma unroll
                for (int im = 0; im < 4; ++im)
                    acc[in][im] = __builtin_amdgcn_mfma_f32_16x16x32_bf16(
                        af[im], bfr[in], acc[in][im], 0, 0, 0);
        }
        __syncthreads();
    }
#pragma unroll
    for (int in = 0; in < 4; ++in) {
        const long n = n0 + wn + in * 16 + fr;
#pragma unroll
        for (int im = 0; im < 4; ++im) {
            floatx4 v = acc[in][im];
            const long m = m0 + wm + im * 16 + (fq << 2);
            v.x = fmaxf(v.x, 0.f);
            v.y = fmaxf(v.y, 0.f);
            v.z = fmaxf(v.z, 0.f);
            v.w = fmaxf(v.w, 0.f);
            bf16* C = p.C + (long)blockIdx.z * p.cStr + n * M + m;
            bf16x4 ov;
            ov[0] = (bf16)v.x;
            ov[1] = (bf16)v.y;
            ov[2] = (bf16)v.z;
            ov[3] = (bf16)v.w;
            *(bf16x4*)C = ov;
        }
    }
}

// ---------------- fused attention block (one block per batch b) --------------
// score -> attw -> windowed-DCT sv -> dct_att -> dctin[0:10] -> att_lin
// -> z0 = gia @ dctin (K padded to 64, bf16). All intermediates in LDS.
__global__ __launch_bounds__(512) void k_att(
    const bf16* __restrict__ qh, const bf16* __restrict__ keyh,
    const float* __restrict__ src, const float* __restrict__ dct10,
    const float* __restrict__ lw, const float* __restrict__ lb,
    const float* __restrict__ gia, float* __restrict__ dctin,
    bf16* __restrict__ z0) {
    const int b = blockIdx.x;
    const int t = threadIdx.x;
    __shared__ float BIG[9216];  // svS (7680) then lwS (9216)
    __shared__ float WD[2400];   // src rows, later gia (2304)
    __shared__ float D[350];
    __shared__ float L[1920];
    __shared__ float dinS[960];
    __shared__ float sS[64];
    __shared__ float awS[64];

    // P1: scores (4 heads x 16 keys, 8 lanes each)
    {
        const int g = t >> 3, lane = t & 7;
        const int h = g >> 4, tt = g & 15;
        const bf16* q = qh + ((long)h * 256 + b) * 512 + lane * 64;
        const bf16* kr = keyh + (long)h * 2097152 + ((long)b * 16 + tt) * 512 + lane * 64;
        float p = 0.f;
#pragma unroll
        for (int i = 0; i < 8; ++i) {
            const bf16x8 qv = *(const bf16x8*)(q + i * 8);
            const bf16x8 kv = *(const bf16x8*)(kr + i * 8);
#pragma unroll
            for (int j = 0; j < 8; ++j) p = fmaf((float)qv[j], (float)kv[j], p);
        }
        p += __shfl_down(p, 4, 8);
        p += __shfl_down(p, 2, 8);
        p += __shfl_down(p, 1, 8);
        if (lane == 0) sS[g] = p + 1e-15f;
    }
    for (int i = t; i < 2400; i += 512) WD[i] = src[(long)b * 2400 + i];
    for (int i = t; i < 350; i += 512) D[i] = dct10[i];
    __syncthreads();
    if (t < 4) {
        float s = 0.f;
#pragma unroll
        for (int k = 0; k < 16; ++k) s += sS[t * 16 + k];
        const float inv = 1.f / s;
#pragma unroll
        for (int k = 0; k < 16; ++k) awS[t * 16 + k] = sS[t * 16 + k] * inv;
    }
    __syncthreads();
    // P2: sv windows (16 x 480)
    for (int p = 0; p < 15; ++p) {
        const int idx = t + p * 512;
        const int n = idx / 480, j = idx % 480;
        const int f = j / 10, d = j % 10;
        float acc = 0.f;
#pragma unroll
        for (int v = 0; v < 35; ++v)
            acc = fmaf(D[d * 35 + v], WD[(n + v) * 48 + f], acc);
        BIG[idx] = acc;
    }
    __syncthreads();
    // P3: dct_att L[h*480+j]
    for (int p = 0; p < 4; ++p) {
        const int idx = t + p * 512;
        if (idx < 1920) {
            const int h = idx / 480, j = idx % 480;
            float acc = 0.f;
#pragma unroll
            for (int k = 0; k < 16; ++k)
                acc = fmaf(awS[h * 16 + k], BIG[k * 480 + j], acc);
            L[idx] = acc;
        }
    }
    // P4a: dctin cols 0..9 (gather rows 40..49, last row repeated)
    if (t < 480) {
        const int f = t / 10, d = t % 10;
        float acc = 0.f;
#pragma unroll
        for (int v = 0; v < 10; ++v)
            acc = fmaf(D[d * 35 + v], WD[(40 + v) * 48 + f], acc);
        float cs = 0.f;
#pragma unroll
        for (int v = 10; v < 35; ++v) cs += D[d * 35 + v];
        acc = fmaf(cs, WD[49 * 48 + f], acc);
        dinS[f * 20 + d] = acc;
        dctin[(long)b * 960 + f * 20 + d] = acc;
    }
    __syncthreads();  // BIG + WD free
    for (int i = t; i < 9216; i += 512) BIG[i] = lw[i];
    for (int i = t; i < 2304; i += 512) WD[i] = gia[i];
    __syncthreads();
    // P4b: att_lin -> dctin cols 10..19
    if (t < 480) {
        const int n = t / 10, d = t % 10;
        float acc = lb[n];
#pragma unroll
        for (int h = 0; h < 4; ++h)
#pragma unroll
            for (int f = 0; f < 48; ++f)
                acc = fmaf(BIG[n * 192 + h * 48 + f], L[h * 480 + f * 10 + d], acc);
        dinS[n * 20 + 10 + d] = acc;
        dctin[(long)b * 960 + n * 20 + 10 + d] = acc;
    }
    __syncthreads();
    // P5: z0 = gia @ dctin  (48 x 20, K-padded to 64)
    for (int p = 0; p < 2; ++p) {
        const int idx = t + p * 512;
        if (idx < 960) {
            const int n = idx / 20, d = idx % 20;
            float acc = 0.f;
#pragma unroll
            for (int m = 0; m < 48; ++m)
                acc = fmaf(WD[n * 48 + m], dinS[m * 20 + d], acc);
            z0[((long)b * 48 + n) * 64 + d] = (bf16)acc;
        }
    }
    for (int i = t; i < 2112; i += 512) {
        const int n = i / 44, c = 20 + i % 44;
        z0[((long)b * 48 + n) * 64 + c] = (bf16)0.f;
    }
}

// ---------------- Z[b,n,f] = sum_m att[n,m] * Y[b,m,f] -----------------------
__global__ __launch_bounds__(256) void k_attmul(const float* __restrict__ att,
                                                const bf16* __restrict__ Y,
                                                bf16* __restrict__ Z) {
    const int ft = blockIdx.x;
    const int b = blockIdx.y;
    __shared__ float attS[2304];
    __shared__ unsigned int YS[48 * 68];
    const int t = threadIdx.x;
#pragma unroll
    for (int i = 0; i < 9; ++i) attS[t + i * 256] = att[t + i * 256];
#pragma unroll
    for (int i = 0; i < 3; ++i) {
        const int u = t + i * 256;
        const int m = u >> 4, fg = u & 15;
        const uint4 v = *(const uint4*)(Y + ((long)b * 48 + m) * 512 + ft * 128 + fg * 8);
        *(uint4*)(YS + m * 68 + fg * 4) = v;
    }
    __syncthreads();
    const int ng = t >> 4, fgp = t & 15;
    float acc[3][8];
#pragma unroll
    for (int i = 0; i < 3; ++i)
#pragma unroll
        for (int j = 0; j < 8; ++j) acc[i][j] = 0.f;
    const float* a0 = attS + (3 * ng) * 48;
#pragma unroll 4
    for (int m = 0; m < 48; ++m) {
        const bf16x8 yv = *(const bf16x8*)(YS + m * 68 + fgp * 4);
        float yf[8];
#pragma unroll
        for (int j = 0; j < 8; ++j) yf[j] = (float)yv[j];
        const float a_0 = a0[m];
        const float a_1 = a0[48 + m];
        const float a_2 = a0[96 + m];
#pragma unroll
        for (int j = 0; j < 8; ++j) {
            acc[0][j] = fmaf(a_0, yf[j], acc[0][j]);
            acc[1][j] = fmaf(a_1, yf[j], acc[1][j]);
            acc[2][j] = fmaf(a_2, yf[j], acc[2][j]);
        }
    }
#pragma unroll
    for (int i = 0; i < 3; ++i) {
        const int n = 3 * ng + i;
        bf16x8 o;
#pragma unroll
        for (int j = 0; j < 8; ++j) o[j] = (bf16)acc[i][j];
        *(bf16x8*)(Z + ((long)b * 48 + n) * 512 + ft * 128 + fgp * 8) = o;
    }
}

// ---------------- fused gc_out second half + iDCT ----------------------------
__global__ __launch_bounds__(512) void k_outidct(
    const bf16* __restrict__ Zo, const float* __restrict__ gow,
    const float* __restrict__ gob, const float* __restrict__ dctin,
    const float* __restrict__ dct10, float* __restrict__ out) {
    const int b = blockIdx.x;
    const int t = threadIdx.x;
    __shared__ bf16 GS[20 * 520];
    __shared__ float dS[960];
    __shared__ float D[350];
    for (int i = t; i < 10240; i += 512) {
        const int d = i >> 9, k = i & 511;
        GS[d * 520 + k] = (bf16)gow[k * 20 + d];
    }
    for (int i = t; i < 350; i += 512) D[i] = dct10[i];
    __syncthreads();
#pragma unroll
    for (int p = 0; p < 2; ++p) {
        const int idx = t + p * 512;
        if (idx < 960) {
            const int n = idx / 20, d = idx % 20;
            float acc = gob[d] + dctin[(long)b * 960 + idx];
            const bf16* zr = Zo + ((long)b * 48 + n) * 512;
            const bf16* gr = GS + d * 520;
#pragma unroll 8
            for (int k8 = 0; k8 < 64; ++k8) {
                const bf16x8 zv = *(const bf16x8*)(zr + k8 * 8);
                const bf16x8 gv = *(const bf16x8*)(gr + k8 * 8);
#pragma unroll
                for (int j = 0; j < 8; ++j)
                    acc = fmaf((float)zv[j], (float)gv[j], acc);
            }
            dS[idx] = acc;
        }
    }
    __syncthreads();
    for (int e = t; e < 1680; e += 512) {
        const int v = e / 48, n = e % 48;
        float acc = 0.f;
#pragma unroll
        for (int d = 0; d < 10; ++d)
            acc = fmaf(D[d * 35 + v], dS[n * 20 + d], acc);
        out[(long)b * 1680 + e] = acc;
    }
}

// ---------------------------------------------------------------------------
// Workspace (BYTE offsets). keyh is now bf16 (16,777,216 B) aliasing WS_T;
// z0 sits at WS_T+17 MB (disjoint from live keyh AND from Z). Z aliases WS_T
// after k_att (keyh dead).
// ---------------------------------------------------------------------------
static constexpr size_t WS_DCT10 = 0;
static constexpr size_t WS_ATTW = 1536;                 // unused now
static constexpr size_t WS_QH = WS_ATTW + 65536;        // bf16, 1 MB used
static constexpr size_t WS_DCTIN = WS_QH + 2097152;
static constexpr size_t WS_DCTOUT = WS_DCTIN + 983040;  // unused now
static constexpr size_t WS_SRCVAL = WS_DCTOUT + 983040; // unused now
static constexpr size_t WS_PAD0 = WS_SRCVAL + 7864320;
static constexpr size_t WS_SRCBF = WS_PAD0 + 8388608;
static constexpr size_t WS_W1TQ = WS_SRCBF + 1229824;
static constexpr size_t WS_W1TK = WS_W1TQ + 1310720;
static constexpr size_t WS_W2TQ = WS_W1TK + 1310720;
static constexpr size_t WS_W2TK = WS_W2TQ + 10485760;
static constexpr size_t WS_GBWT = WS_W2TK + 10485760;
static constexpr size_t WS_R1K = WS_GBWT + 2097152;
static constexpr size_t WS_R1Q = WS_R1K + 20971520;
static constexpr size_t WS_T = WS_R1Q + 5242880;        // 25165824 region
static constexpr size_t WS_YA = WS_T + 25165824;
static constexpr size_t WS_YB = WS_YA + 12582912;
static constexpr size_t WS_GIWP = WS_YB + 12582912;     // 65536
static constexpr size_t WS_KEYH = WS_T;                 // bf16, 16777216 B
static constexpr size_t WS_Z = WS_T;                    // bf16, 12582912 B
static constexpr size_t WS_Z0 = WS_T + 17825792;        // bf16, 1572864 B

extern "C" void kernel_launch(void* const* d_in, const int* in_sizes, int n_in,
                              void* d_out, int out_size, void* d_ws,
                              size_t ws_size, hipStream_t stream) {
    const float* src = (const float*)d_in[0];
    const float* cq1 = (const float*)d_in[1];
    const float* cq2 = (const float*)d_in[2];
    const float* ck1 = (const float*)d_in[3];
    const float* ck2 = (const float*)d_in[4];
    const float* lw = (const float*)d_in[5];
    const float* lb = (const float*)d_in[6];
    const float* giw = (const float*)d_in[7];
    const float* gia = (const float*)d_in[8];
    const float* gib = (const float*)d_in[9];
    const float* gbw = (const float*)d_in[10];
    const float* gba = (const float*)d_in[11];
    const float* gbb = (const float*)d_in[12];
    const float* gow = (const float*)d_in[13];
    const float* goa = (const float*)d_in[14];
    const float* gob = (const float*)d_in[15];
    float* out = (float*)d_out;
    char* ws = (char*)d_ws;

    float* dct10 = (float*)(ws + WS_DCT10);
    bf16* qh = (bf16*)(ws + WS_QH);
    float* dctin = (float*)(ws + WS_DCTIN);
    bf16* keyh = (bf16*)(ws + WS_KEYH);
    bf16* srcbf = (bf16*)(ws + WS_SRCBF);
    bf16* w1tq = (bf16*)(ws + WS_W1TQ);
    bf16* w1tk = (bf16*)(ws + WS_W1TK);
    bf16* w2tq = (bf16*)(ws + WS_W2TQ);
    bf16* w2tk = (bf16*)(ws + WS_W2TK);
    bf16* gbwt = (bf16*)(ws + WS_GBWT);
    bf16* r1k = (bf16*)(ws + WS_R1K);
    bf16* r1q = (bf16*)(ws + WS_R1Q);
    bf16* ya = (bf16*)(ws + WS_YA);
    bf16* yb = (bf16*)(ws + WS_YB);
    bf16* giwP = (bf16*)(ws + WS_GIWP);
    bf16* Z = (bf16*)(ws + WS_Z);
    bf16* z0 = (bf16*)(ws + WS_Z0);

    // 1. all prep in one dispatch
    k_prep<<<52707, 256, 0, stream>>>(src, cq1, ck1, cq2, ck2, gbw, giw, dct10,
                                      srcbf, w1tq, w1tk, w2tq, w2tk, gbwt, giwP);

    // 2. conv1 K+Q in one dispatch (K: 40 x-tiles, Q: 10)
    {
        GP pk{w1tk, srcbf, r1k, 20, 0, 512L * 320, 0L, 5120L * 512};
        GP pq{w1tq, srcbf, r1q, 5, 40, 512L * 320, 0L, 1280L * 512};
        mgemm2<BM_SRC, BM_SRC><<<dim3(50, 4, 4), 256, 0, stream>>>(pk, pq, 40,
                                                                   512, 320);
    }
    // 3. conv2 K+Q in one dispatch; bf16 keyh/qh outputs
    {
        GP pk{w2tk, r1k, keyh, 0, 0, 512L * 2560, 2621440L, 2097152L};
        GP pq{w2tq, r1q, qh, 0, 0, 512L * 2560, 655360L, 131072L};
        mgemm2<BM_R1K, BM_PLAIN><<<dim3(34, 4, 4), 256, 0, stream>>>(pk, pq, 32,
                                                                     512, 2560);
    }

    // 4. fused attention block -> dctin (fp32), z0 (bf16)
    k_att<<<256, 512, 0, stream>>>(qh, keyh, src, dct10, lw, lb, gia, dctin, z0);

    // ---- GCN (reassociated) ----
    mgemm<BM_PLAIN, EPI_TANH_BF16><<<dim3(96, 4, 1), 256, 0, stream>>>(
        giwP, z0, ya, gib, nullptr, 512, 12288, 64, 0, 0, 0L, 0L, 0L);
    k_attmul<<<dim3(4, 256), 256, 0, stream>>>(gba + 0 * 2304, ya, Z);
    mgemm<BM_PLAIN, EPI_TANH_BF16><<<dim3(96, 4, 1), 256, 0, stream>>>(
        gbwt + 0L * 262144, Z, yb, gbb + 0 * 512, nullptr, 512, 12288, 512, 0,
        0, 0L, 0L, 0L);
    k_attmul<<<dim3(4, 256), 256, 0, stream>>>(gba + 1 * 2304, yb, Z);
    mgemm<BM_PLAIN, EPI_TANH_BF16><<<dim3(96, 4, 1), 256, 0, stream>>>(
        gbwt + 1L * 262144, Z, yb, gbb + 1 * 512, ya, 512, 12288, 512, 0, 0,
        0L, 0L, 0L);
    k_attmul<<<dim3(4, 256), 256, 0, stream>>>(gba + 2 * 2304, yb, Z);
    mgemm<BM_PLAIN, EPI_TANH_BF16><<<dim3(96, 4, 1), 256, 0, stream>>>(
        gbwt + 2L * 262144, Z, ya, gbb + 2 * 512, nullptr, 512, 12288, 512, 0,
        0, 0L, 0L, 0L);
    k_attmul<<<dim3(4, 256), 256, 0, stream>>>(gba + 3 * 2304, ya, Z);
    mgemm<BM_PLAIN, EPI_TANH_BF16><<<dim3(96, 4, 1), 256, 0, stream>>>(
        gbwt + 3L * 262144, Z, ya, gbb + 3 * 512, yb, 512, 12288, 512, 0, 0,
        0L, 0L, 0L);

    // gc_out + iDCT
    k_attmul<<<dim3(4, 256), 256, 0, stream>>>(goa, ya, Z);
    k_outidct<<<256, 512, 0, stream>>>(Z, gow, gob, dctin, dct10, out);
}

// Round 8
// 440.684 us; speedup vs baseline: 3.8492x; 1.1230x over previous
//
#include <hip/hip_runtime.h>
#include <math.h>

// ---------------------------------------------------------------------------
// Problem constants (bs=256, in_feat=48, d_model=512, dct_n=10, input_n=50,
// output_n=25, KERNEL=10, HEADS=4, vl=35, vn=16)
// ---------------------------------------------------------------------------
static constexpr float BN_SCALE_F = 0.9999950000374997f;

typedef __bf16 bf16;
typedef bf16 bf16x8 __attribute__((ext_vector_type(8)));
typedef bf16 bf16x4 __attribute__((ext_vector_type(4)));
typedef float floatx4 __attribute__((ext_vector_type(4)));

#define GLOBAL_AS __attribute__((address_space(1)))
#define LDS_AS __attribute__((address_space(3)))

enum { BM_SRC = 0, BM_R1K = 1, BM_PLAIN = 3 };
enum { EPI_F32 = 0, EPI_RELU_F32 = 1, EPI_RELU_BF16 = 2, EPI_TANH_BF16 = 3 };

// ---------------- mega prep: DCT build + all fp32->bf16 transposes ----------
__device__ __forceinline__ void d_trw1(int id, const float* w, bf16* wt) {
    if (id < 4 * 512 * 320) {
        int ho = id / 320, c = id % 320;
        float v = (c < 288) ? w[(long)ho * 288 + (c % 48) * 6 + (c / 48)] * 1e-3f : 0.f;
        wt[id] = (bf16)v;
    }
}
__device__ __forceinline__ void d_trw2(int id, const float* w, bf16* wt) {
    if (id < 4 * 512 * 2560) {
        int ho = id / 2560, c = id % 2560;
        wt[id] = (bf16)w[(long)ho * 2560 + (c % 512) * 5 + (c / 512)];
    }
}
__global__ __launch_bounds__(256) void k_prep(
    const float* __restrict__ src, const float* __restrict__ cq1,
    const float* __restrict__ ck1, const float* __restrict__ cq2,
    const float* __restrict__ ck2, const float* __restrict__ gbw,
    const float* __restrict__ giw, float* __restrict__ dct10,
    bf16* __restrict__ srcbf, bf16* __restrict__ w1tq, bf16* __restrict__ w1tk,
    bf16* __restrict__ w2tq, bf16* __restrict__ w2tk, bf16* __restrict__ gbwt,
    bf16* __restrict__ giwP) {
    int bb = blockIdx.x;
    const int t = threadIdx.x;
    if (bb < 2) {
        int id = bb * 256 + t;
        if (id < 350) {
            int k = id / 35, i = id % 35;
            double w = (k == 0) ? sqrt(1.0 / 35.0) : sqrt(2.0 / 35.0);
            dct10[id] = (float)(w * cos(3.14159265358979323846 * (i + 0.5) * k / 35.0));
        }
        return;
    }
    bb -= 2;
    if (bb < 2401) {
        int id = bb * 256 + t;
        if (id < 614656) srcbf[id] = (bf16)(id < 614400 ? src[id] : 0.f);
        return;
    }
    bb -= 2401;
    if (bb < 2560) { d_trw1(bb * 256 + t, cq1, w1tq); return; }
    bb -= 2560;
    if (bb < 2560) { d_trw1(bb * 256 + t, ck1, w1tk); return; }
    bb -= 2560;
    if (bb < 20480) { d_trw2(bb * 256 + t, cq2, w2tq); return; }
    bb -= 20480;
    if (bb < 20480) { d_trw2(bb * 256 + t, ck2, w2tk); return; }
    bb -= 20480;
    if (bb < 4096) {
        int id = bb * 256 + t;
        if (id < 4 * 512 * 512) {
            int s = id >> 18, r = id & 262143;
            int m = r >> 9, k = r & 511;
            gbwt[id] = (bf16)gbw[(long)s * 262144 + k * 512 + m];
        }
        return;
    }
    bb -= 4096;
    {
        int id = bb * 256 + t;
        if (id < 512 * 64) {
            int f = id >> 6, k = id & 63;
            giwP[id] = (bf16)(k < 20 ? giw[k * 512 + f] : 0.f);
        }
    }
}

// ---------------- bf16 MFMA NT GEMM (single, fused epilogue) -----------------
template <int BMODE, int EPI>
__global__ __launch_bounds__(256) void mgemm(
    const bf16* __restrict__ Ab, const bf16* __restrict__ Bb,
    void* __restrict__ Cb, const float* __restrict__ bias,
    const bf16* __restrict__ res, const int M, const int N, const int K,
    const int NT, const int toff, const long aStr, const long bStr,
    const long cStr) {
    __shared__ bf16 As[128 * 64];
    __shared__ bf16 Bs[128 * 64];
    const int tid = threadIdx.x;
    const int wave = tid >> 6;
    const int lane = tid & 63;
    const int wm = (wave & 1) << 6;
    const int wn = (wave >> 1) << 6;
    const int m0 = blockIdx.y * 128;
    const int n0 = blockIdx.x * 128;
    const bf16* A = Ab + (long)blockIdx.z * aStr;
    const bf16* B = Bb + (long)blockIdx.z * bStr;

    const int srow = lane >> 3;
    const int gch = (lane & 7) ^ srow;
    const bf16* aptr[4];
    const bf16* bptr[4];
#pragma unroll
    for (int i = 0; i < 4; ++i) {
        const int ar = wave * 32 + i * 8 + srow;
        aptr[i] = A + (long)(m0 + ar) * K + gch * 8;
        const int n = n0 + ar;
        long bbase;
        if (BMODE == BM_SRC)
            bbase = (long)(n / NT) * 2400 + (long)((n % NT) + toff) * 48;
        else if (BMODE == BM_R1K)
            bbase = (long)((n >> 4) * 20 + (n & 15)) * 512;
        else
            bbase = (long)n * K;
        bptr[i] = B + bbase + gch * 8;
    }
    const int ldsOff = wave * 32 * 64;

    floatx4 acc[4][4];
#pragma unroll
    for (int j = 0; j < 4; ++j)
#pragma unroll
        for (int i = 0; i < 4; ++i) acc[j][i] = (floatx4){0.f, 0.f, 0.f, 0.f};

    const int fr = lane & 15;
    const int fq = lane >> 4;
    const int fx = lane & 7;

    for (int k0 = 0; k0 < K; k0 += 64) {
#pragma unroll
        for (int i = 0; i < 4; ++i) {
            __builtin_amdgcn_global_load_lds(
                (const GLOBAL_AS void*)(aptr[i] + k0),
                (LDS_AS void*)(As + ldsOff + i * 512), 16, 0, 0);
            __builtin_amdgcn_global_load_lds(
                (const GLOBAL_AS void*)(bptr[i] + k0),
                (LDS_AS void*)(Bs + ldsOff + i * 512), 16, 0, 0);
        }
        __syncthreads();
#pragma unroll
        for (int kk = 0; kk < 2; ++kk) {
            bf16x8 af[4], bfr[4];
#pragma unroll
            for (int im = 0; im < 4; ++im)
                af[im] = *(const bf16x8*)(As + (wm + im * 16 + fr) * 64 +
                                          ((((kk << 2) + fq) ^ fx) << 3));
#pragma unroll
            for (int in = 0; in < 4; ++in)
                bfr[in] = *(const bf16x8*)(Bs + (wn + in * 16 + fr) * 64 +
                                           ((((kk << 2) + fq) ^ fx) << 3));
#pragma unroll
            for (int in = 0; in < 4; ++in)
#pragma unroll
                for (int im = 0; im < 4; ++im)
                    acc[in][im] = __builtin_amdgcn_mfma_f32_16x16x32_bf16(
                        af[im], bfr[in], acc[in][im], 0, 0, 0);
        }
        __syncthreads();
    }
#pragma unroll
    for (int in = 0; in < 4; ++in) {
        const long n = n0 + wn + in * 16 + fr;
#pragma unroll
        for (int im = 0; im < 4; ++im) {
            floatx4 v = acc[in][im];
            const long m = m0 + wm + im * 16 + (fq << 2);
            if (EPI == EPI_RELU_F32 || EPI == EPI_RELU_BF16) {
                v.x = fmaxf(v.x, 0.f);
                v.y = fmaxf(v.y, 0.f);
                v.z = fmaxf(v.z, 0.f);
                v.w = fmaxf(v.w, 0.f);
            }
            if (EPI == EPI_TANH_BF16) {
                const float4 bv = *(const float4*)(bias + m);
                v.x = tanhf((v.x + bv.x) * BN_SCALE_F);
                v.y = tanhf((v.y + bv.y) * BN_SCALE_F);
                v.z = tanhf((v.z + bv.z) * BN_SCALE_F);
                v.w = tanhf((v.w + bv.w) * BN_SCALE_F);
                if (res) {
                    const bf16x4 r = *(const bf16x4*)(res + n * M + m);
                    v.x += (float)r[0];
                    v.y += (float)r[1];
                    v.z += (float)r[2];
                    v.w += (float)r[3];
                }
            }
            if (EPI == EPI_RELU_BF16 || EPI == EPI_TANH_BF16) {
                bf16* C = (bf16*)Cb + (long)blockIdx.z * cStr + n * M + m;
                bf16x4 ov;
                ov[0] = (bf16)v.x;
                ov[1] = (bf16)v.y;
                ov[2] = (bf16)v.z;
                ov[3] = (bf16)v.w;
                *(bf16x4*)C = ov;
            } else {
                float* C = (float*)Cb + (long)blockIdx.z * cStr + n * M + m;
                *(floatx4*)C = v;
            }
        }
    }
}

// ---------------- dual-branch GEMM (two problem instances, padded grid) ------
// gridDim.x MUST be a multiple of 8 so blocks sharing a B-tile (stride
// gridDim.x) land on the same XCD's L2 [round-6 lesson: x=34 -> 226 MB fetch].
struct GP {
    const bf16* A;
    const bf16* B;
    bf16* C;
    int NT;
    int toff;
    int nTiles;  // valid x-tiles for this branch (idle pad blocks exit)
    long aStr, bStr, cStr;
};
template <int BM1, int BM2>
__global__ __launch_bounds__(256) void mgemm2(GP p1, GP p2, const int splitX,
                                              const int M, const int K) {
    const bool first = (int)blockIdx.x < splitX;
    const GP p = first ? p1 : p2;
    const int bx = first ? (int)blockIdx.x : (int)blockIdx.x - splitX;
    if (bx >= p.nTiles) return;  // uniform early-exit for pad blocks
    __shared__ bf16 As[128 * 64];
    __shared__ bf16 Bs[128 * 64];
    const int tid = threadIdx.x;
    const int wave = tid >> 6;
    const int lane = tid & 63;
    const int wm = (wave & 1) << 6;
    const int wn = (wave >> 1) << 6;
    const int m0 = blockIdx.y * 128;
    const int n0 = bx * 128;
    const bf16* A = p.A + (long)blockIdx.z * p.aStr;
    const bf16* B = p.B + (long)blockIdx.z * p.bStr;

    const int srow = lane >> 3;
    const int gch = (lane & 7) ^ srow;
    const bf16* aptr[4];
    const bf16* bptr[4];
#pragma unroll
    for (int i = 0; i < 4; ++i) {
        const int ar = wave * 32 + i * 8 + srow;
        aptr[i] = A + (long)(m0 + ar) * K + gch * 8;
        const int n = n0 + ar;
        long bbase;
        const bool isSrc = first ? (BM1 == BM_SRC) : (BM2 == BM_SRC);
        const bool isR1k = first ? (BM1 == BM_R1K) : (BM2 == BM_R1K);
        if (isSrc)
            bbase = (long)(n / p.NT) * 2400 + (long)((n % p.NT) + p.toff) * 48;
        else if (isR1k)
            bbase = (long)((n >> 4) * 20 + (n & 15)) * 512;
        else
            bbase = (long)n * K;
        bptr[i] = B + bbase + gch * 8;
    }
    const int ldsOff = wave * 32 * 64;

    floatx4 acc[4][4];
#pragma unroll
    for (int j = 0; j < 4; ++j)
#pragma unroll
        for (int i = 0; i < 4; ++i) acc[j][i] = (floatx4){0.f, 0.f, 0.f, 0.f};

    const int fr = lane & 15;
    const int fq = lane >> 4;
    const int fx = lane & 7;

    for (int k0 = 0; k0 < K; k0 += 64) {
#pragma unroll
        for (int i = 0; i < 4; ++i) {
            __builtin_amdgcn_global_load_lds(
                (const GLOBAL_AS void*)(aptr[i] + k0),
                (LDS_AS void*)(As + ldsOff + i * 512), 16, 0, 0);
            __builtin_amdgcn_global_load_lds(
                (const GLOBAL_AS void*)(bptr[i] + k0),
                (LDS_AS void*)(Bs + ldsOff + i * 512), 16, 0, 0);
        }
        __syncthreads();
#pragma unroll
        for (int kk = 0; kk < 2; ++kk) {
            bf16x8 af[4], bfr[4];
#pragma unroll
            for (int im = 0; im < 4; ++im)
                af[im] = *(const bf16x8*)(As + (wm + im * 16 + fr) * 64 +
                                          ((((kk << 2) + fq) ^ fx) << 3));
#pragma unroll
            for (int in = 0; in < 4; ++in)
                bfr[in] = *(const bf16x8*)(Bs + (wn + in * 16 + fr) * 64 +
                                           ((((kk << 2) + fq) ^ fx) << 3));
#pragma unroll
            for (int in = 0; in < 4; ++in)
#pragma unroll
                for (int im = 0; im < 4; ++im)
                    acc[in][im] = __builtin_amdgcn_mfma_f32_16x16x32_bf16(
                        af[im], bfr[in], acc[in][im], 0, 0, 0);
        }
        __syncthreads();
    }
#pragma unroll
    for (int in = 0; in < 4; ++in) {
        const long n = n0 + wn + in * 16 + fr;
#pragma unroll
        for (int im = 0; im < 4; ++im) {
            floatx4 v = acc[in][im];
            const long m = m0 + wm + im * 16 + (fq << 2);
            v.x = fmaxf(v.x, 0.f);
            v.y = fmaxf(v.y, 0.f);
            v.z = fmaxf(v.z, 0.f);
            v.w = fmaxf(v.w, 0.f);
            bf16* C = p.C + (long)blockIdx.z * p.cStr + n * M + m;
            bf16x4 ov;
            ov[0] = (bf16)v.x;
            ov[1] = (bf16)v.y;
            ov[2] = (bf16)v.z;
            ov[3] = (bf16)v.w;
            *(bf16x4*)C = ov;
        }
    }
}

// ---------------- fused attention block (one block per batch b) --------------
__global__ __launch_bounds__(512) void k_att(
    const bf16* __restrict__ qh, const bf16* __restrict__ keyh,
    const float* __restrict__ src, const float* __restrict__ dct10,
    const float* __restrict__ lw, const float* __restrict__ lb,
    const float* __restrict__ gia, float* __restrict__ dctin,
    bf16* __restrict__ z0) {
    const int b = blockIdx.x;
    const int t = threadIdx.x;
    __shared__ float BIG[9216];
    __shared__ float WD[2400];
    __shared__ float D[350];
    __shared__ float L[1920];
    __shared__ float dinS[960];
    __shared__ float sS[64];
    __shared__ float awS[64];

    {
        const int g = t >> 3, lane = t & 7;
        const int h = g >> 4, tt = g & 15;
        const bf16* q = qh + ((long)h * 256 + b) * 512 + lane * 64;
        const bf16* kr = keyh + (long)h * 2097152 + ((long)b * 16 + tt) * 512 + lane * 64;
        float p = 0.f;
#pragma unroll
        for (int i = 0; i < 8; ++i) {
            const bf16x8 qv = *(const bf16x8*)(q + i * 8);
            const bf16x8 kv = *(const bf16x8*)(kr + i * 8);
#pragma unroll
            for (int j = 0; j < 8; ++j) p = fmaf((float)qv[j], (float)kv[j], p);
        }
        p += __shfl_down(p, 4, 8);
        p += __shfl_down(p, 2, 8);
        p += __shfl_down(p, 1, 8);
        if (lane == 0) sS[g] = p + 1e-15f;
    }
    for (int i = t; i < 2400; i += 512) WD[i] = src[(long)b * 2400 + i];
    for (int i = t; i < 350; i += 512) D[i] = dct10[i];
    __syncthreads();
    if (t < 4) {
        float s = 0.f;
#pragma unroll
        for (int k = 0; k < 16; ++k) s += sS[t * 16 + k];
        const float inv = 1.f / s;
#pragma unroll
        for (int k = 0; k < 16; ++k) awS[t * 16 + k] = sS[t * 16 + k] * inv;
    }
    __syncthreads();
    for (int p = 0; p < 15; ++p) {
        const int idx = t + p * 512;
        const int n = idx / 480, j = idx % 480;
        const int f = j / 10, d = j % 10;
        float acc = 0.f;
#pragma unroll
        for (int v = 0; v < 35; ++v)
            acc = fmaf(D[d * 35 + v], WD[(n + v) * 48 + f], acc);
        BIG[idx] = acc;
    }
    __syncthreads();
    for (int p = 0; p < 4; ++p) {
        const int idx = t + p * 512;
        if (idx < 1920) {
            const int h = idx / 480, j = idx % 480;
            float acc = 0.f;
#pragma unroll
            for (int k = 0; k < 16; ++k)
                acc = fmaf(awS[h * 16 + k], BIG[k * 480 + j], acc);
            L[idx] = acc;
        }
    }
    if (t < 480) {
        const int f = t / 10, d = t % 10;
        float acc = 0.f;
#pragma unroll
        for (int v = 0; v < 10; ++v)
            acc = fmaf(D[d * 35 + v], WD[(40 + v) * 48 + f], acc);
        float cs = 0.f;
#pragma unroll
        for (int v = 10; v < 35; ++v) cs += D[d * 35 + v];
        acc = fmaf(cs, WD[49 * 48 + f], acc);
        dinS[f * 20 + d] = acc;
        dctin[(long)b * 960 + f * 20 + d] = acc;
    }
    __syncthreads();
    for (int i = t; i < 9216; i += 512) BIG[i] = lw[i];
    for (int i = t; i < 2304; i += 512) WD[i] = gia[i];
    __syncthreads();
    if (t < 480) {
        const int n = t / 10, d = t % 10;
        float acc = lb[n];
#pragma unroll
        for (int h = 0; h < 4; ++h)
#pragma unroll
            for (int f = 0; f < 48; ++f)
                acc = fmaf(BIG[n * 192 + h * 48 + f], L[h * 480 + f * 10 + d], acc);
        dinS[n * 20 + 10 + d] = acc;
        dctin[(long)b * 960 + n * 20 + 10 + d] = acc;
    }
    __syncthreads();
    for (int p = 0; p < 2; ++p) {
        const int idx = t + p * 512;
        if (idx < 960) {
            const int n = idx / 20, d = idx % 20;
            float acc = 0.f;
#pragma unroll
            for (int m = 0; m < 48; ++m)
                acc = fmaf(WD[n * 48 + m], dinS[m * 20 + d], acc);
            z0[((long)b * 48 + n) * 64 + d] = (bf16)acc;
        }
    }
    for (int i = t; i < 2112; i += 512) {
        const int n = i / 44, c = 20 + i % 44;
        z0[((long)b * 48 + n) * 64 + c] = (bf16)0.f;
    }
}

// ---------------- Z[b,n,f] = sum_m att[n,m] * Y[b,m,f] -----------------------
__global__ __launch_bounds__(256) void k_attmul(const float* __restrict__ att,
                                                const bf16* __restrict__ Y,
                                                bf16* __restrict__ Z) {
    const int ft = blockIdx.x;
    const int b = blockIdx.y;
    __shared__ float attS[2304];
    __shared__ unsigned int YS[48 * 68];
    const int t = threadIdx.x;
#pragma unroll
    for (int i = 0; i < 9; ++i) attS[t + i * 256] = att[t + i * 256];
#pragma unroll
    for (int i = 0; i < 3; ++i) {
        const int u = t + i * 256;
        const int m = u >> 4, fg = u & 15;
        const uint4 v = *(const uint4*)(Y + ((long)b * 48 + m) * 512 + ft * 128 + fg * 8);
        *(uint4*)(YS + m * 68 + fg * 4) = v;
    }
    __syncthreads();
    const int ng = t >> 4, fgp = t & 15;
    float acc[3][8];
#pragma unroll
    for (int i = 0; i < 3; ++i)
#pragma unroll
        for (int j = 0; j < 8; ++j) acc[i][j] = 0.f;
    const float* a0 = attS + (3 * ng) * 48;
#pragma unroll 4
    for (int m = 0; m < 48; ++m) {
        const bf16x8 yv = *(const bf16x8*)(YS + m * 68 + fgp * 4);
        float yf[8];
#pragma unroll
        for (int j = 0; j < 8; ++j) yf[j] = (float)yv[j];
        const float a_0 = a0[m];
        const float a_1 = a0[48 + m];
        const float a_2 = a0[96 + m];
#pragma unroll
        for (int j = 0; j < 8; ++j) {
            acc[0][j] = fmaf(a_0, yf[j], acc[0][j]);
            acc[1][j] = fmaf(a_1, yf[j], acc[1][j]);
            acc[2][j] = fmaf(a_2, yf[j], acc[2][j]);
        }
    }
#pragma unroll
    for (int i = 0; i < 3; ++i) {
        const int n = 3 * ng + i;
        bf16x8 o;
#pragma unroll
        for (int j = 0; j < 8; ++j) o[j] = (bf16)acc[i][j];
        *(bf16x8*)(Z + ((long)b * 48 + n) * 512 + ft * 128 + fgp * 8) = o;
    }
}

// ---------------- fused gc_out: T2 = y@gow; goa@T2 + gob + dctin; iDCT -------
// Uses (goa.y).gow == goa.(y.gow); one block per batch, all LDS-resident.
__global__ __launch_bounds__(512) void k_gcout(
    const bf16* __restrict__ Y, const float* __restrict__ goa,
    const float* __restrict__ gow, const float* __restrict__ gob,
    const float* __restrict__ dctin, const float* __restrict__ dct10,
    float* __restrict__ out) {
    const int b = blockIdx.x;
    const int t = threadIdx.x;
    __shared__ bf16 yaS[48 * 512];
    __shared__ bf16 GS[20 * 520];
    __shared__ float goaS[2304];
    __shared__ float T2[960];
    __shared__ float dS[960];
    __shared__ float D[350];
    // stage Y[b]: 48*512 bf16 = 3072 uint4 = 6 * 512  (round-7 bug: was 3*512)
    {
        const uint4* ysrc = (const uint4*)(Y + (long)b * 48 * 512);
#pragma unroll
        for (int i = 0; i < 6; ++i) *((uint4*)yaS + t + i * 512) = ysrc[t + i * 512];
    }
    for (int i = t; i < 10240; i += 512) {
        const int d = i >> 9, k = i & 511;
        GS[d * 520 + k] = (bf16)gow[k * 20 + d];
    }
    for (int i = t; i < 2304; i += 512) goaS[i] = goa[i];
    for (int i = t; i < 350; i += 512) D[i] = dct10[i];
    __syncthreads();
    // T2[m,d] = sum_k Y[b,m,k]*gow[k,d]
#pragma unroll
    for (int p = 0; p < 2; ++p) {
        const int idx = t + p * 512;
        if (idx < 960) {
            const int m = idx / 20, d = idx % 20;
            float acc = 0.f;
            const bf16* yr = yaS + m * 512;
            const bf16* gr = GS + d * 520;
#pragma unroll 8
            for (int k8 = 0; k8 < 64; ++k8) {
                const bf16x8 yv = *(const bf16x8*)(yr + k8 * 8);
                const bf16x8 gv = *(const bf16x8*)(gr + k8 * 8);
#pragma unroll
                for (int j = 0; j < 8; ++j)
                    acc = fmaf((float)yv[j], (float)gv[j], acc);
            }
            T2[idx] = acc;
        }
    }
    __syncthreads();
    // dct_out[n,d] = gob[d] + dctin + sum_m goa[n,m]*T2[m,d]
#pragma unroll
    for (int p = 0; p < 2; ++p) {
        const int idx = t + p * 512;
        if (idx < 960) {
            const int n = idx / 20, d = idx % 20;
            float acc = gob[d] + dctin[(long)b * 960 + idx];
#pragma unroll
            for (int m = 0; m < 48; ++m)
                acc = fmaf(goaS[n * 48 + m], T2[m * 20 + d], acc);
            dS[idx] = acc;
        }
    }
    __syncthreads();
    for (int e = t; e < 1680; e += 512) {
        const int v = e / 48, n = e % 48;
        float acc = 0.f;
#pragma unroll
        for (int d = 0; d < 10; ++d)
            acc = fmaf(D[d * 35 + v], dS[n * 20 + d], acc);
        out[(long)b * 1680 + e] = acc;
    }
}

// ---------------------------------------------------------------------------
// Workspace (BYTE offsets). keyh bf16 (16.8 MB) aliases WS_T; z0 at WS_T+17MB;
// Z aliases WS_T after k_att (keyh dead).
// ---------------------------------------------------------------------------
static constexpr size_t WS_DCT10 = 0;
static constexpr size_t WS_ATTW = 1536;
static constexpr size_t WS_QH = WS_ATTW + 65536;
static constexpr size_t WS_DCTIN = WS_QH + 2097152;
static constexpr size_t WS_DCTOUT = WS_DCTIN + 983040;
static constexpr size_t WS_SRCVAL = WS_DCTOUT + 983040;
static constexpr size_t WS_PAD0 = WS_SRCVAL + 7864320;
static constexpr size_t WS_SRCBF = WS_PAD0 + 8388608;
static constexpr size_t WS_W1TQ = WS_SRCBF + 1229824;
static constexpr size_t WS_W1TK = WS_W1TQ + 1310720;
static constexpr size_t WS_W2TQ = WS_W1TK + 1310720;
static constexpr size_t WS_W2TK = WS_W2TQ + 10485760;
static constexpr size_t WS_GBWT = WS_W2TK + 10485760;
static constexpr size_t WS_R1K = WS_GBWT + 2097152;
static constexpr size_t WS_R1Q = WS_R1K + 20971520;
static constexpr size_t WS_T = WS_R1Q + 5242880;
static constexpr size_t WS_YA = WS_T + 25165824;
static constexpr size_t WS_YB = WS_YA + 12582912;
static constexpr size_t WS_GIWP = WS_YB + 12582912;
static constexpr size_t WS_KEYH = WS_T;
static constexpr size_t WS_Z = WS_T;
static constexpr size_t WS_Z0 = WS_T + 17825792;

extern "C" void kernel_launch(void* const* d_in, const int* in_sizes, int n_in,
                              void* d_out, int out_size, void* d_ws,
                              size_t ws_size, hipStream_t stream) {
    const float* src = (const float*)d_in[0];
    const float* cq1 = (const float*)d_in[1];
    const float* cq2 = (const float*)d_in[2];
    const float* ck1 = (const float*)d_in[3];
    const float* ck2 = (const float*)d_in[4];
    const float* lw = (const float*)d_in[5];
    const float* lb = (const float*)d_in[6];
    const float* giw = (const float*)d_in[7];
    const float* gia = (const float*)d_in[8];
    const float* gib = (const float*)d_in[9];
    const float* gbw = (const float*)d_in[10];
    const float* gba = (const float*)d_in[11];
    const float* gbb = (const float*)d_in[12];
    const float* gow = (const float*)d_in[13];
    const float* goa = (const float*)d_in[14];
    const float* gob = (const float*)d_in[15];
    float* out = (float*)d_out;
    char* ws = (char*)d_ws;

    float* dct10 = (float*)(ws + WS_DCT10);
    bf16* qh = (bf16*)(ws + WS_QH);
    float* dctin = (float*)(ws + WS_DCTIN);
    bf16* keyh = (bf16*)(ws + WS_KEYH);
    bf16* srcbf = (bf16*)(ws + WS_SRCBF);
    bf16* w1tq = (bf16*)(ws + WS_W1TQ);
    bf16* w1tk = (bf16*)(ws + WS_W1TK);
    bf16* w2tq = (bf16*)(ws + WS_W2TQ);
    bf16* w2tk = (bf16*)(ws + WS_W2TK);
    bf16* gbwt = (bf16*)(ws + WS_GBWT);
    bf16* r1k = (bf16*)(ws + WS_R1K);
    bf16* r1q = (bf16*)(ws + WS_R1Q);
    bf16* ya = (bf16*)(ws + WS_YA);
    bf16* yb = (bf16*)(ws + WS_YB);
    bf16* giwP = (bf16*)(ws + WS_GIWP);
    bf16* Z = (bf16*)(ws + WS_Z);
    bf16* z0 = (bf16*)(ws + WS_Z0);

    // 1. all prep in one dispatch
    k_prep<<<52707, 256, 0, stream>>>(src, cq1, ck1, cq2, ck2, gbw, giw, dct10,
                                      srcbf, w1tq, w1tk, w2tq, w2tk, gbwt, giwP);

    // 2. conv1 K+Q, gridDim.x padded to 56 (mult of 8 for XCD L2 locality)
    {
        GP pk{w1tk, srcbf, r1k, 20, 0, 40, 512L * 320, 0L, 5120L * 512};
        GP pq{w1tq, srcbf, r1q, 5, 40, 10, 512L * 320, 0L, 1280L * 512};
        mgemm2<BM_SRC, BM_SRC><<<dim3(56, 4, 4), 256, 0, stream>>>(pk, pq, 40,
                                                                   512, 320);
    }
    // 3. conv2 K+Q, gridDim.x padded to 40; bf16 keyh/qh outputs
    {
        GP pk{w2tk, r1k, keyh, 0, 0, 32, 512L * 2560, 2621440L, 2097152L};
        GP pq{w2tq, r1q, qh, 0, 0, 2, 512L * 2560, 655360L, 131072L};
        mgemm2<BM_R1K, BM_PLAIN><<<dim3(40, 4, 4), 256, 0, stream>>>(pk, pq, 32,
                                                                     512, 2560);
    }

    // 4. fused attention block -> dctin (fp32), z0 (bf16)
    k_att<<<256, 512, 0, stream>>>(qh, keyh, src, dct10, lw, lb, gia, dctin, z0);

    // ---- GCN (reassociated) ----
    mgemm<BM_PLAIN, EPI_TANH_BF16><<<dim3(96, 4, 1), 256, 0, stream>>>(
        giwP, z0, ya, gib, nullptr, 512, 12288, 64, 0, 0, 0L, 0L, 0L);
    k_attmul<<<dim3(4, 256), 256, 0, stream>>>(gba + 0 * 2304, ya, Z);
    mgemm<BM_PLAIN, EPI_TANH_BF16><<<dim3(96, 4, 1), 256, 0, stream>>>(
        gbwt + 0L * 262144, Z, yb, gbb + 0 * 512, nullptr, 512, 12288, 512, 0,
        0, 0L, 0L, 0L);
    k_attmul<<<dim3(4, 256), 256, 0, stream>>>(gba + 1 * 2304, yb, Z);
    mgemm<BM_PLAIN, EPI_TANH_BF16><<<dim3(96, 4, 1), 256, 0, stream>>>(
        gbwt + 1L * 262144, Z, yb, gbb + 1 * 512, ya, 512, 12288, 512, 0, 0,
        0L, 0L, 0L);
    k_attmul<<<dim3(4, 256), 256, 0, stream>>>(gba + 2 * 2304, yb, Z);
    mgemm<BM_PLAIN, EPI_TANH_BF16><<<dim3(96, 4, 1), 256, 0, stream>>>(
        gbwt + 2L * 262144, Z, ya, gbb + 2 * 512, nullptr, 512, 12288, 512, 0,
        0, 0L, 0L, 0L);
    k_attmul<<<dim3(4, 256), 256, 0, stream>>>(gba + 3 * 2304, ya, Z);
    mgemm<BM_PLAIN, EPI_TANH_BF16><<<dim3(96, 4, 1), 256, 0, stream>>>(
        gbwt + 3L * 262144, Z, ya, gbb + 3 * 512, yb, 512, 12288, 512, 0, 0,
        0L, 0L, 0L);

    // gc_out fused: T2 = ya@gow, goa@T2 + gob + dctin, iDCT -> out
    k_gcout<<<256, 512, 0, stream>>>(ya, goa, gow, gob, dctin, dct10, out);
}

// Round 9
// 410.646 us; speedup vs baseline: 4.1307x; 1.0731x over previous
//
#include <hip/hip_runtime.h>
#include <math.h>

// ---------------------------------------------------------------------------
// Problem constants (bs=256, in_feat=48, d_model=512, dct_n=10, input_n=50,
// output_n=25, KERNEL=10, HEADS=4, vl=35, vn=16)
// ---------------------------------------------------------------------------
static constexpr float BN_SCALE_F = 0.9999950000374997f;

typedef __bf16 bf16;
typedef bf16 bf16x8 __attribute__((ext_vector_type(8)));
typedef bf16 bf16x4 __attribute__((ext_vector_type(4)));
typedef float floatx4 __attribute__((ext_vector_type(4)));

#define GLOBAL_AS __attribute__((address_space(1)))
#define LDS_AS __attribute__((address_space(3)))

enum { BM_SRC = 0, BM_R1K = 1, BM_PLAIN = 3 };
enum { EPI_F32 = 0, EPI_RELU_F32 = 1, EPI_RELU_BF16 = 2 };

__device__ __forceinline__ float tanh_fast(float x) {
    // 1 - 2/(e^{2x}+1): exact at 0, saturates correctly at +-inf
    const float e = __expf(2.f * x);
    return 1.f - 2.f / (e + 1.f);
}

// ---------------- mega prep: DCT build + all fp32->bf16 transposes ----------
__device__ __forceinline__ void d_trw1(int id, const float* w, bf16* wt) {
    if (id < 4 * 512 * 320) {
        int ho = id / 320, c = id % 320;
        float v = (c < 288) ? w[(long)ho * 288 + (c % 48) * 6 + (c / 48)] * 1e-3f : 0.f;
        wt[id] = (bf16)v;
    }
}
__device__ __forceinline__ void d_trw2(int id, const float* w, bf16* wt) {
    if (id < 4 * 512 * 2560) {
        int ho = id / 2560, c = id % 2560;
        wt[id] = (bf16)w[(long)ho * 2560 + (c % 512) * 5 + (c / 512)];
    }
}
__global__ __launch_bounds__(256) void k_prep(
    const float* __restrict__ src, const float* __restrict__ cq1,
    const float* __restrict__ ck1, const float* __restrict__ cq2,
    const float* __restrict__ ck2, const float* __restrict__ gbw,
    const float* __restrict__ giw, float* __restrict__ dct10,
    bf16* __restrict__ srcbf, bf16* __restrict__ w1tq, bf16* __restrict__ w1tk,
    bf16* __restrict__ w2tq, bf16* __restrict__ w2tk, bf16* __restrict__ gbwt,
    bf16* __restrict__ giwP) {
    int bb = blockIdx.x;
    const int t = threadIdx.x;
    if (bb < 2) {
        int id = bb * 256 + t;
        if (id < 350) {
            int k = id / 35, i = id % 35;
            double w = (k == 0) ? sqrt(1.0 / 35.0) : sqrt(2.0 / 35.0);
            dct10[id] = (float)(w * cos(3.14159265358979323846 * (i + 0.5) * k / 35.0));
        }
        return;
    }
    bb -= 2;
    if (bb < 2401) {
        int id = bb * 256 + t;
        if (id < 614656) srcbf[id] = (bf16)(id < 614400 ? src[id] : 0.f);
        return;
    }
    bb -= 2401;
    if (bb < 2560) { d_trw1(bb * 256 + t, cq1, w1tq); return; }
    bb -= 2560;
    if (bb < 2560) { d_trw1(bb * 256 + t, ck1, w1tk); return; }
    bb -= 2560;
    if (bb < 20480) { d_trw2(bb * 256 + t, cq2, w2tq); return; }
    bb -= 20480;
    if (bb < 20480) { d_trw2(bb * 256 + t, ck2, w2tk); return; }
    bb -= 20480;
    if (bb < 4096) {
        int id = bb * 256 + t;
        if (id < 4 * 512 * 512) {
            int s = id >> 18, r = id & 262143;
            int m = r >> 9, k = r & 511;
            gbwt[id] = (bf16)gbw[(long)s * 262144 + k * 512 + m];
        }
        return;
    }
    bb -= 4096;
    {
        int id = bb * 256 + t;
        if (id < 512 * 64) {
            int f = id >> 6, k = id & 63;
            giwP[id] = (bf16)(k < 20 ? giw[k * 512 + f] : 0.f);
        }
    }
}

// ---------------- bf16 MFMA NT GEMM (relu epilogues) -------------------------
// SWZ: 1-D grid of 512 blocks; blockIdx&7 = (half<<2)|head so each head's
// A-tile is resident on exactly 2 XCDs (round-8 lesson: A was fetched 8x).
template <int BMODE, int EPI, bool SWZ>
__global__ __launch_bounds__(256) void mgemm(
    const bf16* __restrict__ Ab, const bf16* __restrict__ Bb,
    void* __restrict__ Cb, const int M, const int N, const int K,
    const int NT, const int toff, const long aStr, const long bStr,
    const long cStr) {
    int bx, by, bz;
    if (SWZ) {
        const int i = blockIdx.x;
        const int slot = i & 7;
        bz = slot & 3;
        const int half = slot >> 2;
        const int j = i >> 3;
        bx = half * 16 + (j & 15);
        by = j >> 4;
    } else {
        bx = blockIdx.x; by = blockIdx.y; bz = blockIdx.z;
    }
    __shared__ bf16 As[128 * 64];
    __shared__ bf16 Bs[128 * 64];
    const int tid = threadIdx.x;
    const int wave = tid >> 6;
    const int lane = tid & 63;
    const int wm = (wave & 1) << 6;
    const int wn = (wave >> 1) << 6;
    const int m0 = by * 128;
    const int n0 = bx * 128;
    const bf16* A = Ab + (long)bz * aStr;
    const bf16* B = Bb + (long)bz * bStr;

    const int srow = lane >> 3;
    const int gch = (lane & 7) ^ srow;
    const bf16* aptr[4];
    const bf16* bptr[4];
#pragma unroll
    for (int i = 0; i < 4; ++i) {
        const int ar = wave * 32 + i * 8 + srow;
        aptr[i] = A + (long)(m0 + ar) * K + gch * 8;
        const int n = n0 + ar;
        long bbase;
        if (BMODE == BM_SRC)
            bbase = (long)(n / NT) * 2400 + (long)((n % NT) + toff) * 48;
        else if (BMODE == BM_R1K)
            bbase = (long)((n >> 4) * 20 + (n & 15)) * 512;
        else
            bbase = (long)n * K;
        bptr[i] = B + bbase + gch * 8;
    }
    const int ldsOff = wave * 32 * 64;

    floatx4 acc[4][4];
#pragma unroll
    for (int j = 0; j < 4; ++j)
#pragma unroll
        for (int i = 0; i < 4; ++i) acc[j][i] = (floatx4){0.f, 0.f, 0.f, 0.f};

    const int fr = lane & 15;
    const int fq = lane >> 4;
    const int fx = lane & 7;

    for (int k0 = 0; k0 < K; k0 += 64) {
#pragma unroll
        for (int i = 0; i < 4; ++i) {
            __builtin_amdgcn_global_load_lds(
                (const GLOBAL_AS void*)(aptr[i] + k0),
                (LDS_AS void*)(As + ldsOff + i * 512), 16, 0, 0);
            __builtin_amdgcn_global_load_lds(
                (const GLOBAL_AS void*)(bptr[i] + k0),
                (LDS_AS void*)(Bs + ldsOff + i * 512), 16, 0, 0);
        }
        __syncthreads();
#pragma unroll
        for (int kk = 0; kk < 2; ++kk) {
            bf16x8 af[4], bfr[4];
#pragma unroll
            for (int im = 0; im < 4; ++im)
                af[im] = *(const bf16x8*)(As + (wm + im * 16 + fr) * 64 +
                                          ((((kk << 2) + fq) ^ fx) << 3));
#pragma unroll
            for (int in = 0; in < 4; ++in)
                bfr[in] = *(const bf16x8*)(Bs + (wn + in * 16 + fr) * 64 +
                                           ((((kk << 2) + fq) ^ fx) << 3));
#pragma unroll
            for (int in = 0; in < 4; ++in)
#pragma unroll
                for (int im = 0; im < 4; ++im)
                    acc[in][im] = __builtin_amdgcn_mfma_f32_16x16x32_bf16(
                        af[im], bfr[in], acc[in][im], 0, 0, 0);
        }
        __syncthreads();
    }
#pragma unroll
    for (int in = 0; in < 4; ++in) {
        const long n = n0 + wn + in * 16 + fr;
#pragma unroll
        for (int im = 0; im < 4; ++im) {
            floatx4 v = acc[in][im];
            const long m = m0 + wm + im * 16 + (fq << 2);
            v.x = fmaxf(v.x, 0.f);
            v.y = fmaxf(v.y, 0.f);
            v.z = fmaxf(v.z, 0.f);
            v.w = fmaxf(v.w, 0.f);
            if (EPI == EPI_RELU_BF16) {
                bf16* C = (bf16*)Cb + (long)bz * cStr + n * M + m;
                bf16x4 ov;
                ov[0] = (bf16)v.x;
                ov[1] = (bf16)v.y;
                ov[2] = (bf16)v.z;
                ov[3] = (bf16)v.w;
                *(bf16x4*)C = ov;
            } else {
                float* C = (float*)Cb + (long)bz * cStr + n * M + m;
                *(floatx4*)C = v;
            }
        }
    }
}

// ---------------- dual-branch GEMM for conv1 (padded grid) -------------------
struct GP {
    const bf16* A;
    const bf16* B;
    bf16* C;
    int NT;
    int toff;
    int nTiles;
    long aStr, bStr, cStr;
};
template <int BM1, int BM2>
__global__ __launch_bounds__(256) void mgemm2(GP p1, GP p2, const int splitX,
                                              const int M, const int K) {
    const bool first = (int)blockIdx.x < splitX;
    const GP p = first ? p1 : p2;
    const int bx = first ? (int)blockIdx.x : (int)blockIdx.x - splitX;
    if (bx >= p.nTiles) return;
    __shared__ bf16 As[128 * 64];
    __shared__ bf16 Bs[128 * 64];
    const int tid = threadIdx.x;
    const int wave = tid >> 6;
    const int lane = tid & 63;
    const int wm = (wave & 1) << 6;
    const int wn = (wave >> 1) << 6;
    const int m0 = blockIdx.y * 128;
    const int n0 = bx * 128;
    const bf16* A = p.A + (long)blockIdx.z * p.aStr;
    const bf16* B = p.B + (long)blockIdx.z * p.bStr;

    const int srow = lane >> 3;
    const int gch = (lane & 7) ^ srow;
    const bf16* aptr[4];
    const bf16* bptr[4];
#pragma unroll
    for (int i = 0; i < 4; ++i) {
        const int ar = wave * 32 + i * 8 + srow;
        aptr[i] = A + (long)(m0 + ar) * K + gch * 8;
        const int n = n0 + ar;
        long bbase;
        const bool isSrc = first ? (BM1 == BM_SRC) : (BM2 == BM_SRC);
        const bool isR1k = first ? (BM1 == BM_R1K) : (BM2 == BM_R1K);
        if (isSrc)
            bbase = (long)(n / p.NT) * 2400 + (long)((n % p.NT) + p.toff) * 48;
        else if (isR1k)
            bbase = (long)((n >> 4) * 20 + (n & 15)) * 512;
        else
            bbase = (long)n * K;
        bptr[i] = B + bbase + gch * 8;
    }
    const int ldsOff = wave * 32 * 64;

    floatx4 acc[4][4];
#pragma unroll
    for (int j = 0; j < 4; ++j)
#pragma unroll
        for (int i = 0; i < 4; ++i) acc[j][i] = (floatx4){0.f, 0.f, 0.f, 0.f};

    const int fr = lane & 15;
    const int fq = lane >> 4;
    const int fx = lane & 7;

    for (int k0 = 0; k0 < K; k0 += 64) {
#pragma unroll
        for (int i = 0; i < 4; ++i) {
            __builtin_amdgcn_global_load_lds(
                (const GLOBAL_AS void*)(aptr[i] + k0),
                (LDS_AS void*)(As + ldsOff + i * 512), 16, 0, 0);
            __builtin_amdgcn_global_load_lds(
                (const GLOBAL_AS void*)(bptr[i] + k0),
                (LDS_AS void*)(Bs + ldsOff + i * 512), 16, 0, 0);
        }
        __syncthreads();
#pragma unroll
        for (int kk = 0; kk < 2; ++kk) {
            bf16x8 af[4], bfr[4];
#pragma unroll
            for (int im = 0; im < 4; ++im)
                af[im] = *(const bf16x8*)(As + (wm + im * 16 + fr) * 64 +
                                          ((((kk << 2) + fq) ^ fx) << 3));
#pragma unroll
            for (int in = 0; in < 4; ++in)
                bfr[in] = *(const bf16x8*)(Bs + (wn + in * 16 + fr) * 64 +
                                           ((((kk << 2) + fq) ^ fx) << 3));
#pragma unroll
            for (int in = 0; in < 4; ++in)
#pragma unroll
                for (int im = 0; im < 4; ++im)
                    acc[in][im] = __builtin_amdgcn_mfma_f32_16x16x32_bf16(
                        af[im], bfr[in], acc[in][im], 0, 0, 0);
        }
        __syncthreads();
    }
#pragma unroll
    for (int in = 0; in < 4; ++in) {
        const long n = n0 + wn + in * 16 + fr;
#pragma unroll
        for (int im = 0; im < 4; ++im) {
            floatx4 v = acc[in][im];
            const long m = m0 + wm + im * 16 + (fq << 2);
            v.x = fmaxf(v.x, 0.f);
            v.y = fmaxf(v.y, 0.f);
            v.z = fmaxf(v.z, 0.f);
            v.w = fmaxf(v.w, 0.f);
            bf16* C = p.C + (long)blockIdx.z * p.cStr + n * M + m;
            bf16x4 ov;
            ov[0] = (bf16)v.x;
            ov[1] = (bf16)v.y;
            ov[2] = (bf16)v.z;
            ov[3] = (bf16)v.w;
            *(bf16x4*)C = ov;
        }
    }
}

// ---------------- fused attention block (one block per batch b) --------------
__global__ __launch_bounds__(512) void k_att(
    const bf16* __restrict__ qh, const bf16* __restrict__ keyh,
    const float* __restrict__ src, const float* __restrict__ dct10,
    const float* __restrict__ lw, const float* __restrict__ lb,
    const float* __restrict__ gia, float* __restrict__ dctin,
    bf16* __restrict__ z0) {
    const int b = blockIdx.x;
    const int t = threadIdx.x;
    __shared__ float BIG[9216];
    __shared__ float WD[2400];
    __shared__ float D[350];
    __shared__ float L[1920];
    __shared__ float dinS[960];
    __shared__ float sS[64];
    __shared__ float awS[64];

    {
        const int g = t >> 3, lane = t & 7;
        const int h = g >> 4, tt = g & 15;
        const bf16* q = qh + ((long)h * 256 + b) * 512 + lane * 64;
        const bf16* kr = keyh + (long)h * 2097152 + ((long)b * 16 + tt) * 512 + lane * 64;
        float p = 0.f;
#pragma unroll
        for (int i = 0; i < 8; ++i) {
            const bf16x8 qv = *(const bf16x8*)(q + i * 8);
            const bf16x8 kv = *(const bf16x8*)(kr + i * 8);
#pragma unroll
            for (int j = 0; j < 8; ++j) p = fmaf((float)qv[j], (float)kv[j], p);
        }
        p += __shfl_down(p, 4, 8);
        p += __shfl_down(p, 2, 8);
        p += __shfl_down(p, 1, 8);
        if (lane == 0) sS[g] = p + 1e-15f;
    }
    for (int i = t; i < 2400; i += 512) WD[i] = src[(long)b * 2400 + i];
    for (int i = t; i < 350; i += 512) D[i] = dct10[i];
    __syncthreads();
    if (t < 4) {
        float s = 0.f;
#pragma unroll
        for (int k = 0; k < 16; ++k) s += sS[t * 16 + k];
        const float inv = 1.f / s;
#pragma unroll
        for (int k = 0; k < 16; ++k) awS[t * 16 + k] = sS[t * 16 + k] * inv;
    }
    __syncthreads();
    for (int p = 0; p < 15; ++p) {
        const int idx = t + p * 512;
        const int n = idx / 480, j = idx % 480;
        const int f = j / 10, d = j % 10;
        float acc = 0.f;
#pragma unroll
        for (int v = 0; v < 35; ++v)
            acc = fmaf(D[d * 35 + v], WD[(n + v) * 48 + f], acc);
        BIG[idx] = acc;
    }
    __syncthreads();
    for (int p = 0; p < 4; ++p) {
        const int idx = t + p * 512;
        if (idx < 1920) {
            const int h = idx / 480, j = idx % 480;
            float acc = 0.f;
#pragma unroll
            for (int k = 0; k < 16; ++k)
                acc = fmaf(awS[h * 16 + k], BIG[k * 480 + j], acc);
            L[idx] = acc;
        }
    }
    if (t < 480) {
        const int f = t / 10, d = t % 10;
        float acc = 0.f;
#pragma unroll
        for (int v = 0; v < 10; ++v)
            acc = fmaf(D[d * 35 + v], WD[(40 + v) * 48 + f], acc);
        float cs = 0.f;
#pragma unroll
        for (int v = 10; v < 35; ++v) cs += D[d * 35 + v];
        acc = fmaf(cs, WD[49 * 48 + f], acc);
        dinS[f * 20 + d] = acc;
        dctin[(long)b * 960 + f * 20 + d] = acc;
    }
    __syncthreads();
    for (int i = t; i < 9216; i += 512) BIG[i] = lw[i];
    for (int i = t; i < 2304; i += 512) WD[i] = gia[i];
    __syncthreads();
    if (t < 480) {
        const int n = t / 10, d = t % 10;
        float acc = lb[n];
#pragma unroll
        for (int h = 0; h < 4; ++h)
#pragma unroll
            for (int f = 0; f < 48; ++f)
                acc = fmaf(BIG[n * 192 + h * 48 + f], L[h * 480 + f * 10 + d], acc);
        dinS[n * 20 + 10 + d] = acc;
        dctin[(long)b * 960 + n * 20 + 10 + d] = acc;
    }
    __syncthreads();
    for (int p = 0; p < 2; ++p) {
        const int idx = t + p * 512;
        if (idx < 960) {
            const int n = idx / 20, d = idx % 20;
            float acc = 0.f;
#pragma unroll
            for (int m = 0; m < 48; ++m)
                acc = fmaf(WD[n * 48 + m], dinS[m * 20 + d], acc);
            z0[((long)b * 48 + n) * 64 + d] = (bf16)acc;
        }
    }
    for (int i = t; i < 2112; i += 512) {
        const int n = i / 44, c = 20 + i % 44;
        z0[((long)b * 48 + n) * 64 + c] = (bf16)0.f;
    }
}

// ---------------- GCN mega-kernel helpers ------------------------------------
// All per-batch state LDS-resident. Row-major [48][520] (pad 8: row=1040 B,
// 16B-aligned, A-frag b128 2-way bank = free).
// MFMA convention (established r4-r8): D[row=m_A=quad*4+r][col=n_B=lane&15];
// A-frag m=lane&15, k=quad*8+j; B-frag n=lane&15, k=quad*8+j.

// OUT[i][f] = act(sum_k Z[i][k]*Bg_row_f[k] + bias[f]) (+res) ; Bg rows K-contig
__device__ __forceinline__ void gcn_matmul(const bf16* zS, const bf16* Bg,
                                           const int K, const float* bias,
                                           const bf16* resS, bf16* outS,
                                           const int wave, const int lane) {
    const int fr = lane & 15, fq = lane >> 4;
    const int f0 = wave * 64;
    floatx4 acc[3][4];
#pragma unroll
    for (int it = 0; it < 3; ++it)
#pragma unroll
        for (int jt = 0; jt < 4; ++jt) acc[it][jt] = (floatx4){0.f, 0.f, 0.f, 0.f};
#pragma unroll 4
    for (int k0 = 0; k0 < K; k0 += 32) {
        bf16x8 af[3];
#pragma unroll
        for (int it = 0; it < 3; ++it)
            af[it] = *(const bf16x8*)(zS + (it * 16 + fr) * 520 + k0 + fq * 8);
        bf16x8 bfv[4];
#pragma unroll
        for (int jt = 0; jt < 4; ++jt)
            bfv[jt] = *(const bf16x8*)(Bg + (long)(f0 + jt * 16 + fr) * K + k0 + fq * 8);
#pragma unroll
        for (int it = 0; it < 3; ++it)
#pragma unroll
            for (int jt = 0; jt < 4; ++jt)
                acc[it][jt] = __builtin_amdgcn_mfma_f32_16x16x32_bf16(
                    af[it], bfv[jt], acc[it][jt], 0, 0, 0);
    }
#pragma unroll
    for (int jt = 0; jt < 4; ++jt) {
        const int f = f0 + jt * 16 + fr;
        const float bv = bias[f];
#pragma unroll
        for (int it = 0; it < 3; ++it)
#pragma unroll
            for (int r = 0; r < 4; ++r) {
                const int irow = it * 16 + fq * 4 + r;
                float v = tanh_fast((acc[it][jt][r] + bv) * BN_SCALE_F);
                if (resS) v += (float)resS[irow * 520 + f];
                outS[irow * 520 + f] = (bf16)v;
            }
    }
}

// Z[i][f] = sum_m att[i][m] * Y[m][f]; att LDS [48][72] (cols 48..71 zero)
__device__ __forceinline__ void gcn_attmul(const bf16* attS, const bf16* yS,
                                           bf16* zS, const int wave,
                                           const int lane) {
    const int fr = lane & 15, fq = lane >> 4;
    const int f0 = wave * 64;
    floatx4 acc[3][4];
#pragma unroll
    for (int it = 0; it < 3; ++it)
#pragma unroll
        for (int jt = 0; jt < 4; ++jt) acc[it][jt] = (floatx4){0.f, 0.f, 0.f, 0.f};
#pragma unroll
    for (int k0 = 0; k0 < 64; k0 += 32) {
        bf16x8 af[3];
#pragma unroll
        for (int it = 0; it < 3; ++it)
            af[it] = *(const bf16x8*)(attS + (it * 16 + fr) * 72 + k0 + fq * 8);
        bf16x8 bfv[4];
#pragma unroll
        for (int jt = 0; jt < 4; ++jt) {
            const int f = f0 + jt * 16 + fr;
            bf16x8 v;
#pragma unroll
            for (int e = 0; e < 8; ++e) {
                int m = k0 + fq * 8 + e;
                m = m < 48 ? m : 47;  // att cols >=48 are zero -> safe clamp
                v[e] = yS[m * 520 + f];
            }
            bfv[jt] = v;
        }
#pragma unroll
        for (int it = 0; it < 3; ++it)
#pragma unroll
            for (int jt = 0; jt < 4; ++jt)
                acc[it][jt] = __builtin_amdgcn_mfma_f32_16x16x32_bf16(
                    af[it], bfv[jt], acc[it][jt], 0, 0, 0);
    }
#pragma unroll
    for (int jt = 0; jt < 4; ++jt) {
        const int f = f0 + jt * 16 + fr;
#pragma unroll
        for (int it = 0; it < 3; ++it)
#pragma unroll
            for (int r = 0; r < 4; ++r)
                zS[(it * 16 + fq * 4 + r) * 520 + f] = (bf16)acc[it][jt][r];
    }
}

// ---------------- GCN mega-kernel: layer0 + 4 layers + gc_out + iDCT ---------
// 256 blocks (1/CU), 512 threads, ~153 KB LDS. W streamed L2->B-fragments.
__global__ __launch_bounds__(512) void k_gcn(
    const bf16* __restrict__ z0, const bf16* __restrict__ giwP,
    const float* __restrict__ gib, const bf16* __restrict__ gbwt,
    const float* __restrict__ gba, const float* __restrict__ gbb,
    const float* __restrict__ goa, const float* __restrict__ gow,
    const float* __restrict__ gob, const float* __restrict__ dctin,
    const float* __restrict__ dct10, float* __restrict__ out) {
    const int b = blockIdx.x;
    const int t = threadIdx.x;
    const int wave = t >> 6, lane = t & 63;
    __shared__ __align__(16) bf16 yaS[48 * 520];
    __shared__ __align__(16) bf16 ybS[48 * 520];
    __shared__ __align__(16) bf16 zS[48 * 520];
    __shared__ __align__(16) bf16 attS[48 * 72];

    // layer 0: zS <- z0[b] (48x64, pre-zero-padded); ya = tanh(z0@giwP + gib)
    if (t < 384) {
        const int r = t >> 3, c = t & 7;
        *(bf16x8*)(zS + r * 520 + c * 8) =
            *(const bf16x8*)(z0 + ((long)b * 48 + r) * 64 + c * 8);
    }
    __syncthreads();
    gcn_matmul(zS, giwP, 64, gib, nullptr, yaS, wave, lane);
    __syncthreads();

#pragma unroll
    for (int l = 0; l < 4; ++l) {
        bf16* Yin = (l == 0 || l == 3) ? yaS : ybS;
        bf16* Yout = (l < 2) ? ybS : yaS;
        bf16* Res = (l == 1) ? yaS : (l == 3 ? ybS : nullptr);
        // stage att (bf16, zero-pad cols 48..71)
        for (int i = t; i < 48 * 72; i += 512) {
            const int rr = i / 72, c = i % 72;
            attS[i] = (bf16)(c < 48 ? gba[l * 2304 + rr * 48 + c] : 0.f);
        }
        __syncthreads();
        gcn_attmul(attS, Yin, zS, wave, lane);
        __syncthreads();
        gcn_matmul(zS, gbwt + (long)l * 262144, 512, gbb + l * 512, Res, Yout,
                   wave, lane);
        __syncthreads();
    }
    // ---- gc_out + iDCT (final Y = yaS; ybS/zS/attS dead -> aliased) ----
    bf16* GS = zS;                                   // [20][520] gow^T
    float* goaS = (float*)((char*)zS + 24576);       // 2304 f32
    float* Df = (float*)attS;                        // 350 f32
    float* T2 = (float*)ybS;                         // 960 f32
    float* dS = ((float*)ybS) + 1024;                // 960 f32
    for (int i = t; i < 10240; i += 512) {
        const int d = i >> 9, k = i & 511;
        GS[d * 520 + k] = (bf16)gow[k * 20 + d];
    }
    for (int i = t; i < 2304; i += 512) goaS[i] = goa[i];
    if (t < 350) Df[t] = dct10[t];
    __syncthreads();
    // T2[m][d] = sum_k ya[m][k] * gow[k][d]
    for (int idx = t; idx < 960; idx += 512) {
        const int m = idx / 20, d = idx % 20;
        float acc = 0.f;
        const bf16* yr = yaS + m * 520;
        const bf16* gr = GS + d * 520;
#pragma unroll 8
        for (int k8 = 0; k8 < 64; ++k8) {
            const bf16x8 yv = *(const bf16x8*)(yr + k8 * 8);
            const bf16x8 gv = *(const bf16x8*)(gr + k8 * 8);
#pragma unroll
            for (int j = 0; j < 8; ++j) acc = fmaf((float)yv[j], (float)gv[j], acc);
        }
        T2[idx] = acc;
    }
    __syncthreads();
    // dct_out[n][d] = gob[d] + dctin + sum_m goa[n][m]*T2[m][d]
    for (int idx = t; idx < 960; idx += 512) {
        const int n = idx / 20, d = idx % 20;
        float acc = gob[d] + dctin[(long)b * 960 + idx];
#pragma unroll
        for (int m = 0; m < 48; ++m)
            acc = fmaf(goaS[n * 48 + m], T2[m * 20 + d], acc);
        dS[idx] = acc;
    }
    __syncthreads();
    for (int e = t; e < 1680; e += 512) {
        const int v = e / 48, n = e % 48;
        float acc = 0.f;
#pragma unroll
        for (int d = 0; d < 10; ++d)
            acc = fmaf(Df[d * 35 + v], dS[n * 20 + d], acc);
        out[(long)b * 1680 + e] = acc;
    }
}

// ---------------------------------------------------------------------------
// Workspace (BYTE offsets). keyh bf16 (16.8 MB) aliases WS_T; z0 at WS_T+17MB
// (disjoint from live keyh; both dead regions reused nowhere else now).
// ---------------------------------------------------------------------------
static constexpr size_t WS_DCT10 = 0;
static constexpr size_t WS_ATTW = 1536;
static constexpr size_t WS_QH = WS_ATTW + 65536;
static constexpr size_t WS_DCTIN = WS_QH + 2097152;
static constexpr size_t WS_DCTOUT = WS_DCTIN + 983040;
static constexpr size_t WS_SRCVAL = WS_DCTOUT + 983040;
static constexpr size_t WS_PAD0 = WS_SRCVAL + 7864320;
static constexpr size_t WS_SRCBF = WS_PAD0 + 8388608;
static constexpr size_t WS_W1TQ = WS_SRCBF + 1229824;
static constexpr size_t WS_W1TK = WS_W1TQ + 1310720;
static constexpr size_t WS_W2TQ = WS_W1TK + 1310720;
static constexpr size_t WS_W2TK = WS_W2TQ + 10485760;
static constexpr size_t WS_GBWT = WS_W2TK + 10485760;
static constexpr size_t WS_R1K = WS_GBWT + 2097152;
static constexpr size_t WS_R1Q = WS_R1K + 20971520;
static constexpr size_t WS_T = WS_R1Q + 5242880;
static constexpr size_t WS_GIWP = WS_T + 50331648;
static constexpr size_t WS_KEYH = WS_T;                 // bf16, 16777216 B
static constexpr size_t WS_Z0 = WS_T + 17825792;        // bf16, 1572864 B

extern "C" void kernel_launch(void* const* d_in, const int* in_sizes, int n_in,
                              void* d_out, int out_size, void* d_ws,
                              size_t ws_size, hipStream_t stream) {
    const float* src = (const float*)d_in[0];
    const float* cq1 = (const float*)d_in[1];
    const float* cq2 = (const float*)d_in[2];
    const float* ck1 = (const float*)d_in[3];
    const float* ck2 = (const float*)d_in[4];
    const float* lw = (const float*)d_in[5];
    const float* lb = (const float*)d_in[6];
    const float* giw = (const float*)d_in[7];
    const float* gia = (const float*)d_in[8];
    const float* gib = (const float*)d_in[9];
    const float* gbw = (const float*)d_in[10];
    const float* gba = (const float*)d_in[11];
    const float* gbb = (const float*)d_in[12];
    const float* gow = (const float*)d_in[13];
    const float* goa = (const float*)d_in[14];
    const float* gob = (const float*)d_in[15];
    float* out = (float*)d_out;
    char* ws = (char*)d_ws;

    float* dct10 = (float*)(ws + WS_DCT10);
    bf16* qh = (bf16*)(ws + WS_QH);
    float* dctin = (float*)(ws + WS_DCTIN);
    bf16* keyh = (bf16*)(ws + WS_KEYH);
    bf16* srcbf = (bf16*)(ws + WS_SRCBF);
    bf16* w1tq = (bf16*)(ws + WS_W1TQ);
    bf16* w1tk = (bf16*)(ws + WS_W1TK);
    bf16* w2tq = (bf16*)(ws + WS_W2TQ);
    bf16* w2tk = (bf16*)(ws + WS_W2TK);
    bf16* gbwt = (bf16*)(ws + WS_GBWT);
    bf16* r1k = (bf16*)(ws + WS_R1K);
    bf16* r1q = (bf16*)(ws + WS_R1Q);
    bf16* giwP = (bf16*)(ws + WS_GIWP);
    bf16* z0 = (bf16*)(ws + WS_Z0);

    // 1. all prep in one dispatch
    k_prep<<<52707, 256, 0, stream>>>(src, cq1, ck1, cq2, ck2, gbw, giw, dct10,
                                      srcbf, w1tq, w1tk, w2tq, w2tk, gbwt, giwP);

    // 2. conv1 K+Q fused, gridDim.x padded to 56
    {
        GP pk{w1tk, srcbf, r1k, 20, 0, 40, 512L * 320, 0L, 5120L * 512};
        GP pq{w1tq, srcbf, r1q, 5, 40, 10, 512L * 320, 0L, 1280L * 512};
        mgemm2<BM_SRC, BM_SRC><<<dim3(56, 4, 4), 256, 0, stream>>>(pk, pq, 40,
                                                                   512, 320);
    }
    // 3a. conv2-K: 1-D 512-block grid, head->XCD-pair swizzle
    mgemm<BM_R1K, EPI_RELU_BF16, true><<<512, 256, 0, stream>>>(
        w2tk, r1k, keyh, 512, 4096, 2560, 0, 0, 512L * 2560, 2621440L,
        2097152L);
    // 3b. conv2-Q (small)
    mgemm<BM_PLAIN, EPI_RELU_BF16, false><<<dim3(2, 4, 4), 256, 0, stream>>>(
        w2tq, r1q, qh, 512, 256, 2560, 0, 0, 512L * 2560, 655360L, 131072L);

    // 4. fused attention block -> dctin (fp32), z0 (bf16)
    k_att<<<256, 512, 0, stream>>>(qh, keyh, src, dct10, lw, lb, gia, dctin, z0);

    // 5. whole GCN (layer0 + 4 layers + gc_out + iDCT) in one dispatch
    k_gcn<<<256, 512, 0, stream>>>(z0, giwP, gib, gbwt, gba, gbb, goa, gow,
                                   gob, dctin, dct10, out);
}

// Round 10
// 373.495 us; speedup vs baseline: 4.5416x; 1.0995x over previous
//
#include <hip/hip_runtime.h>
#include <math.h>

// ---------------------------------------------------------------------------
// Problem constants (bs=256, in_feat=48, d_model=512, dct_n=10, input_n=50,
// output_n=25, KERNEL=10, HEADS=4, vl=35, vn=16)
// ---------------------------------------------------------------------------
static constexpr float BN_SCALE_F = 0.9999950000374997f;

typedef __bf16 bf16;
typedef bf16 bf16x8 __attribute__((ext_vector_type(8)));
typedef bf16 bf16x4 __attribute__((ext_vector_type(4)));
typedef float floatx4 __attribute__((ext_vector_type(4)));

#define GLOBAL_AS __attribute__((address_space(1)))
#define LDS_AS __attribute__((address_space(3)))

enum { BM_SRC = 0, BM_R1K = 1, BM_PLAIN = 3 };

__device__ __forceinline__ float tanh_fast(float x) {
    const float e = __expf(2.f * x);
    return 1.f - 2.f / (e + 1.f);
}

// ---------------- mega prep -------------------------------------------------
// segments (blocks): dct 2 | cvtsrc 2401 | trw1q 2560 | trw1k 2560 |
// trw2q 2048 (per-ho LDS) | trw2k 2048 | trgw 256 (64x64 tiles) | trgiw 128
__device__ __forceinline__ void d_trw1(int id, const float* w, bf16* wt) {
    if (id < 4 * 512 * 320) {
        int ho = id / 320, c = id % 320;
        float v = (c < 288) ? w[(long)ho * 288 + (c % 48) * 6 + (c / 48)] * 1e-3f : 0.f;
        wt[id] = (bf16)v;
    }
}
__global__ __launch_bounds__(256) void k_prep(
    const float* __restrict__ src, const float* __restrict__ cq1,
    const float* __restrict__ ck1, const float* __restrict__ cq2,
    const float* __restrict__ ck2, const float* __restrict__ gbw,
    const float* __restrict__ giw, float* __restrict__ dct10,
    bf16* __restrict__ srcbf, bf16* __restrict__ w1tq, bf16* __restrict__ w1tk,
    bf16* __restrict__ w2tq, bf16* __restrict__ w2tk, bf16* __restrict__ gbwt,
    bf16* __restrict__ giwP) {
    __shared__ float lds[4160];  // 16.6 KB: trw2 (2560) / trgw (64*65)
    int bb = blockIdx.x;
    const int t = threadIdx.x;
    if (bb < 2) {
        int id = bb * 256 + t;
        if (id < 350) {
            int k = id / 35, i = id % 35;
            double w = (k == 0) ? sqrt(1.0 / 35.0) : sqrt(2.0 / 35.0);
            dct10[id] = (float)(w * cos(3.14159265358979323846 * (i + 0.5) * k / 35.0));
        }
        return;
    }
    bb -= 2;
    if (bb < 2401) {
        int id = bb * 256 + t;
        if (id < 614656) srcbf[id] = (bf16)(id < 614400 ? src[id] : 0.f);
        return;
    }
    bb -= 2401;
    if (bb < 2560) { d_trw1(bb * 256 + t, cq1, w1tq); return; }
    bb -= 2560;
    if (bb < 2560) { d_trw1(bb * 256 + t, ck1, w1tk); return; }
    bb -= 2560;
    if (bb < 4096) {  // trw2: one block per ho (q first 2048, then k)
        const bool isQ = bb < 2048;
        const int ho = isQ ? bb : bb - 2048;
        const float* wrow = (isQ ? cq2 : ck2) + (long)ho * 2560;
        bf16* orow = (isQ ? w2tq : w2tk) + (long)ho * 2560;
        for (int j = t; j < 2560; j += 256) lds[j] = wrow[j];
        __syncthreads();
        for (int c = t; c < 2560; c += 256) {
            const int k = c >> 9, ii = c & 511;
            orow[c] = (bf16)lds[ii * 5 + k];
        }
        return;
    }
    bb -= 4096;
    if (bb < 256) {  // trgw: gbw[s][k][m] -> gbwt[s][m][k], 64x64 tiles
        const int s = bb >> 6, tile = bb & 63;
        const int tr = tile >> 3, tc = tile & 7;
        const float* in = gbw + (long)s * 262144;
        bf16* o = gbwt + (long)s * 262144;
#pragma unroll
        for (int r = 0; r < 16; ++r) {
            const int kl = (t >> 6) * 16 + r, ml = t & 63;
            lds[kl * 65 + ml] = in[(long)(tr * 64 + kl) * 512 + tc * 64 + ml];
        }
        __syncthreads();
#pragma unroll
        for (int r = 0; r < 16; ++r) {
            const int ml = (t >> 6) * 16 + r, kl = t & 63;
            o[(long)(tc * 64 + ml) * 512 + tr * 64 + kl] = (bf16)lds[kl * 65 + ml];
        }
        return;
    }
    bb -= 256;
    {
        int id = bb * 256 + t;
        if (id < 512 * 64) {
            int f = id >> 6, k = id & 63;
            giwP[id] = (bf16)(k < 20 ? giw[k * 512 + f] : 0.f);
        }
    }
}

// ---------------- dual-branch GEMM for conv1 (padded grid) -------------------
struct GP {
    const bf16* A;
    const bf16* B;
    bf16* C;
    int NT;
    int toff;
    int nTiles;
    long aStr, bStr, cStr;
};
template <int BM1, int BM2>
__global__ __launch_bounds__(256) void mgemm2(GP p1, GP p2, const int splitX,
                                              const int M, const int K) {
    const bool first = (int)blockIdx.x < splitX;
    const GP p = first ? p1 : p2;
    const int bx = first ? (int)blockIdx.x : (int)blockIdx.x - splitX;
    if (bx >= p.nTiles) return;
    __shared__ bf16 As[128 * 64];
    __shared__ bf16 Bs[128 * 64];
    const int tid = threadIdx.x;
    const int wave = tid >> 6;
    const int lane = tid & 63;
    const int wm = (wave & 1) << 6;
    const int wn = (wave >> 1) << 6;
    const int m0 = blockIdx.y * 128;
    const int n0 = bx * 128;
    const bf16* A = p.A + (long)blockIdx.z * p.aStr;
    const bf16* B = p.B + (long)blockIdx.z * p.bStr;

    const int srow = lane >> 3;
    const int gch = (lane & 7) ^ srow;
    const bf16* aptr[4];
    const bf16* bptr[4];
#pragma unroll
    for (int i = 0; i < 4; ++i) {
        const int ar = wave * 32 + i * 8 + srow;
        aptr[i] = A + (long)(m0 + ar) * K + gch * 8;
        const int n = n0 + ar;
        long bbase;
        const bool isSrc = first ? (BM1 == BM_SRC) : (BM2 == BM_SRC);
        if (isSrc)
            bbase = (long)(n / p.NT) * 2400 + (long)((n % p.NT) + p.toff) * 48;
        else
            bbase = (long)n * K;
        bptr[i] = B + bbase + gch * 8;
    }
    const int ldsOff = wave * 32 * 64;

    floatx4 acc[4][4];
#pragma unroll
    for (int j = 0; j < 4; ++j)
#pragma unroll
        for (int i = 0; i < 4; ++i) acc[j][i] = (floatx4){0.f, 0.f, 0.f, 0.f};

    const int fr = lane & 15;
    const int fq = lane >> 4;
    const int fx = lane & 7;

    for (int k0 = 0; k0 < K; k0 += 64) {
#pragma unroll
        for (int i = 0; i < 4; ++i) {
            __builtin_amdgcn_global_load_lds(
                (const GLOBAL_AS void*)(aptr[i] + k0),
                (LDS_AS void*)(As + ldsOff + i * 512), 16, 0, 0);
            __builtin_amdgcn_global_load_lds(
                (const GLOBAL_AS void*)(bptr[i] + k0),
                (LDS_AS void*)(Bs + ldsOff + i * 512), 16, 0, 0);
        }
        __syncthreads();
#pragma unroll
        for (int kk = 0; kk < 2; ++kk) {
            bf16x8 af[4], bfr[4];
#pragma unroll
            for (int im = 0; im < 4; ++im)
                af[im] = *(const bf16x8*)(As + (wm + im * 16 + fr) * 64 +
                                          ((((kk << 2) + fq) ^ fx) << 3));
#pragma unroll
            for (int in = 0; in < 4; ++in)
                bfr[in] = *(const bf16x8*)(Bs + (wn + in * 16 + fr) * 64 +
                                           ((((kk << 2) + fq) ^ fx) << 3));
#pragma unroll
            for (int in = 0; in < 4; ++in)
#pragma unroll
                for (int im = 0; im < 4; ++im)
                    acc[in][im] = __builtin_amdgcn_mfma_f32_16x16x32_bf16(
                        af[im], bfr[in], acc[in][im], 0, 0, 0);
        }
        __syncthreads();
    }
#pragma unroll
    for (int in = 0; in < 4; ++in) {
        const long n = n0 + wn + in * 16 + fr;
#pragma unroll
        for (int im = 0; im < 4; ++im) {
            floatx4 v = acc[in][im];
            const long m = m0 + wm + im * 16 + (fq << 2);
            v.x = fmaxf(v.x, 0.f);
            v.y = fmaxf(v.y, 0.f);
            v.z = fmaxf(v.z, 0.f);
            v.w = fmaxf(v.w, 0.f);
            bf16* C = p.C + (long)blockIdx.z * p.cStr + n * M + m;
            bf16x4 ov;
            ov[0] = (bf16)v.x;
            ov[1] = (bf16)v.y;
            ov[2] = (bf16)v.z;
            ov[3] = (bf16)v.w;
            *(bf16x4*)C = ov;
        }
    }
}

// ---------------- conv2 K+Q fused (544 blocks, K swizzled for XCD L2) --------
__global__ __launch_bounds__(256) void k_conv2(
    const bf16* __restrict__ w2tk, const bf16* __restrict__ r1k,
    bf16* __restrict__ keyh, const bf16* __restrict__ w2tq,
    const bf16* __restrict__ r1q, bf16* __restrict__ qh) {
    const int M = 512, K = 2560;
    int bx, by, bz;
    const bf16 *A, *B;
    bf16* C;
    bool r1kMode;
    long aStr, bStr, cStr;
    {
        const int i = blockIdx.x;
        if (i < 512) {  // K-branch: blockIdx&7 = (half<<2)|head
            const int slot = i & 7;
            bz = slot & 3;
            const int half = slot >> 2;
            const int j = i >> 3;
            bx = half * 16 + (j & 15);
            by = j >> 4;
            A = w2tk; B = r1k; C = keyh; r1kMode = true;
            aStr = 512L * 2560; bStr = 2621440L; cStr = 2097152L;
        } else {  // Q-branch: 32 blocks
            const int j = i - 512;
            bx = j & 1;
            by = (j >> 1) & 3;
            bz = j >> 3;
            A = w2tq; B = r1q; C = qh; r1kMode = false;
            aStr = 512L * 2560; bStr = 655360L; cStr = 131072L;
        }
    }
    __shared__ bf16 As[128 * 64];
    __shared__ bf16 Bs[128 * 64];
    const int tid = threadIdx.x;
    const int wave = tid >> 6;
    const int lane = tid & 63;
    const int wm = (wave & 1) << 6;
    const int wn = (wave >> 1) << 6;
    const int m0 = by * 128;
    const int n0 = bx * 128;
    A += (long)bz * aStr;
    B += (long)bz * bStr;

    const int srow = lane >> 3;
    const int gch = (lane & 7) ^ srow;
    const bf16* aptr[4];
    const bf16* bptr[4];
#pragma unroll
    for (int i = 0; i < 4; ++i) {
        const int ar = wave * 32 + i * 8 + srow;
        aptr[i] = A + (long)(m0 + ar) * K + gch * 8;
        const int n = n0 + ar;
        const long bbase = r1kMode ? (long)((n >> 4) * 20 + (n & 15)) * 512
                                   : (long)n * K;
        bptr[i] = B + bbase + gch * 8;
    }
    const int ldsOff = wave * 32 * 64;

    floatx4 acc[4][4];
#pragma unroll
    for (int j = 0; j < 4; ++j)
#pragma unroll
        for (int i = 0; i < 4; ++i) acc[j][i] = (floatx4){0.f, 0.f, 0.f, 0.f};

    const int fr = lane & 15;
    const int fq = lane >> 4;
    const int fx = lane & 7;

    for (int k0 = 0; k0 < K; k0 += 64) {
#pragma unroll
        for (int i = 0; i < 4; ++i) {
            __builtin_amdgcn_global_load_lds(
                (const GLOBAL_AS void*)(aptr[i] + k0),
                (LDS_AS void*)(As + ldsOff + i * 512), 16, 0, 0);
            __builtin_amdgcn_global_load_lds(
                (const GLOBAL_AS void*)(bptr[i] + k0),
                (LDS_AS void*)(Bs + ldsOff + i * 512), 16, 0, 0);
        }
        __syncthreads();
#pragma unroll
        for (int kk = 0; kk < 2; ++kk) {
            bf16x8 af[4], bfr[4];
#pragma unroll
            for (int im = 0; im < 4; ++im)
                af[im] = *(const bf16x8*)(As + (wm + im * 16 + fr) * 64 +
                                          ((((kk << 2) + fq) ^ fx) << 3));
#pragma unroll
            for (int in = 0; in < 4; ++in)
                bfr[in] = *(const bf16x8*)(Bs + (wn + in * 16 + fr) * 64 +
                                           ((((kk << 2) + fq) ^ fx) << 3));
#pragma unroll
            for (int in = 0; in < 4; ++in)
#pragma unroll
                for (int im = 0; im < 4; ++im)
                    acc[in][im] = __builtin_amdgcn_mfma_f32_16x16x32_bf16(
                        af[im], bfr[in], acc[in][im], 0, 0, 0);
        }
        __syncthreads();
    }
#pragma unroll
    for (int in = 0; in < 4; ++in) {
        const long n = n0 + wn + in * 16 + fr;
#pragma unroll
        for (int im = 0; im < 4; ++im) {
            floatx4 v = acc[in][im];
            const long m = m0 + wm + im * 16 + (fq << 2);
            v.x = fmaxf(v.x, 0.f);
            v.y = fmaxf(v.y, 0.f);
            v.z = fmaxf(v.z, 0.f);
            v.w = fmaxf(v.w, 0.f);
            bf16* Cp = C + (long)bz * cStr + n * M + m;
            bf16x4 ov;
            ov[0] = (bf16)v.x;
            ov[1] = (bf16)v.y;
            ov[2] = (bf16)v.z;
            ov[3] = (bf16)v.w;
            *(bf16x4*)Cp = ov;
        }
    }
}

// ---------------- fused attention block (one block per batch b) --------------
__global__ __launch_bounds__(512) void k_att(
    const bf16* __restrict__ qh, const bf16* __restrict__ keyh,
    const float* __restrict__ src, const float* __restrict__ dct10,
    const float* __restrict__ lw, const float* __restrict__ lb,
    const float* __restrict__ gia, float* __restrict__ dctin,
    bf16* __restrict__ z0) {
    const int b = blockIdx.x;
    const int t = threadIdx.x;
    __shared__ float BIG[9216];
    __shared__ float WD[2400];
    __shared__ float D[350];
    __shared__ float L[1920];
    __shared__ float dinS[960];
    __shared__ float sS[64];
    __shared__ float awS[64];

    {
        const int g = t >> 3, lane = t & 7;
        const int h = g >> 4, tt = g & 15;
        const bf16* q = qh + ((long)h * 256 + b) * 512 + lane * 64;
        const bf16* kr = keyh + (long)h * 2097152 + ((long)b * 16 + tt) * 512 + lane * 64;
        float p = 0.f;
#pragma unroll
        for (int i = 0; i < 8; ++i) {
            const bf16x8 qv = *(const bf16x8*)(q + i * 8);
            const bf16x8 kv = *(const bf16x8*)(kr + i * 8);
#pragma unroll
            for (int j = 0; j < 8; ++j) p = fmaf((float)qv[j], (float)kv[j], p);
        }
        p += __shfl_down(p, 4, 8);
        p += __shfl_down(p, 2, 8);
        p += __shfl_down(p, 1, 8);
        if (lane == 0) sS[g] = p + 1e-15f;
    }
    for (int i = t; i < 2400; i += 512) WD[i] = src[(long)b * 2400 + i];
    for (int i = t; i < 350; i += 512) D[i] = dct10[i];
    __syncthreads();
    if (t < 4) {
        float s = 0.f;
#pragma unroll
        for (int k = 0; k < 16; ++k) s += sS[t * 16 + k];
        const float inv = 1.f / s;
#pragma unroll
        for (int k = 0; k < 16; ++k) awS[t * 16 + k] = sS[t * 16 + k] * inv;
    }
    __syncthreads();
    for (int p = 0; p < 15; ++p) {
        const int idx = t + p * 512;
        const int n = idx / 480, j = idx % 480;
        const int f = j / 10, d = j % 10;
        float acc = 0.f;
#pragma unroll
        for (int v = 0; v < 35; ++v)
            acc = fmaf(D[d * 35 + v], WD[(n + v) * 48 + f], acc);
        BIG[idx] = acc;
    }
    __syncthreads();
    for (int p = 0; p < 4; ++p) {
        const int idx = t + p * 512;
        if (idx < 1920) {
            const int h = idx / 480, j = idx % 480;
            float acc = 0.f;
#pragma unroll
            for (int k = 0; k < 16; ++k)
                acc = fmaf(awS[h * 16 + k], BIG[k * 480 + j], acc);
            L[idx] = acc;
        }
    }
    if (t < 480) {
        const int f = t / 10, d = t % 10;
        float acc = 0.f;
#pragma unroll
        for (int v = 0; v < 10; ++v)
            acc = fmaf(D[d * 35 + v], WD[(40 + v) * 48 + f], acc);
        float cs = 0.f;
#pragma unroll
        for (int v = 10; v < 35; ++v) cs += D[d * 35 + v];
        acc = fmaf(cs, WD[49 * 48 + f], acc);
        dinS[f * 20 + d] = acc;
        dctin[(long)b * 960 + f * 20 + d] = acc;
    }
    __syncthreads();
    for (int i = t; i < 9216; i += 512) BIG[i] = lw[i];
    for (int i = t; i < 2304; i += 512) WD[i] = gia[i];
    __syncthreads();
    if (t < 480) {
        const int n = t / 10, d = t % 10;
        float acc = lb[n];
#pragma unroll
        for (int h = 0; h < 4; ++h)
#pragma unroll
            for (int f = 0; f < 48; ++f)
                acc = fmaf(BIG[n * 192 + h * 48 + f], L[h * 480 + f * 10 + d], acc);
        dinS[n * 20 + 10 + d] = acc;
        dctin[(long)b * 960 + n * 20 + 10 + d] = acc;
    }
    __syncthreads();
    for (int p = 0; p < 2; ++p) {
        const int idx = t + p * 512;
        if (idx < 960) {
            const int n = idx / 20, d = idx % 20;
            float acc = 0.f;
#pragma unroll
            for (int m = 0; m < 48; ++m)
                acc = fmaf(WD[n * 48 + m], dinS[m * 20 + d], acc);
            z0[((long)b * 48 + n) * 64 + d] = (bf16)acc;
        }
    }
    for (int i = t; i < 2112; i += 512) {
        const int n = i / 44, c = 20 + i % 44;
        z0[((long)b * 48 + n) * 64 + c] = (bf16)0.f;
    }
}

// ---------------- GCN mega-kernel (1024 threads, 16 waves) -------------------
// f-split 32/wave. W streamed L2->registers with explicit double-buffering.
__device__ __forceinline__ void gcn_matmul(const bf16* zS, const bf16* Bg,
                                           const int K, const float* bias,
                                           const bf16* resS, bf16* outS,
                                           const int wave, const int lane) {
    const int fr = lane & 15, fq = lane >> 4;
    const int f0 = wave * 32;
    floatx4 acc[3][2];
#pragma unroll
    for (int it = 0; it < 3; ++it)
#pragma unroll
        for (int jt = 0; jt < 2; ++jt) acc[it][jt] = (floatx4){0.f, 0.f, 0.f, 0.f};
    const bf16* bp0 = Bg + (long)(f0 + fr) * K + fq * 8;
    const bf16* bp1 = Bg + (long)(f0 + 16 + fr) * K + fq * 8;
    bf16x8 bc0 = *(const bf16x8*)(bp0);
    bf16x8 bc1 = *(const bf16x8*)(bp1);
    for (int k0 = 0; k0 < K; k0 += 32) {
        bf16x8 bn0, bn1;
        if (k0 + 32 < K) {
            bn0 = *(const bf16x8*)(bp0 + k0 + 32);
            bn1 = *(const bf16x8*)(bp1 + k0 + 32);
        }
        bf16x8 af[3];
#pragma unroll
        for (int it = 0; it < 3; ++it)
            af[it] = *(const bf16x8*)(zS + (it * 16 + fr) * 520 + k0 + fq * 8);
#pragma unroll
        for (int it = 0; it < 3; ++it) {
            acc[it][0] = __builtin_amdgcn_mfma_f32_16x16x32_bf16(af[it], bc0,
                                                                acc[it][0], 0, 0, 0);
            acc[it][1] = __builtin_amdgcn_mfma_f32_16x16x32_bf16(af[it], bc1,
                                                                acc[it][1], 0, 0, 0);
        }
        bc0 = bn0;
        bc1 = bn1;
    }
#pragma unroll
    for (int jt = 0; jt < 2; ++jt) {
        const int f = f0 + jt * 16 + fr;
        const float bv = bias[f];
#pragma unroll
        for (int it = 0; it < 3; ++it)
#pragma unroll
            for (int r = 0; r < 4; ++r) {
                const int irow = it * 16 + fq * 4 + r;
                float v = tanh_fast((acc[it][jt][r] + bv) * BN_SCALE_F);
                if (resS) v += (float)resS[irow * 520 + f];
                outS[irow * 520 + f] = (bf16)v;
            }
    }
}

__device__ __forceinline__ void gcn_attmul(const bf16* attS, const bf16* yS,
                                           bf16* zS, const int wave,
                                           const int lane) {
    const int fr = lane & 15, fq = lane >> 4;
    const int f0 = wave * 32;
    floatx4 acc[3][2];
#pragma unroll
    for (int it = 0; it < 3; ++it)
#pragma unroll
        for (int jt = 0; jt < 2; ++jt) acc[it][jt] = (floatx4){0.f, 0.f, 0.f, 0.f};
#pragma unroll
    for (int k0 = 0; k0 < 64; k0 += 32) {
        bf16x8 af[3];
#pragma unroll
        for (int it = 0; it < 3; ++it)
            af[it] = *(const bf16x8*)(attS + (it * 16 + fr) * 72 + k0 + fq * 8);
        bf16x8 bfv[2];
#pragma unroll
        for (int jt = 0; jt < 2; ++jt) {
            const int f = f0 + jt * 16 + fr;
            bf16x8 v;
#pragma unroll
            for (int e = 0; e < 8; ++e) {
                int m = k0 + fq * 8 + e;
                m = m < 48 ? m : 47;  // att cols >=48 zero -> clamp safe
                v[e] = yS[m * 520 + f];
            }
            bfv[jt] = v;
        }
#pragma unroll
        for (int it = 0; it < 3; ++it)
#pragma unroll
            for (int jt = 0; jt < 2; ++jt)
                acc[it][jt] = __builtin_amdgcn_mfma_f32_16x16x32_bf16(
                    af[it], bfv[jt], acc[it][jt], 0, 0, 0);
    }
#pragma unroll
    for (int jt = 0; jt < 2; ++jt) {
        const int f = f0 + jt * 16 + fr;
#pragma unroll
        for (int it = 0; it < 3; ++it)
#pragma unroll
            for (int r = 0; r < 4; ++r)
                zS[(it * 16 + fq * 4 + r) * 520 + f] = (bf16)acc[it][jt][r];
    }
}

__global__ __launch_bounds__(1024) void k_gcn(
    const bf16* __restrict__ z0, const bf16* __restrict__ giwP,
    const float* __restrict__ gib, const bf16* __restrict__ gbwt,
    const float* __restrict__ gba, const float* __restrict__ gbb,
    const float* __restrict__ goa, const float* __restrict__ gow,
    const float* __restrict__ gob, const float* __restrict__ dctin,
    const float* __restrict__ dct10, float* __restrict__ out) {
    const int b = blockIdx.x;
    const int t = threadIdx.x;
    const int wave = t >> 6, lane = t & 63;
    __shared__ __align__(16) bf16 yaS[48 * 520];
    __shared__ __align__(16) bf16 ybS[48 * 520];
    __shared__ __align__(16) bf16 zS[48 * 520];
    __shared__ __align__(16) bf16 attS[48 * 72];

    if (t < 384) {
        const int r = t >> 3, c = t & 7;
        *(bf16x8*)(zS + r * 520 + c * 8) =
            *(const bf16x8*)(z0 + ((long)b * 48 + r) * 64 + c * 8);
    }
    __syncthreads();
    gcn_matmul(zS, giwP, 64, gib, nullptr, yaS, wave, lane);
    __syncthreads();

#pragma unroll
    for (int l = 0; l < 4; ++l) {
        bf16* Yin = (l == 0 || l == 3) ? yaS : ybS;
        bf16* Yout = (l < 2) ? ybS : yaS;
        bf16* Res = (l == 1) ? yaS : (l == 3 ? ybS : nullptr);
        for (int i = t; i < 48 * 72; i += 1024) {
            const int rr = i / 72, c = i % 72;
            attS[i] = (bf16)(c < 48 ? gba[l * 2304 + rr * 48 + c] : 0.f);
        }
        __syncthreads();
        gcn_attmul(attS, Yin, zS, wave, lane);
        __syncthreads();
        gcn_matmul(zS, gbwt + (long)l * 262144, 512, gbb + l * 512, Res, Yout,
                   wave, lane);
        __syncthreads();
    }
    // ---- gc_out + iDCT (final Y = yaS) ----
    bf16* GS = zS;                              // [20][520] gow^T
    float* goaS = (float*)((char*)zS + 24576);  // 2304 f32
    float* Df = (float*)attS;                   // 350 f32
    float* T2 = (float*)ybS;                    // 960 f32
    float* dS = ((float*)ybS) + 1024;           // 960 f32
    for (int i = t; i < 10240; i += 1024) {
        const int d = i >> 9, k = i & 511;
        GS[d * 520 + k] = (bf16)gow[k * 20 + d];
    }
    for (int i = t; i < 2304; i += 1024) goaS[i] = goa[i];
    if (t < 350) Df[t] = dct10[t];
    __syncthreads();
    for (int idx = t; idx < 960; idx += 1024) {
        const int m = idx / 20, d = idx % 20;
        float acc = 0.f;
        const bf16* yr = yaS + m * 520;
        const bf16* gr = GS + d * 520;
#pragma unroll 8
        for (int k8 = 0; k8 < 64; ++k8) {
            const bf16x8 yv = *(const bf16x8*)(yr + k8 * 8);
            const bf16x8 gv = *(const bf16x8*)(gr + k8 * 8);
#pragma unroll
            for (int j = 0; j < 8; ++j) acc = fmaf((float)yv[j], (float)gv[j], acc);
        }
        T2[idx] = acc;
    }
    __syncthreads();
    for (int idx = t; idx < 960; idx += 1024) {
        const int n = idx / 20, d = idx % 20;
        float acc = gob[d] + dctin[(long)b * 960 + idx];
#pragma unroll
        for (int m = 0; m < 48; ++m)
            acc = fmaf(goaS[n * 48 + m], T2[m * 20 + d], acc);
        dS[idx] = acc;
    }
    __syncthreads();
    for (int e = t; e < 1680; e += 1024) {
        const int v = e / 48, n = e % 48;
        float acc = 0.f;
#pragma unroll
        for (int d = 0; d < 10; ++d)
            acc = fmaf(Df[d * 35 + v], dS[n * 20 + d], acc);
        out[(long)b * 1680 + e] = acc;
    }
}

// ---------------------------------------------------------------------------
// Workspace (BYTE offsets). keyh bf16 (16.8 MB) aliases WS_T; z0 at WS_T+17MB.
// ---------------------------------------------------------------------------
static constexpr size_t WS_DCT10 = 0;
static constexpr size_t WS_ATTW = 1536;
static constexpr size_t WS_QH = WS_ATTW + 65536;
static constexpr size_t WS_DCTIN = WS_QH + 2097152;
static constexpr size_t WS_DCTOUT = WS_DCTIN + 983040;
static constexpr size_t WS_SRCVAL = WS_DCTOUT + 983040;
static constexpr size_t WS_PAD0 = WS_SRCVAL + 7864320;
static constexpr size_t WS_SRCBF = WS_PAD0 + 8388608;
static constexpr size_t WS_W1TQ = WS_SRCBF + 1229824;
static constexpr size_t WS_W1TK = WS_W1TQ + 1310720;
static constexpr size_t WS_W2TQ = WS_W1TK + 1310720;
static constexpr size_t WS_W2TK = WS_W2TQ + 10485760;
static constexpr size_t WS_GBWT = WS_W2TK + 10485760;
static constexpr size_t WS_R1K = WS_GBWT + 2097152;
static constexpr size_t WS_R1Q = WS_R1K + 20971520;
static constexpr size_t WS_T = WS_R1Q + 5242880;
static constexpr size_t WS_GIWP = WS_T + 50331648;
static constexpr size_t WS_KEYH = WS_T;
static constexpr size_t WS_Z0 = WS_T + 17825792;

extern "C" void kernel_launch(void* const* d_in, const int* in_sizes, int n_in,
                              void* d_out, int out_size, void* d_ws,
                              size_t ws_size, hipStream_t stream) {
    const float* src = (const float*)d_in[0];
    const float* cq1 = (const float*)d_in[1];
    const float* cq2 = (const float*)d_in[2];
    const float* ck1 = (const float*)d_in[3];
    const float* ck2 = (const float*)d_in[4];
    const float* lw = (const float*)d_in[5];
    const float* lb = (const float*)d_in[6];
    const float* giw = (const float*)d_in[7];
    const float* gia = (const float*)d_in[8];
    const float* gib = (const float*)d_in[9];
    const float* gbw = (const float*)d_in[10];
    const float* gba = (const float*)d_in[11];
    const float* gbb = (const float*)d_in[12];
    const float* gow = (const float*)d_in[13];
    const float* goa = (const float*)d_in[14];
    const float* gob = (const float*)d_in[15];
    float* out = (float*)d_out;
    char* ws = (char*)d_ws;

    float* dct10 = (float*)(ws + WS_DCT10);
    bf16* qh = (bf16*)(ws + WS_QH);
    float* dctin = (float*)(ws + WS_DCTIN);
    bf16* keyh = (bf16*)(ws + WS_KEYH);
    bf16* srcbf = (bf16*)(ws + WS_SRCBF);
    bf16* w1tq = (bf16*)(ws + WS_W1TQ);
    bf16* w1tk = (bf16*)(ws + WS_W1TK);
    bf16* w2tq = (bf16*)(ws + WS_W2TQ);
    bf16* w2tk = (bf16*)(ws + WS_W2TK);
    bf16* gbwt = (bf16*)(ws + WS_GBWT);
    bf16* r1k = (bf16*)(ws + WS_R1K);
    bf16* r1q = (bf16*)(ws + WS_R1Q);
    bf16* giwP = (bf16*)(ws + WS_GIWP);
    bf16* z0 = (bf16*)(ws + WS_Z0);

    // 1. all prep in one dispatch (tiled transposes)
    k_prep<<<12003, 256, 0, stream>>>(src, cq1, ck1, cq2, ck2, gbw, giw, dct10,
                                      srcbf, w1tq, w1tk, w2tq, w2tk, gbwt, giwP);

    // 2. conv1 K+Q fused, gridDim.x padded to 56
    {
        GP pk{w1tk, srcbf, r1k, 20, 0, 40, 512L * 320, 0L, 5120L * 512};
        GP pq{w1tq, srcbf, r1q, 5, 40, 10, 512L * 320, 0L, 1280L * 512};
        mgemm2<BM_SRC, BM_SRC><<<dim3(56, 4, 4), 256, 0, stream>>>(pk, pq, 40,
                                                                   512, 320);
    }
    // 3. conv2 K+Q in one 544-block dispatch (K swizzled)
    k_conv2<<<544, 256, 0, stream>>>(w2tk, r1k, keyh, w2tq, r1q, qh);

    // 4. fused attention block -> dctin (fp32), z0 (bf16)
    k_att<<<256, 512, 0, stream>>>(qh, keyh, src, dct10, lw, lb, gia, dctin, z0);

    // 5. whole GCN in one dispatch (1024 threads / 16 waves)
    k_gcn<<<256, 1024, 0, stream>>>(z0, giwP, gib, gbwt, gba, gbb, goa, gow,
                                    gob, dctin, dct10, out);
}